// Round 6
// baseline (5307.929 us; speedup 1.0000x reference)
//
#include <hip/hip_runtime.h>
#include <math.h>

#define EMB 512
#define HEADS 8
#define NLAYERS 4
#define NB 32
#define SEQ 200
#define TOKN 50
#define DH 64
#define FFND 2048
#define NCLS 204
#define VC 640          // virtual conv channels, padded (600 real)
#define KD 1024         // conv K dim
#define CCH 8           // conv row-chunks
#define CROWS (6400/CCH)        // 800 seq rows per chunk
#define CM (CROWS*TOKN)         // 40000 GEMM M-rows per chunk
#define MSEG 16                 // means two-stage row segments
#define CMT ((CM + 127) / 128)  // 313 m-tiles
#define CNT (VC / 128)          // 5 n-tiles
#define CT  (CMT * CNT)         // 1565 tiles

typedef __attribute__((ext_vector_type(8))) short v8s;
typedef __attribute__((ext_vector_type(4))) float v4f;
typedef unsigned short ushort_t;

__device__ __forceinline__ ushort_t f2bu(float f){  // f32 -> bf16 bits, RNE
  unsigned u = __float_as_uint(f);
  return (ushort_t)((u + 0x7FFFu + ((u >> 16) & 1u)) >> 16);
}
__device__ __forceinline__ float bu2f(ushort_t u){
  return __uint_as_float(((unsigned)u) << 16);
}

// bijective XCD-chunk swizzle (m204): orig dispatch id -> logical tile id,
// contiguous logical tiles per XCD.
__device__ __forceinline__ int xcd_swz(int lin, int nwg){
  int xcd = lin & 7, idx = lin >> 3;
  int q = nwg >> 3, r = nwg & 7;
  return ((xcd < r) ? xcd * (q + 1) : r * (q + 1) + (xcd - r) * q) + idx;
}

__device__ __forceinline__ float block_reduce(float v, float* red, int nwaves, bool domax){
  int tid = threadIdx.x;
  #pragma unroll
  for (int o = 32; o > 0; o >>= 1){
    float t = __shfl_down(v, o, 64);
    v = domax ? fmaxf(v, t) : (v + t);
  }
  __syncthreads();
  if ((tid & 63) == 0) red[tid >> 6] = v;
  __syncthreads();
  float r = red[0];
  for (int i = 1; i < nwaves; i++) r = domax ? fmaxf(r, red[i]) : (r + red[i]);
  return r;
}

// ---------------------------------------------------------------------------
// Prep kernels
// ---------------------------------------------------------------------------
__global__ void prep_w_kernel(const float* __restrict__ cw1, const float* __restrict__ cw2,
                              const float* __restrict__ cw3, ushort_t* __restrict__ Wb){
  int idx4 = blockIdx.x * 256 + threadIdx.x;
  if (idx4 >= VC * KD / 4) return;
  int row = idx4 >> 8;
  int k = (idx4 & 255) * 4;
  float4 v = make_float4(0.f, 0.f, 0.f, 0.f);
  const float* s = nullptr;
  if (row < 100)      s = cw1 + (size_t)row * KD;
  else if (row < 200) s = cw2 + (size_t)((row - 100) * 2 + 0) * KD;
  else if (row < 300) s = cw2 + (size_t)((row - 200) * 2 + 1) * KD;
  else if (row < 400) s = cw3 + (size_t)((row - 300) * 3 + 0) * KD;
  else if (row < 500) s = cw3 + (size_t)((row - 400) * 3 + 1) * KD;
  else if (row < 600) s = cw3 + (size_t)((row - 500) * 3 + 2) * KD;
  if (s) v = *(const float4*)(s + k);
  ushort4 o;
  o.x = f2bu(v.x); o.y = f2bu(v.y); o.z = f2bu(v.z); o.w = f2bu(v.w);
  *(ushort4*)(Wb + (size_t)row * KD + k) = o;
}

// emb f32 (20000 x 1024) -> bf16 RNE (same rounding the conv staging used)
__global__ void prep_embbf_kernel(const float* __restrict__ emb, ushort_t* __restrict__ embb){
  size_t i4 = ((size_t)blockIdx.x * 256 + threadIdx.x) * 4;
  if (i4 >= 20000ULL * KD) return;
  float4 f = *(const float4*)(emb + i4);
  ushort4 o;
  o.x = f2bu(f.x); o.y = f2bu(f.y); o.z = f2bu(f.z); o.w = f2bu(f.w);
  *(ushort4*)(embb + i4) = o;
}

__global__ void prep_tfwT_kernel(const float* __restrict__ tfw, float* __restrict__ tfwT){
  int idx = blockIdx.x * 256 + threadIdx.x;
  if (idx >= 300 * EMB) return;
  int j = idx >> 9, o = idx & 511;
  tfwT[(size_t)j * EMB + o] = tfw[(size_t)o * 300 + j];
}

// split f32 -> (hi bf16 trunc, lo bf16 RNE of remainder)
__global__ void split_kernel(const float* __restrict__ src, ushort_t* __restrict__ hi,
                             ushort_t* __restrict__ lo, int n){
  int i4 = (blockIdx.x * 256 + threadIdx.x) * 4;
  if (i4 >= n) return;
  float4 f = *(const float4*)(src + i4);
  float x[4] = {f.x, f.y, f.z, f.w};
  ushort4 h, l;
  ushort_t hh[4], ll[4];
  #pragma unroll
  for (int e = 0; e < 4; e++){
    unsigned u = __float_as_uint(x[e]);
    float hf = __uint_as_float(u & 0xFFFF0000u);
    hh[e] = (ushort_t)(u >> 16);
    ll[e] = f2bu(x[e] - hf);
  }
  h.x=hh[0]; h.y=hh[1]; h.z=hh[2]; h.w=hh[3];
  l.x=ll[0]; l.y=ll[1]; l.z=ll[2]; l.w=ll[3];
  *(ushort4*)(hi + i4) = h;
  *(ushort4*)(lo + i4) = l;
}

__global__ void qkvbias_kernel(const float* __restrict__ bq, const float* __restrict__ bk,
                               const float* __restrict__ bv, float* __restrict__ bqkv){
  int l = blockIdx.x;
  for (int j = threadIdx.x; j < 1536; j += 256){
    float v;
    if (j < 512) v = bq[l * 512 + j];
    else if (j < 1024) v = bk[l * 512 + j - 512];
    else v = bv[l * 512 + j - 1024];
    bqkv[l * 1536 + j] = v;
  }
}

// grid-stride float4 zero (for split-K accumulators)
__global__ __launch_bounds__(256) void zerobuf_kernel(float* __restrict__ p, size_t n4){
  size_t i = (size_t)blockIdx.x * 256 + threadIdx.x;
  size_t stride = (size_t)gridDim.x * 256;
  for (; i < n4; i += stride)
    ((float4*)p)[i] = make_float4(0.f, 0.f, 0.f, 0.f);
}

// ---------------------------------------------------------------------------
// Conv GEMM (textcnn stage 1): C[m][n] = Eb[m] . Wb[n], bf16 in/out, f32 acc.
// ---------------------------------------------------------------------------
__global__ __launch_bounds__(256, 4) void conv_gemm_kernel(
    const int* __restrict__ tok, const ushort_t* __restrict__ embb,
    const ushort_t* __restrict__ Wb, ushort_t* __restrict__ Cout, int Mc)
{
  __shared__ ushort_t Al[128][40];
  __shared__ ushort_t Bl[128][40];
  const int tid = threadIdx.x;
  const int t = xcd_swz(blockIdx.x, CT);
  const int n0 = (t % CNT) * 128;
  const int m0 = (t / CNT) * 128;
  const int wave = tid >> 6, lane = tid & 63;
  const int wm = (wave >> 1) * 64, wn = (wave & 1) * 64;
  const int lcol = lane & 15, lq = lane >> 4;

  v4f acc[4][4];
  #pragma unroll
  for (int i = 0; i < 4; i++)
    #pragma unroll
    for (int j = 0; j < 4; j++) acc[i][j] = (v4f){0.f, 0.f, 0.f, 0.f};

  const int srow = tid >> 1, skh = (tid & 1) * 16;
  const int am = m0 + srow;
  const ushort_t* aep = (am < Mc) ? (embb + (size_t)tok[am] * KD + skh) : nullptr;
  const ushort_t* bep = Wb + (size_t)(n0 + srow) * KD + skh;

  for (int k0 = 0; k0 < KD; k0 += 32){
    uint4 a0 = make_uint4(0,0,0,0), a1 = make_uint4(0,0,0,0);
    if (aep){
      a0 = *(const uint4*)(aep + k0);
      a1 = *(const uint4*)(aep + k0 + 8);
    }
    *(uint4*)&Al[srow][skh]     = a0;
    *(uint4*)&Al[srow][skh + 8] = a1;
    uint4 b0 = *(const uint4*)(bep + k0);
    uint4 b1 = *(const uint4*)(bep + k0 + 8);
    *(uint4*)&Bl[srow][skh]     = b0;
    *(uint4*)&Bl[srow][skh + 8] = b1;
    __syncthreads();

    v8s af[4];
    #pragma unroll
    for (int mi = 0; mi < 4; mi++)
      af[mi] = *(const v8s*)&Al[wm + mi*16 + lcol][lq*8];
    #pragma unroll
    for (int ni = 0; ni < 4; ni++){
      v8s bf = *(const v8s*)&Bl[wn + ni*16 + lcol][lq*8];
      #pragma unroll
      for (int mi = 0; mi < 4; mi++)
        acc[mi][ni] = __builtin_amdgcn_mfma_f32_16x16x32_bf16(af[mi], bf, acc[mi][ni], 0, 0, 0);
    }
    __syncthreads();
  }

  #pragma unroll
  for (int ni = 0; ni < 4; ni++){
    int n = n0 + wn + ni*16 + lcol;
    #pragma unroll
    for (int mi = 0; mi < 4; mi++){
      int mbase = m0 + wm + mi*16 + lq*4;
      #pragma unroll
      for (int rg = 0; rg < 4; rg++){
        int m = mbase + rg;
        if (m < Mc) Cout[(size_t)m * VC + n] = f2bu(acc[mi][ni][rg]);
      }
    }
  }
}

// ---------------------------------------------------------------------------
// Pool + FC + ln_free (textcnn stage 2): one block per seq row in chunk.
// ---------------------------------------------------------------------------
__global__ __launch_bounds__(256, 2) void pool_fc_kernel(
    const ushort_t* __restrict__ Cc, const float* __restrict__ tfwT,
    const float* __restrict__ cb1, const float* __restrict__ cb2,
    const float* __restrict__ cb3, const float* __restrict__ tfb,
    float* __restrict__ basep)
{
  __shared__ ushort_t Sg[VC][54];
  __shared__ float pooled[304];
  __shared__ float red[8];
  const int tid = threadIdx.x;
  const int r = blockIdx.x;

  const unsigned* cr = (const unsigned*)(Cc + (size_t)r * TOKN * VC);
  for (int p = 0; p < TOKN; p++){
    for (int t = tid; t < VC/2; t += 256){
      unsigned u = cr[p * (VC/2) + t];
      Sg[2*t][p]   = (ushort_t)(u & 0xFFFFu);
      Sg[2*t+1][p] = (ushort_t)(u >> 16);
    }
  }
  __syncthreads();

  for (int c = tid; c < 300; c += 256){
    float mv = -1e30f;
    if (c < 100){
      float bb = cb1[c];
      for (int p = 0; p < 50; p++) mv = fmaxf(mv, bu2f(Sg[c][p]) + bb);
    } else if (c < 200){
      int o = c - 100; float bb = cb2[o];
      for (int p = 0; p < 49; p++)
        mv = fmaxf(mv, bu2f(Sg[100 + o][p]) + bu2f(Sg[200 + o][p + 1]) + bb);
    } else {
      int o = c - 200; float bb = cb3[o];
      for (int p = 0; p < 48; p++)
        mv = fmaxf(mv, bu2f(Sg[300 + o][p]) + bu2f(Sg[400 + o][p + 1]) + bu2f(Sg[500 + o][p + 2]) + bb);
    }
    pooled[c] = fmaxf(mv, 0.f);
  }
  __syncthreads();

  float v0 = tfb[tid], v1 = tfb[tid + 256];
  for (int j = 0; j < 300; j++){
    float pj = pooled[j];
    v0 = fmaf(pj, tfwT[(size_t)j * EMB + tid], v0);
    v1 = fmaf(pj, tfwT[(size_t)j * EMB + tid + 256], v1);
  }
  float tot = block_reduce(v0 + v1, red, 4, false);
  float mu = tot * (1.f / 512.f);
  float s0 = v0 - mu, s1 = v1 - mu;
  float var = block_reduce(s0 * s0 + s1 * s1, red, 4, false) * (1.f / 512.f);
  float sc = sqrtf(1.f / (var + 1e-12f));
  basep[(size_t)r * EMB + tid] = s0 * sc;
  basep[(size_t)r * EMB + tid + 256] = s1 * sc;
}

// ---------------------------------------------------------------------------
// Split-bf16 MFMA GEMM, 128x128 tile, PRE-SPLIT weights, 1-D swizzled grid.
// ---------------------------------------------------------------------------
__global__ __launch_bounds__(256, 3) void gemm_mfma_pre_kernel(
    const float* __restrict__ A, const ushort_t* __restrict__ Whi,
    const ushort_t* __restrict__ Wlo, const float* __restrict__ bias,
    float* __restrict__ C, int M, int N, int K, int ldc, int act, int mt, int nt)
{
  __shared__ ushort_t Ahi[128][40];
  __shared__ ushort_t Alo[128][40];
  __shared__ ushort_t Bhi[128][40];
  __shared__ ushort_t Blo[128][40];

  const int tid = threadIdx.x;
  const int t = xcd_swz(blockIdx.x, mt * nt);
  const int n0 = (t % nt) * 128, m0 = (t / nt) * 128;
  const int wave = tid >> 6, lane = tid & 63;
  const int wm = (wave >> 1) * 64, wn = (wave & 1) * 64;
  const int lcol = lane & 15, lq = lane >> 4;

  v4f acc[4][4];
  #pragma unroll
  for (int i = 0; i < 4; i++)
    #pragma unroll
    for (int j = 0; j < 4; j++) acc[i][j] = (v4f){0.f, 0.f, 0.f, 0.f};

  const int srow = tid >> 1;
  const int skh  = (tid & 1) * 16;
  const int am = m0 + srow, bn = n0 + srow;
  const bool mok = (am < M), nok = (bn < N);
  const float* ap = A + (size_t)am * K + skh;
  const ushort_t* bph = Whi + (size_t)bn * K + skh;
  const ushort_t* bpl = Wlo + (size_t)bn * K + skh;

  for (int k0 = 0; k0 < K; k0 += 32){
    bool kfull = (k0 + 32 <= K);
    // ---- stage A (split on the fly) ----
    {
      float av[16];
      if (mok && kfull){
        #pragma unroll
        for (int q = 0; q < 4; q++){
          float4 f = *(const float4*)(ap + k0 + q*4);
          av[q*4+0]=f.x; av[q*4+1]=f.y; av[q*4+2]=f.z; av[q*4+3]=f.w;
        }
      } else {
        #pragma unroll
        for (int e = 0; e < 16; e++){
          int k = k0 + skh + e;
          av[e] = (mok && k < K) ? ap[k0 + e] : 0.f;
        }
      }
      uint4 uh[2], ul[2];
      #pragma unroll
      for (int h = 0; h < 2; h++){
        unsigned hw[8], lw[8];
        #pragma unroll
        for (int e = 0; e < 8; e++){
          float x = av[h*8+e];
          unsigned u = __float_as_uint(x);
          float hf = __uint_as_float(u & 0xFFFF0000u);
          hw[e] = u >> 16;
          lw[e] = f2bu(x - hf);
        }
        uh[h] = make_uint4(hw[0]|(hw[1]<<16), hw[2]|(hw[3]<<16), hw[4]|(hw[5]<<16), hw[6]|(hw[7]<<16));
        ul[h] = make_uint4(lw[0]|(lw[1]<<16), lw[2]|(lw[3]<<16), lw[4]|(lw[5]<<16), lw[6]|(lw[7]<<16));
      }
      *(uint4*)&Ahi[srow][skh]     = uh[0];
      *(uint4*)&Ahi[srow][skh + 8] = uh[1];
      *(uint4*)&Alo[srow][skh]     = ul[0];
      *(uint4*)&Alo[srow][skh + 8] = ul[1];
    }
    // ---- stage B (pre-split: plain copies) ----
    {
      uint4 h0 = make_uint4(0,0,0,0), h1 = h0, l0 = h0, l1 = h0;
      if (nok && kfull){
        h0 = *(const uint4*)(bph + k0);
        h1 = *(const uint4*)(bph + k0 + 8);
        l0 = *(const uint4*)(bpl + k0);
        l1 = *(const uint4*)(bpl + k0 + 8);
      } else if (nok){
        ushort_t he[16], le[16];
        #pragma unroll
        for (int e = 0; e < 16; e++){
          int k = k0 + skh + e;
          he[e] = (k < K) ? bph[k0 + e] : (ushort_t)0;
          le[e] = (k < K) ? bpl[k0 + e] : (ushort_t)0;
        }
        h0 = *(uint4*)&he[0]; h1 = *(uint4*)&he[8];
        l0 = *(uint4*)&le[0]; l1 = *(uint4*)&le[8];
      }
      *(uint4*)&Bhi[srow][skh]     = h0;
      *(uint4*)&Bhi[srow][skh + 8] = h1;
      *(uint4*)&Blo[srow][skh]     = l0;
      *(uint4*)&Blo[srow][skh + 8] = l1;
    }
    __syncthreads();

    v8s ah[4], al[4];
    #pragma unroll
    for (int mi = 0; mi < 4; mi++){
      ah[mi] = *(const v8s*)&Ahi[wm + mi*16 + lcol][lq*8];
      al[mi] = *(const v8s*)&Alo[wm + mi*16 + lcol][lq*8];
    }
    #pragma unroll
    for (int ni = 0; ni < 4; ni++){
      v8s bh = *(const v8s*)&Bhi[wn + ni*16 + lcol][lq*8];
      v8s bl = *(const v8s*)&Blo[wn + ni*16 + lcol][lq*8];
      #pragma unroll
      for (int mi = 0; mi < 4; mi++){
        acc[mi][ni] = __builtin_amdgcn_mfma_f32_16x16x32_bf16(ah[mi], bh, acc[mi][ni], 0, 0, 0);
        acc[mi][ni] = __builtin_amdgcn_mfma_f32_16x16x32_bf16(al[mi], bh, acc[mi][ni], 0, 0, 0);
        acc[mi][ni] = __builtin_amdgcn_mfma_f32_16x16x32_bf16(ah[mi], bl, acc[mi][ni], 0, 0, 0);
      }
    }
    __syncthreads();
  }

  #pragma unroll
  for (int ni = 0; ni < 4; ni++){
    int n = n0 + wn + ni*16 + lcol;
    if (n >= N) continue;
    float bv = bias[n];
    #pragma unroll
    for (int mi = 0; mi < 4; mi++){
      int mbase = m0 + wm + mi*16 + lq*4;
      #pragma unroll
      for (int rg = 0; rg < 4; rg++){
        int m = mbase + rg;
        if (m >= M) continue;
        float v = acc[mi][ni][rg] + bv;
        if (act == 1) v = fmaxf(v, 0.f);
        else if (act == 2) v = 0.5f * v * (1.f + erff(v * 0.70710678118654752f));
        C[(size_t)m * ldc + n] = v;
      }
    }
  }
}

// ---------------------------------------------------------------------------
// Split-bf16 MFMA GEMM, 128M x 64N tile, PRE-SPLIT weights, 1-D swizzled grid,
// optional split-K (ks slices accumulate into pre-zeroed C via atomicAdd;
// slice 0 folds the bias; host guarantees act==0 when ks>1).
// ---------------------------------------------------------------------------
__global__ __launch_bounds__(256, 4) void gemm_mfma_pre64_kernel(
    const float* __restrict__ A, const ushort_t* __restrict__ Whi,
    const ushort_t* __restrict__ Wlo, const float* __restrict__ bias,
    float* __restrict__ C, int M, int N, int K, int ldc, int act, int mt, int nt, int ks)
{
  __shared__ ushort_t Ahi[128][40];
  __shared__ ushort_t Alo[128][40];
  __shared__ ushort_t Bhi[64][40];
  __shared__ ushort_t Blo[64][40];

  const int tid = threadIdx.x;
  const int tiles = mt * nt;
  const int t_ = xcd_swz(blockIdx.x, tiles * ks);
  const int slice = t_ / tiles;
  const int t = t_ % tiles;
  const int n0 = (t % nt) * 64, m0 = (t / nt) * 128;
  // K-slice bounds (32-aligned)
  const int kstep = ((K + 31) / 32 + ks - 1) / ks;   // k-steps per slice
  const int kb = slice * kstep * 32;
  const int ke = min(K, kb + kstep * 32);
  if (kb >= ke) return;
  const int wave = tid >> 6, lane = tid & 63;
  const int wm = (wave >> 1) * 64, wn = (wave & 1) * 32;
  const int lcol = lane & 15, lq = lane >> 4;

  v4f acc[4][2];
  #pragma unroll
  for (int i = 0; i < 4; i++)
    #pragma unroll
    for (int j = 0; j < 2; j++) acc[i][j] = (v4f){0.f, 0.f, 0.f, 0.f};

  // A staging: 256 threads, row tid>>1, 16-elem half (tid&1)*16
  const int srow = tid >> 1;
  const int skh  = (tid & 1) * 16;
  const int am = m0 + srow;
  const bool mok = (am < M);
  const float* ap = A + (size_t)am * K + skh;
  // B staging: 256 threads, row tid>>2, 8-elem quarter (tid&3)*8
  const int brow = tid >> 2;
  const int bkq  = (tid & 3) * 8;
  const int bn = n0 + brow;
  const bool nok = (bn < N);
  const ushort_t* bph = Whi + (size_t)bn * K + bkq;
  const ushort_t* bpl = Wlo + (size_t)bn * K + bkq;

  for (int k0 = kb; k0 < ke; k0 += 32){
    bool kfull = (k0 + 32 <= K);
    // ---- stage A (split on the fly) ----
    {
      float av[16];
      if (mok && kfull){
        #pragma unroll
        for (int q = 0; q < 4; q++){
          float4 f = *(const float4*)(ap + k0 + q*4);
          av[q*4+0]=f.x; av[q*4+1]=f.y; av[q*4+2]=f.z; av[q*4+3]=f.w;
        }
      } else {
        #pragma unroll
        for (int e = 0; e < 16; e++){
          int k = k0 + skh + e;
          av[e] = (mok && k < K) ? ap[k0 + e] : 0.f;
        }
      }
      uint4 uh[2], ul[2];
      #pragma unroll
      for (int h = 0; h < 2; h++){
        unsigned hw[8], lw[8];
        #pragma unroll
        for (int e = 0; e < 8; e++){
          float x = av[h*8+e];
          unsigned u = __float_as_uint(x);
          float hf = __uint_as_float(u & 0xFFFF0000u);
          hw[e] = u >> 16;
          lw[e] = f2bu(x - hf);
        }
        uh[h] = make_uint4(hw[0]|(hw[1]<<16), hw[2]|(hw[3]<<16), hw[4]|(hw[5]<<16), hw[6]|(hw[7]<<16));
        ul[h] = make_uint4(lw[0]|(lw[1]<<16), lw[2]|(lw[3]<<16), lw[4]|(lw[5]<<16), lw[6]|(lw[7]<<16));
      }
      *(uint4*)&Ahi[srow][skh]     = uh[0];
      *(uint4*)&Ahi[srow][skh + 8] = uh[1];
      *(uint4*)&Alo[srow][skh]     = ul[0];
      *(uint4*)&Alo[srow][skh + 8] = ul[1];
    }
    // ---- stage B (pre-split: plain 8-elem copies) ----
    {
      uint4 h0 = make_uint4(0,0,0,0), l0 = h0;
      if (nok && kfull){
        h0 = *(const uint4*)(bph + k0);
        l0 = *(const uint4*)(bpl + k0);
      } else if (nok){
        ushort_t he[8], le[8];
        #pragma unroll
        for (int e = 0; e < 8; e++){
          int k = k0 + bkq + e;
          he[e] = (k < K) ? bph[k0 + e] : (ushort_t)0;
          le[e] = (k < K) ? bpl[k0 + e] : (ushort_t)0;
        }
        h0 = *(uint4*)&he[0];
        l0 = *(uint4*)&le[0];
      }
      *(uint4*)&Bhi[brow][bkq] = h0;
      *(uint4*)&Blo[brow][bkq] = l0;
    }
    __syncthreads();

    v8s ah[4], al[4];
    #pragma unroll
    for (int mi = 0; mi < 4; mi++){
      ah[mi] = *(const v8s*)&Ahi[wm + mi*16 + lcol][lq*8];
      al[mi] = *(const v8s*)&Alo[wm + mi*16 + lcol][lq*8];
    }
    #pragma unroll
    for (int ni = 0; ni < 2; ni++){
      v8s bh = *(const v8s*)&Bhi[wn + ni*16 + lcol][lq*8];
      v8s bl = *(const v8s*)&Blo[wn + ni*16 + lcol][lq*8];
      #pragma unroll
      for (int mi = 0; mi < 4; mi++){
        acc[mi][ni] = __builtin_amdgcn_mfma_f32_16x16x32_bf16(ah[mi], bh, acc[mi][ni], 0, 0, 0);
        acc[mi][ni] = __builtin_amdgcn_mfma_f32_16x16x32_bf16(al[mi], bh, acc[mi][ni], 0, 0, 0);
        acc[mi][ni] = __builtin_amdgcn_mfma_f32_16x16x32_bf16(ah[mi], bl, acc[mi][ni], 0, 0, 0);
      }
    }
    __syncthreads();
  }

  #pragma unroll
  for (int ni = 0; ni < 2; ni++){
    int n = n0 + wn + ni*16 + lcol;
    if (n >= N) continue;
    float bv = (ks == 1 || slice == 0) ? bias[n] : 0.f;
    #pragma unroll
    for (int mi = 0; mi < 4; mi++){
      int mbase = m0 + wm + mi*16 + lq*4;
      #pragma unroll
      for (int rg = 0; rg < 4; rg++){
        int m = mbase + rg;
        if (m >= M) continue;
        float v = acc[mi][ni][rg] + bv;
        if (ks == 1){
          if (act == 1) v = fmaxf(v, 0.f);
          else if (act == 2) v = 0.5f * v * (1.f + erff(v * 0.70710678118654752f));
          C[(size_t)m * ldc + n] = v;
        } else {
          atomicAdd(&C[(size_t)m * ldc + n], v);
        }
      }
    }
  }
}

// ---------------------------------------------------------------------------
// On-the-fly split GEMM (fallback when ws too small for pre-split weights).
// ---------------------------------------------------------------------------
__global__ __launch_bounds__(256, 2) void gemm_mfma_kernel(
    const float* __restrict__ A, const float* __restrict__ W,
    const float* __restrict__ bias, float* __restrict__ C,
    int M, int N, int K, int ldc, int act)
{
  __shared__ ushort_t Ahi[128][40];
  __shared__ ushort_t Alo[128][40];
  __shared__ ushort_t Bhi[128][40];
  __shared__ ushort_t Blo[128][40];

  const int tid = threadIdx.x;
  const int m0 = blockIdx.y * 128, n0 = blockIdx.x * 128;
  const int wave = tid >> 6, lane = tid & 63;
  const int wm = (wave >> 1) * 64, wn = (wave & 1) * 64;
  const int lcol = lane & 15, lq = lane >> 4;

  v4f acc[4][4];
  #pragma unroll
  for (int i = 0; i < 4; i++)
    #pragma unroll
    for (int j = 0; j < 4; j++) acc[i][j] = (v4f){0.f, 0.f, 0.f, 0.f};

  const int srow = tid >> 1;
  const int skh  = (tid & 1) * 16;

  for (int k0 = 0; k0 < K; k0 += 32){
    {
      float av[16];
      int m = m0 + srow;
      const float* ap = A + (size_t)m * K + k0 + skh;
      bool mok = (m < M);
      if (mok && (k0 + 32 <= K)){
        #pragma unroll
        for (int q = 0; q < 4; q++){
          float4 f = ((const float4*)ap)[q];
          av[q*4+0]=f.x; av[q*4+1]=f.y; av[q*4+2]=f.z; av[q*4+3]=f.w;
        }
      } else {
        #pragma unroll
        for (int e = 0; e < 16; e++){
          int k = k0 + skh + e;
          av[e] = (mok && k < K) ? ap[e] : 0.f;
        }
      }
      uint4 uh[2], ul[2];
      #pragma unroll
      for (int h = 0; h < 2; h++){
        unsigned hw[8], lw[8];
        #pragma unroll
        for (int e = 0; e < 8; e++){
          float x = av[h*8+e];
          unsigned u = __float_as_uint(x);
          float hf = __uint_as_float(u & 0xFFFF0000u);
          hw[e] = u >> 16;
          lw[e] = f2bu(x - hf);
        }
        uh[h] = make_uint4(hw[0]|(hw[1]<<16), hw[2]|(hw[3]<<16), hw[4]|(hw[5]<<16), hw[6]|(hw[7]<<16));
        ul[h] = make_uint4(lw[0]|(lw[1]<<16), lw[2]|(lw[3]<<16), lw[4]|(lw[5]<<16), lw[6]|(lw[7]<<16));
      }
      *(uint4*)&Ahi[srow][skh]     = uh[0];
      *(uint4*)&Ahi[srow][skh + 8] = uh[1];
      *(uint4*)&Alo[srow][skh]     = ul[0];
      *(uint4*)&Alo[srow][skh + 8] = ul[1];
    }
    {
      float bv[16];
      int n = n0 + srow;
      const float* bp = W + (size_t)n * K + k0 + skh;
      bool nok = (n < N);
      if (nok && (k0 + 32 <= K)){
        #pragma unroll
        for (int q = 0; q < 4; q++){
          float4 f = ((const float4*)bp)[q];
          bv[q*4+0]=f.x; bv[q*4+1]=f.y; bv[q*4+2]=f.z; bv[q*4+3]=f.w;
        }
      } else {
        #pragma unroll
        for (int e = 0; e < 16; e++){
          int k = k0 + skh + e;
          bv[e] = (nok && k < K) ? bp[e] : 0.f;
        }
      }
      uint4 uh[2], ul[2];
      #pragma unroll
      for (int h = 0; h < 2; h++){
        unsigned hw[8], lw[8];
        #pragma unroll
        for (int e = 0; e < 8; e++){
          float x = bv[h*8+e];
          unsigned u = __float_as_uint(x);
          float hf = __uint_as_float(u & 0xFFFF0000u);
          hw[e] = u >> 16;
          lw[e] = f2bu(x - hf);
        }
        uh[h] = make_uint4(hw[0]|(hw[1]<<16), hw[2]|(hw[3]<<16), hw[4]|(hw[5]<<16), hw[6]|(hw[7]<<16));
        ul[h] = make_uint4(lw[0]|(lw[1]<<16), lw[2]|(lw[3]<<16), lw[4]|(lw[5]<<16), lw[6]|(lw[7]<<16));
      }
      *(uint4*)&Bhi[srow][skh]     = uh[0];
      *(uint4*)&Bhi[srow][skh + 8] = uh[1];
      *(uint4*)&Blo[srow][skh]     = ul[0];
      *(uint4*)&Blo[srow][skh + 8] = ul[1];
    }
    __syncthreads();

    v8s ah[4], al[4];
    #pragma unroll
    for (int mi = 0; mi < 4; mi++){
      ah[mi] = *(const v8s*)&Ahi[wm + mi*16 + lcol][lq*8];
      al[mi] = *(const v8s*)&Alo[wm + mi*16 + lcol][lq*8];
    }
    #pragma unroll
    for (int ni = 0; ni < 4; ni++){
      v8s bh = *(const v8s*)&Bhi[wn + ni*16 + lcol][lq*8];
      v8s bl = *(const v8s*)&Blo[wn + ni*16 + lcol][lq*8];
      #pragma unroll
      for (int mi = 0; mi < 4; mi++){
        acc[mi][ni] = __builtin_amdgcn_mfma_f32_16x16x32_bf16(ah[mi], bh, acc[mi][ni], 0, 0, 0);
        acc[mi][ni] = __builtin_amdgcn_mfma_f32_16x16x32_bf16(al[mi], bh, acc[mi][ni], 0, 0, 0);
        acc[mi][ni] = __builtin_amdgcn_mfma_f32_16x16x32_bf16(ah[mi], bl, acc[mi][ni], 0, 0, 0);
      }
    }
    __syncthreads();
  }

  #pragma unroll
  for (int ni = 0; ni < 4; ni++){
    int n = n0 + wn + ni*16 + lcol;
    if (n >= N) continue;
    float bv = bias[n];
    #pragma unroll
    for (int mi = 0; mi < 4; mi++){
      int mbase = m0 + wm + mi*16 + lq*4;
      #pragma unroll
      for (int rg = 0; rg < 4; rg++){
        int m = mbase + rg;
        if (m >= M) continue;
        float v = acc[mi][ni][rg] + bv;
        if (act == 1) v = fmaxf(v, 0.f);
        else if (act == 2) v = 0.5f * v * (1.f + erff(v * 0.70710678118654752f));
        C[(size_t)m * ldc + n] = v;
      }
    }
  }
}

// ---------------------------------------------------------------------------
// f32 GEMM kept for tiny shapes (M=32).
// ---------------------------------------------------------------------------
__global__ __launch_bounds__(256) void gemm_kernel(
    const float* __restrict__ A, const float* __restrict__ W,
    const float* __restrict__ bias, float* __restrict__ C,
    int M, int N, int K, int act)
{
  __shared__ float As[16][64];
  __shared__ float Ws[16][64];
  const int tid = threadIdx.x;
  const int m0 = blockIdx.y * 64, n0 = blockIdx.x * 64;
  const int lr = tid >> 2;
  const int lk = (tid & 3) * 4;
  const int tx = tid & 15, ty = tid >> 4;
  float cc[4][4];
  #pragma unroll
  for (int i = 0; i < 4; i++)
    #pragma unroll
    for (int j = 0; j < 4; j++) cc[i][j] = 0.f;

  for (int k0 = 0; k0 < K; k0 += 16){
    #pragma unroll
    for (int i = 0; i < 4; i++){
      int k = k0 + lk + i;
      int m = m0 + lr;
      As[lk + i][lr] = (m < M && k < K) ? A[(size_t)m * K + k] : 0.f;
      int n = n0 + lr;
      Ws[lk + i][lr] = (n < N && k < K) ? W[(size_t)n * K + k] : 0.f;
    }
    __syncthreads();
    #pragma unroll
    for (int kk = 0; kk < 16; kk++){
      float4 a = *(const float4*)&As[kk][ty * 4];
      float4 b = *(const float4*)&Ws[kk][tx * 4];
      float av[4] = {a.x, a.y, a.z, a.w};
      float bv[4] = {b.x, b.y, b.z, b.w};
      #pragma unroll
      for (int i = 0; i < 4; i++)
        #pragma unroll
        for (int j = 0; j < 4; j++) cc[i][j] = fmaf(av[i], bv[j], cc[i][j]);
    }
    __syncthreads();
  }

  #pragma unroll
  for (int i = 0; i < 4; i++){
    int m = m0 + ty * 4 + i;
    if (m >= M) continue;
    #pragma unroll
    for (int j = 0; j < 4; j++){
      int n = n0 + tx * 4 + j;
      if (n >= N) continue;
      float v = cc[i][j] + bias[n];
      if (act == 1) v = fmaxf(v, 0.f);
      else if (act == 2) v = 0.5f * v * (1.f + erff(v * 0.70710678118654752f));
      C[(size_t)m * N + n] = v;
    }
  }
}

// ---------------------------------------------------------------------------
// LayerNorm over EMB=512.
// ---------------------------------------------------------------------------
__global__ __launch_bounds__(256) void ln_kernel(
    const float* __restrict__ X, const float* __restrict__ Res,
    const float* __restrict__ g, const float* __restrict__ bta,
    const float* __restrict__ pscale, const float* __restrict__ pbias,
    float* __restrict__ Y, int S, float eps)
{
  __shared__ float red[8];
  const int r = blockIdx.x, tid = threadIdx.x;
  size_t o0 = (size_t)r * EMB + tid;
  size_t o1 = o0 + 256;
  float v0 = X[o0] + (Res ? Res[o0] : 0.f);
  float v1 = X[o1] + (Res ? Res[o1] : 0.f);
  float tot = block_reduce(v0 + v1, red, 4, false);
  float mu = tot * (1.f / 512.f);
  float s0 = v0 - mu, s1 = v1 - mu;
  float var = block_reduce(s0 * s0 + s1 * s1, red, 4, false) * (1.f / 512.f);
  float rs = 1.f / sqrtf(var + eps);
  float y0 = s0 * rs, y1 = s1 * rs;
  if (g){
    y0 = y0 * g[tid] + bta[tid];
    y1 = y1 * g[tid + 256] + bta[tid + 256];
  }
  if (pscale){
    int b = r / S, t = r % S;
    size_t po = ((size_t)(b * 300 + t)) * EMB;
    y0 = y0 * pscale[po + tid] + pbias[po + tid];
    y1 = y1 * pscale[po + tid + 256] + pbias[po + tid + 256];
  }
  Y[o0] = y0;
  Y[o1] = y1;
}

// ---------------------------------------------------------------------------
// V column-mean per (b,h) (for fully-masked uniform-softmax rows).
// ---------------------------------------------------------------------------
__global__ __launch_bounds__(64) void vmean_kernel(const float* __restrict__ qkv,
                                                   float* __restrict__ vm, int S){
  int bh = blockIdx.x; int b = bh >> 3, h = bh & 7; int d = threadIdx.x;
  const float* vr = qkv + (size_t)(b * S) * 1536 + 1024 + h * DH + d;
  float s = 0.f;
  for (int j = 0; j < S; j++) s += vr[(size_t)j * 1536];
  vm[bh * DH + d] = s / (float)S;
}

// ---------------------------------------------------------------------------
// Masked attention, mask-structure-aware.
// ---------------------------------------------------------------------------
__global__ __launch_bounds__(64) void attn_kernel(
    const float* __restrict__ qkv, const float* __restrict__ vm,
    float* __restrict__ Ctx, int S)
{
  __shared__ float qv[DH];
  __shared__ float sc[SEQ];
  __shared__ float wts[16];
  const int tid = threadIdx.x;
  const int blk = blockIdx.x;
  const int i = blk % S;
  const int bh = blk / S;
  const int h = bh % HEADS;
  const int b = bh / HEADS;
  const size_t rowoff = ((size_t)(b * S + i)) * 1536 + h * DH;
  const size_t coff = ((size_t)(b * S + i)) * EMB + h * DH;
  const bool rowall = (i == 0) || (b == 0 && h >= 6);

  if (rowall){
    qv[tid] = qkv[rowoff + tid];
    __syncthreads();
    for (int j = tid; j < S; j += 64){
      const float* kr = qkv + ((size_t)(b * S + j)) * 1536 + 512 + h * DH;
      float d = 0.f;
      #pragma unroll
      for (int d4 = 0; d4 < 16; d4++){
        float4 kk = *(const float4*)(kr + d4 * 4);
        d = fmaf(qv[d4*4+0], kk.x, d);
        d = fmaf(qv[d4*4+1], kk.y, d);
        d = fmaf(qv[d4*4+2], kk.z, d);
        d = fmaf(qv[d4*4+3], kk.w, d);
      }
      sc[j] = d * 0.125f;
    }
    __syncthreads();
    float mx = -INFINITY;
    for (int j = tid; j < S; j += 64) mx = fmaxf(mx, sc[j]);
    #pragma unroll
    for (int o = 32; o > 0; o >>= 1) mx = fmaxf(mx, __shfl_down(mx, o, 64));
    mx = __shfl(mx, 0, 64);
    float sm = 0.f;
    for (int j = tid; j < S; j += 64){ float e = expf(sc[j] - mx); sc[j] = e; sm += e; }
    #pragma unroll
    for (int o = 32; o > 0; o >>= 1) sm += __shfl_down(sm, o, 64);
    sm = __shfl(sm, 0, 64);
    float inv = 1.f / sm;
    __syncthreads();
    float a_ = 0.f;
    const float* vr = qkv + ((size_t)(b * S)) * 1536 + 1024 + h * DH + tid;
    for (int j = 0; j < S; j++) a_ = fmaf(sc[j], vr[(size_t)j * 1536], a_);
    Ctx[coff + tid] = a_ * inv;
  } else if (h < 6){
    qv[tid] = qkv[rowoff + tid];
    __syncthreads();
    const int lo = max(0, i - 5), hi = min(S - 1, i + 4);
    const int cnt = hi - lo + 1;
    float s = -INFINITY;
    if (tid < cnt){
      const float* kr = qkv + ((size_t)(b * S + lo + tid)) * 1536 + 512 + h * DH;
      float d = 0.f;
      #pragma unroll
      for (int d4 = 0; d4 < 16; d4++){
        float4 kk = *(const float4*)(kr + d4 * 4);
        d = fmaf(qv[d4*4+0], kk.x, d);
        d = fmaf(qv[d4*4+1], kk.y, d);
        d = fmaf(qv[d4*4+2], kk.z, d);
        d = fmaf(qv[d4*4+3], kk.w, d);
      }
      s = d * 0.125f;
    }
    float mx = s;
    #pragma unroll
    for (int o = 8; o > 0; o >>= 1) mx = fmaxf(mx, __shfl_xor(mx, o, 16));
    float e = (tid < cnt) ? expf(s - mx) : 0.f;
    float sm = e;
    #pragma unroll
    for (int o = 8; o > 0; o >>= 1) sm += __shfl_xor(sm, o, 16);
    if (tid < 16) wts[tid] = e / sm;
    __syncthreads();
    float a_ = 0.f;
    const float* vr = qkv + ((size_t)(b * S + lo)) * 1536 + 1024 + h * DH + tid;
    for (int j = 0; j < cnt; j++) a_ = fmaf(wts[j], vr[(size_t)j * 1536], a_);
    Ctx[coff + tid] = a_;
  } else {
    Ctx[coff + tid] = vm[(b * HEADS + h) * DH + tid];
  }
}

// --------------------------- small utility kernels -------------------------
__global__ void buildx1_kernel(const float* __restrict__ base, float* __restrict__ x1){
  int idx = blockIdx.x * 256 + threadIdx.x;
  if (idx >= NB * 101 * EMB) return;
  int e = idx & 511;
  int bt = idx >> 9;
  int t = bt % 101, b = bt / 101;
  x1[idx] = (t == 0) ? 0.f : base[((size_t)(b * SEQ + t - 1)) * EMB + e];
}

__global__ void extract_kernel(const float* __restrict__ p2, float* __restrict__ clsE, float* __restrict__ tok){
  int idx = blockIdx.x * 256 + threadIdx.x;
  if (idx >= NB * 101 * NCLS) return;
  int n = idx % NCLS;
  int bt = idx / NCLS;
  int t = bt % 101, b = bt / 101;
  float v = p2[idx];
  if (t == 0) clsE[b * NCLS + n] = v;
  else tok[((size_t)(b * 100 + t - 1)) * NCLS + n] = v;
}

__global__ void zero_kernel(float* p){ if (threadIdx.x == 0) p[0] = 0.f; }

__global__ __launch_bounds__(256) void slhat_kernel(
    const float* __restrict__ P, const float* __restrict__ ls, float* __restrict__ SLh)
{
  int bm = blockIdx.x;
  int b = bm / NCLS, m = bm % NCLS;
  int n = threadIdx.x;
  if (n >= NCLS) return;
  const float* Pb = P + (size_t)b * 100 * NCLS;
  float s = 0.f;
  for (int t = 0; t < 100; t++) s = fmaf(Pb[t * NCLS + m], Pb[t * NCLS + n], s);
  SLh[((size_t)bm) * NCLS + n] = ls[m * NCLS + n] + 0.4f * s;
}

__global__ __launch_bounds__(256) void outIII_kernel(
    const float* __restrict__ cls3, const float* __restrict__ SLh, float* __restrict__ o3)
{
  int b = blockIdx.x, n = threadIdx.x;
  if (n >= NCLS) return;
  float s = 0.f;
  for (int m = 0; m < NCLS; m++)
    s = fmaf(cls3[b * NCLS + m], SLh[((size_t)(b * NCLS + m)) * NCLS + n], s);
  o3[b * NCLS + n] = s;
}

__global__ __launch_bounds__(256) void softmax_out_kernel(const float* __restrict__ X, float* __restrict__ O, int n){
  __shared__ float red[8];
  int r = blockIdx.x, tid = threadIdx.x;
  float mx = -INFINITY;
  for (int j = tid; j < n; j += 256) mx = fmaxf(mx, X[(size_t)r * n + j]);
  mx = block_reduce(mx, red, 4, true);
  float sm = 0.f;
  for (int j = tid; j < n; j += 256) sm += expf(X[(size_t)r * n + j] - mx);
  sm = block_reduce(sm, red, 4, false);
  for (int j = tid; j < n; j += 256) O[(size_t)r * n + j] = expf(X[(size_t)r * n + j] - mx) / sm;
}

__global__ __launch_bounds__(256) void normalize_kernel(
    const float* __restrict__ clsE, const float* __restrict__ u4,
    float* __restrict__ imn, float* __restrict__ sn)
{
  __shared__ float red[8];
  int r = blockIdx.x, tid = threadIdx.x;
  const float* s = (r < NB) ? (clsE + (size_t)r * NCLS) : (u4 + (size_t)(r - NB) * NCLS);
  float* d = (r < NB) ? (imn + (size_t)r * NCLS) : (sn + (size_t)(r - NB) * NCLS);
  float v = (tid < NCLS) ? s[tid] : 0.f;
  float ss = block_reduce(v * v, red, 4, false);
  float nrm = fmaxf(sqrtf(ss), 1e-12f);
  if (tid < NCLS) d[tid] = v / nrm;
}

__global__ __launch_bounds__(1024) void contrastive_kernel(
    const float* __restrict__ imn, const float* __restrict__ sn, float* __restrict__ out)
{
  __shared__ float sc[NB][NB];
  __shared__ float red[16];
  int tid = threadIdx.x;
  int i = tid >> 5, j = tid & 31;
  float d = 0.f;
  for (int c = 0; c < NCLS; c++) d = fmaf(imn[i * NCLS + c], sn[j * NCLS + c], d);
  sc[i][j] = d;
  __syncthreads();
  float di = sc[i][i], dj = sc[j][j];
  float v = 0.f;
  if (i != j)
    v = fmaxf(0.02f + sc[i][j] - di, 0.f) + fmaxf(0.02f + sc[i][j] - dj, 0.f);
  #pragma unroll
  for (int o = 32; o > 0; o >>= 1) v += __shfl_down(v, o, 64);
  if ((tid & 63) == 0) red[tid >> 6] = v;
  __syncthreads();
  if (tid == 0){
    float s = 0.f;
    for (int w = 0; w < 16; w++) s += red[w];
    out[13057] = s * 0.01f;
  }
}

// ---------------------------------------------------------------------------
// Two-stage means over rows of p1 (NCLS cols) and ap (EMB cols).
// ---------------------------------------------------------------------------
__global__ __launch_bounds__(256) void means_part_kernel(
    const float* __restrict__ p1, const float* __restrict__ ap,
    float* __restrict__ part)
{
  const int blk = blockIdx.x;
  const int bi = blk / MSEG, seg = blk % MSEG;
  const int b = bi >> 1, i = bi & 1;
  const int start = i;
  const int cnt = (i == 0) ? 100 : 199;
  const int per = (cnt + MSEG - 1) / MSEG;
  const int r0 = seg * per;
  const int r1 = min(r0 + per, cnt);
  float* dst = part + (size_t)blk * 720;
  for (int c = threadIdx.x; c < NCLS + EMB; c += 256){
    float s = 0.f;
    if (c < NCLS){
      for (int rr = r0; rr < r1; rr++)
        s += p1[((size_t)(b * SEQ + start + rr)) * NCLS + c];
    } else {
      int cc = c - NCLS;
      for (int rr = r0; rr < r1; rr++)
        s += ap[((size_t)(b * SEQ + start + rr)) * EMB + cc];
    }
    dst[c] = s;
  }
}

__global__ __launch_bounds__(256) void means_final_kernel(
    const float* __restrict__ part, float* __restrict__ mp, float* __restrict__ ma)
{
  const int bi = blockIdx.x;
  const int i = bi & 1;
  const float icnt = (i == 0) ? (1.f / 100.f) : (1.f / 199.f);
  for (int c = threadIdx.x; c < NCLS + EMB; c += 256){
    float s = 0.f;
    #pragma unroll
    for (int g = 0; g < MSEG; g++)
      s += part[((size_t)(bi * MSEG + g)) * 720 + c];
    if (c < NCLS) mp[(size_t)bi * NCLS + c] = s * icnt;
    else          ma[(size_t)bi * EMB + (c - NCLS)] = s * icnt;
  }
}

__global__ __launch_bounds__(64) void klfinal_kernel(
    const float* __restrict__ cbuf, const float* __restrict__ abuf, float* __restrict__ acc)
{
  const int b = blockIdx.x, lane = threadIdx.x;
  float rk[4], re[4];
  #pragma unroll
  for (int pr = 0; pr < 4; pr++){
    int i = pr >> 1, j = pr & 1;
    const float* c1 = cbuf + ((size_t)(b * 2 + i)) * NCLS;
    const float* c2 = cbuf + ((size_t)(b * 2 + j)) * NCLS;
    float s = 0.f;
    for (int n = lane; n < NCLS; n += 64){
      float x = c1[n] + 1e-6f, y = c2[n] + 1e-6f;
      s += x * logf(x / y);
    }
    #pragma unroll
    for (int o = 32; o > 0; o >>= 1) s += __shfl_down(s, o, 64);
    rk[pr] = __shfl(s, 0, 64);
    const float* a1 = abuf + ((size_t)(b * 2 + i)) * EMB;
    const float* a2 = abuf + ((size_t)(b * 2 + j)) * EMB;
    float s2 = 0.f;
    for (int n = lane; n < EMB; n += 64){
      float dd = a1[n] - a2[n];
      s2 += dd * dd;
    }
    #pragma unroll
    for (int o = 32; o > 0; o >>= 1) s2 += __shfl_down(s2, o, 64);
    re[pr] = sqrtf(__shfl(s2, 0, 64) + 1e-12f);
  }
  if (lane == 0){
    float sk[4], se[4];
    float mk = -INFINITY, me = -INFINITY;
    for (int p = 0; p < 4; p++){
      sk[p] = rk[p] * 10.f;
      mk = fmaxf(mk, sk[p]);
      se[p] = re[p];
      me = fmaxf(me, se[p]);
    }
    float ssk = 0.f, sse = 0.f;
    for (int p = 0; p < 4; p++){ sk[p] = expf(sk[p] - mk); ssk += sk[p]; se[p] = expf(se[p] - me); sse += se[p]; }
    float loss = 0.f;
    for (int p = 0; p < 4; p++){
      float x = sk[p] / ssk + 1e-6f, y = se[p] / sse + 1e-6f;
      loss += x * logf(x / y);
    }
    atomicAdd(acc, loss);
  }
}

__global__ void finalize_kernel(const float* __restrict__ acc, float* __restrict__ out){
  if (threadIdx.x == 0) out[13056] = acc[0] * (100000.f / 32.f);
}

// ---------------------------------------------------------------------------
extern "C" void kernel_launch(void* const* d_in, const int* in_sizes, int n_in,
                              void* d_out, int out_size, void* d_ws, size_t ws_size,
                              hipStream_t stream)
{
  (void)in_sizes; (void)n_in; (void)out_size;
  const int*   src  = (const int*)  d_in[0];
  const float* user_info = (const float*)d_in[1];
  const float* ls   = (const float*)d_in[2];
  const float* emb  = (const float*)d_in[3];
  const float* cw1  = (const float*)d_in[4];  const float* cb1 = (const float*)d_in[5];
  const float* cw2  = (const float*)d_in[6];  const float* cb2 = (const float*)d_in[7];
  const float* cw3  = (const float*)d_in[8];  const float* cb3 = (const float*)d_in[9];
  const float* tfw  = (const float*)d_in[10]; const float* tfb = (const float*)d_in[11];
  const float* wq   = (const float*)d_in[12]; const float* bq  = (const float*)d_in[13];
  const float* wk   = (const float*)d_in[14]; const float* bk  = (const float*)d_in[15];
  const float* wv   = (const float*)d_in[16]; const float* bv  = (const float*)d_in[17];
  const float* wo   = (const float*)d_in[18]; const float* bo  = (const float*)d_in[19];
  const float* l1g  = (const float*)d_in[20]; const float* l1b = (const float*)d_in[21];
  const float* fw1  = (const float*)d_in[22]; const float* fb1 = (const float*)d_in[23];
  const float* fw2  = (const float*)d_in[24]; const float* fb2 = (const float*)d_in[25];
  const float* l2g  = (const float*)d_in[26]; const float* l2b = (const float*)d_in[27];
  const float* fc1w = (const float*)d_in[28]; const float* fc1b= (const float*)d_in[29];
  const float* fc2w = (const float*)d_in[30]; const float* fc2b= (const float*)d_in[31];
  const float* fc3w = (const float*)d_in[32]; const float* fc3b= (const float*)d_in[33];
  const float* fc4w = (const float*)d_in[34]; const float* fc4b= (const float*)d_in[35];
  const float* pscale = (const float*)d_in[36];
  const float* pbias  = (const float*)d_in[37];
  float* out = (float*)d_out;
  float* ws = (float*)d_ws;

  size_t off = 0;
  auto alloc = [&](size_t n){ float* p = ws + off; off += ((n + 3) & ~(size_t)3); return p; };
  float* base = alloc(6400ULL * EMB);
  float* x1   = alloc((size_t)NB * 101 * EMB);
  float* qkv  = alloc(6400ULL * 1536);
  float* ctx  = alloc(6400ULL * EMB);
  float* proj = alloc(6400ULL * EMB);
  float* hb   = alloc(6400ULL * FFND);         // FFN buffer; reused as conv-chunk out + means partials
  float* p2   = alloc(6400ULL * NCLS);
  float* clsE = alloc((size_t)NB * NCLS);
  float* tok  = alloc(3200ULL * NCLS);
  float* Pb   = alloc(3200ULL * NCLS);
  float* cls3 = alloc((size_t)NB * NCLS);
  float* SLh  = alloc((size_t)NB * NCLS * NCLS);
  float* o3   = alloc((size_t)NB * NCLS);
  float* u4   = alloc((size_t)NB * NCLS);
  float* imn  = alloc((size_t)NB * NCLS);
  float* sn   = alloc((size_t)NB * NCLS);
  float* mp   = alloc(64ULL * NCLS);
  float* ma   = alloc(64ULL * EMB);
  float* cbf  = alloc(64ULL * NCLS);
  float* abf  = alloc(64ULL * EMB);
  float* lacc = alloc(4);
  float* vmb  = alloc((size_t)NB * HEADS * DH);
  ushort_t* Wb = (ushort_t*)alloc((size_t)VC * KD / 2);   // conv weights bf16
  float* tfwT = alloc(300ULL * EMB);
  float* bqkv = alloc(4ULL * 1536);
  // bf16 embedding table (20000x1024, 41 MB) ALIASES qkv+ctx: only live
  // during textcnn stage 1, which completes before any encoder kernel runs.
  ushort_t* embb = (ushort_t*)qkv;
  // pre-split encoder weights (bf16 hi/lo). Element offsets within each array:
  const size_t OQKV = 0, OWO = 3145728, OF1 = 4194304, OF2 = 8388608;
  const size_t OC1 = 12582912, OC2 = 12845056, OC3 = 12949504, WTOT = 12991120;
  ushort_t* WhiA = (ushort_t*)alloc((WTOT + 1) / 2);
  ushort_t* WloA = (ushort_t*)alloc((WTOT + 1) / 2);
  const bool presplit = (off * sizeof(float) <= ws_size);   // ~205 MB needed

  auto gemm_f32 = [&](const float* A, const float* W, const float* bi, float* C,
                      int M, int N, int K, int act){
    dim3 g((N + 63) / 64, (M + 63) / 64);
    gemm_kernel<<<g, 256, 0, stream>>>(A, W, bi, C, M, N, K, act);
  };
  auto gemm_fly = [&](const float* A, const float* W, const float* bi, float* C,
                      int M, int N, int K, int ldc, int act){
    dim3 g((N + 127) / 128, (M + 127) / 128);
    gemm_mfma_kernel<<<g, 256, 0, stream>>>(A, W, bi, C, M, N, K, ldc, act);
  };
  auto gemm_pre = [&](const float* A, size_t woff, const float* bi, float* C,
                      int M, int N, int K, int ldc, int act){
    int mt = (M + 127) / 128;
    if (N <= 512){
      int nt = (N + 63) / 64;
      int tiles = mt * nt;
      // split-K: only for act==0 (atomic accumulation can't fuse activation);
      // K-slice kept >=128 and total grid capped at 2048 blocks.
      int ks = 1;
      if (act == 0){
        while (ks < 8 && tiles * ks * 2 <= 2048 && K / (ks * 2) >= 128) ks *= 2;
      }
      if (ks > 1){
        size_t n4 = ((size_t)M * N) / 4;
        int zg = (int)min((n4 + 255) / 256, (size_t)2048);
        zerobuf_kernel<<<zg, 256, 0, stream>>>(C, n4);
      }
      gemm_mfma_pre64_kernel<<<tiles * ks, 256, 0, stream>>>(
          A, WhiA + woff, WloA + woff, bi, C, M, N, K, ldc, act, mt, nt, ks);
    } else {
      int nt = (N + 127) / 128;
      gemm_mfma_pre_kernel<<<mt * nt, 256, 0, stream>>>(
          A, WhiA + woff, WloA + woff, bi, C, M, N, K, ldc, act, mt, nt);
    }
  };
  auto split = [&](const float* srcw, size_t woff, int n){
    split_kernel<<<(n / 4 + 255) / 256, 256, 0, stream>>>(srcw, WhiA + woff, WloA + woff, n);
  };

  // Stage 0: weight prep (same work every call; graph-safe)
  prep_w_kernel<<<(VC * KD / 4 + 255) / 256, 256, 0, stream>>>(cw1, cw2, cw3, Wb);
  prep_embbf_kernel<<<(int)((20000ULL * KD / 4 + 255) / 256), 256, 0, stream>>>(emb, embb);
  prep_tfwT_kernel<<<(300 * EMB + 255) / 256, 256, 0, stream>>>(tfw, tfwT);
  if (presplit){
    for (int l = 0; l < NLAYERS; l++){
      split(wq + (size_t)l * 262144, OQKV + (size_t)l * 786432,          262144);
      split(wk + (size_t)l * 262144, OQKV + (size_t)l * 786432 + 262144, 262144);
      split(wv + (size_t)l * 262144, OQKV + (size_t)l * 786432 + 524288, 262144);
      split(wo + (size_t)l * 262144, OWO + (size_t)l * 262144, 262144);
      split(fw1 + (size_t)l * 1048576, OF1 + (size_t)l * 1048576, 1048576);
      split(fw2 + (size_t)l * 1048576, OF2 + (size_t)l * 1048576, 1048576);
    }
    split(fc1w, OC1, 262144);
    split(fc2w, OC2, NCLS * EMB);
    split(fc3w, OC3, NCLS * NCLS);
    qkvbias_kernel<<<4, 256, 0, stream>>>(bq, bk, bv, bqkv);
  }

  // Stage 1: textcnn = conv GEMM (chunked, reusing hb) + pool/FC/ln
  for (int c = 0; c < CCH; c++){
    conv_gemm_kernel<<<CT, 256, 0, stream>>>(
        src + (size_t)c * CM, embb, Wb, (ushort_t*)hb, CM);
    pool_fc_kernel<<<CROWS, 256, 0, stream>>>(
        (ushort_t*)hb, tfwT, cb1, cb2, cb3, tfb, base + (size_t)c * CROWS * EMB);
  }
  buildx1_kernel<<<(NB * 101 * EMB + 255) / 256, 256, 0, stream>>>(base, x1);

  auto encoder = [&](float* x, int S){
    int M = NB * S;
    for (int l = 0; l < NLAYERS; l++){
      if (presplit){
        gemm_pre(x, OQKV + (size_t)l * 786432, bqkv + l * 1536, qkv, M, 1536, EMB, 1536, 0);
      } else {
        gemm_fly(x, wq + (size_t)l * EMB * EMB, bq + l * EMB, qkv,        M, EMB, EMB, 1536, 0);
        gemm_fly(x, wk + (size_t)l * EMB * EMB, bk + l * EMB, qkv + 512,  M, EMB, EMB, 1536, 0);
        gemm_fly(x, wv + (size_t)l * EMB * EMB, bv + l * EMB, qkv + 1024, M, EMB, EMB, 1536, 0);
      }
      vmean_kernel<<<NB * HEADS, 64, 0, stream>>>(qkv, vmb, S);
      attn_kernel<<<NB * HEADS * S, 64, 0, stream>>>(qkv, vmb, ctx, S);
      if (presplit) gemm_pre(ctx, OWO + (size_t)l * 262144, bo + l * EMB, proj, M, EMB, EMB, EMB, 0);
      else gemm_fly(ctx, wo + (size_t)l * EMB * EMB, bo + l * EMB, proj, M, EMB, EMB, EMB, 0);
      ln_kernel<<<M, 256, 0, stream>>>(proj, x, l1g + l * EMB, l1b + l * EMB, nullptr, nullptr, x, S, 1e-5f);
      if (presplit) gemm_pre(x, OF1 + (size_t)l * 1048576, fb1 + l * FFND, hb, M, FFND, EMB, FFND, 1);
      else gemm_fly(x, fw1 + (size_t)l * FFND * EMB, fb1 + l * FFND, hb, M, FFND, EMB, FFND, 1);
      if (presplit) gemm_pre(hb, OF2 + (size_t)l * 1048576, fb2 + l * EMB, proj, M, EMB, FFND, EMB, 0);
      else gemm_fly(hb, fw2 + (size_t)l * EMB * FFND, fb2 + l * EMB, proj, M, EMB, FFND, EMB, 0);
      ln_kernel<<<M, 256, 0, stream>>>(proj, x, l2g + l * EMB, l2b + l * EMB, nullptr, nullptr, x, S, 1e-5f);
    }
    if (presplit) gemm_pre(x, OC1, fc1b, ctx, M, EMB, EMB, EMB, 2);
    else gemm_fly(x, fc1w, fc1b, ctx, M, EMB, EMB, EMB, 2);
    ln_kernel<<<M, 256, 0, stream>>>(ctx, nullptr, nullptr, nullptr, pscale, pbias, ctx, S, 1e-12f);
    if (presplit) gemm_pre(ctx, OC2, fc2b, p2, M, NCLS, EMB, NCLS, 0);
    else gemm_fly(ctx, fc2w, fc2b, p2, M, NCLS, EMB, NCLS, 0);
  };

  // Branch 1: S=101
  encoder(x1, 101);
  extract_kernel<<<(NB * 101 * NCLS + 255) / 256, 256, 0, stream>>>(p2, clsE, tok);
  if (presplit) gemm_pre(tok, OC3, fc3b, Pb, 3200, NCLS, NCLS, NCLS, 0);
  else gemm_fly(tok, fc3w, fc3b, Pb, 3200, NCLS, NCLS, NCLS, 0);
  gemm_f32(clsE, fc3w, fc3b, cls3, NB, NCLS, NCLS, 0);
  slhat_kernel<<<NB * NCLS, 256, 0, stream>>>(Pb, ls, SLh);
  outIII_kernel<<<NB, 256, 0, stream>>>(cls3, SLh, o3);
  softmax_out_kernel<<<NB, 256, 0, stream>>>(o3, out, NCLS);                    // output 0
  softmax_out_kernel<<<NB, 256, 0, stream>>>(clsE, out + NB * NCLS, NCLS);      // output 1
  gemm_f32(user_info, fc4w, fc4b, u4, NB, NCLS, 142, 0);
  normalize_kernel<<<64, 256, 0, stream>>>(clsE, u4, imn, sn);
  contrastive_kernel<<<1, 1024, 0, stream>>>(imn, sn, out);                     // output 3

  // Branch 2: S=200
  encoder(base, SEQ);
  zero_kernel<<<1, 64, 0, stream>>>(lacc);
  // two-stage means: partials into hb (free after encoder), then reduce
  means_part_kernel<<<64 * MSEG, 256, 0, stream>>>(p2, ctx, hb);
  means_final_kernel<<<64, 256, 0, stream>>>(hb, mp, ma);
  softmax_out_kernel<<<64, 256, 0, stream>>>(mp, cbf, NCLS);
  softmax_out_kernel<<<64, 256, 0, stream>>>(ma, abf, EMB);
  klfinal_kernel<<<NB, 64, 0, stream>>>(cbf, abf, lacc);
  finalize_kernel<<<1, 64, 0, stream>>>(lacc, out);                             // output 2
}

// Round 7
// 4967.605 us; speedup vs baseline: 1.0685x; 1.0685x over previous
//
#include <hip/hip_runtime.h>
#include <math.h>

#define EMB 512
#define HEADS 8
#define NLAYERS 4
#define NB 32
#define SEQ 200
#define TOKN 50
#define DH 64
#define FFND 2048
#define NCLS 204
#define VC 640          // virtual conv channels, padded (600 real)
#define KD 1024         // conv K dim
#define CCH 8           // conv row-chunks
#define CROWS (6400/CCH)        // 800 seq rows per chunk
#define CM (CROWS*TOKN)         // 40000 GEMM M-rows per chunk
#define MSEG 16                 // means two-stage row segments
#define CMT ((CM + 127) / 128)  // 313 m-tiles
#define CNT (VC / 128)          // 5 n-tiles
#define CT  (CMT * CNT)         // 1565 tiles

typedef __attribute__((ext_vector_type(8))) short v8s;
typedef __attribute__((ext_vector_type(4))) float v4f;
typedef unsigned short ushort_t;

__device__ __forceinline__ ushort_t f2bu(float f){  // f32 -> bf16 bits, RNE
  unsigned u = __float_as_uint(f);
  return (ushort_t)((u + 0x7FFFu + ((u >> 16) & 1u)) >> 16);
}
__device__ __forceinline__ float bu2f(ushort_t u){
  return __uint_as_float(((unsigned)u) << 16);
}

// bijective XCD-chunk swizzle (m204): orig dispatch id -> logical tile id,
// contiguous logical tiles per XCD.
__device__ __forceinline__ int xcd_swz(int lin, int nwg){
  int xcd = lin & 7, idx = lin >> 3;
  int q = nwg >> 3, r = nwg & 7;
  return ((xcd < r) ? xcd * (q + 1) : r * (q + 1) + (xcd - r) * q) + idx;
}

__device__ __forceinline__ float block_reduce(float v, float* red, int nwaves, bool domax){
  int tid = threadIdx.x;
  #pragma unroll
  for (int o = 32; o > 0; o >>= 1){
    float t = __shfl_down(v, o, 64);
    v = domax ? fmaxf(v, t) : (v + t);
  }
  __syncthreads();
  if ((tid & 63) == 0) red[tid >> 6] = v;
  __syncthreads();
  float r = red[0];
  for (int i = 1; i < nwaves; i++) r = domax ? fmaxf(r, red[i]) : (r + red[i]);
  return r;
}

// ---------------------------------------------------------------------------
// Prep kernels
// ---------------------------------------------------------------------------
__global__ void prep_w_kernel(const float* __restrict__ cw1, const float* __restrict__ cw2,
                              const float* __restrict__ cw3, ushort_t* __restrict__ Wb){
  int idx4 = blockIdx.x * 256 + threadIdx.x;
  if (idx4 >= VC * KD / 4) return;
  int row = idx4 >> 8;
  int k = (idx4 & 255) * 4;
  float4 v = make_float4(0.f, 0.f, 0.f, 0.f);
  const float* s = nullptr;
  if (row < 100)      s = cw1 + (size_t)row * KD;
  else if (row < 200) s = cw2 + (size_t)((row - 100) * 2 + 0) * KD;
  else if (row < 300) s = cw2 + (size_t)((row - 200) * 2 + 1) * KD;
  else if (row < 400) s = cw3 + (size_t)((row - 300) * 3 + 0) * KD;
  else if (row < 500) s = cw3 + (size_t)((row - 400) * 3 + 1) * KD;
  else if (row < 600) s = cw3 + (size_t)((row - 500) * 3 + 2) * KD;
  if (s) v = *(const float4*)(s + k);
  ushort4 o;
  o.x = f2bu(v.x); o.y = f2bu(v.y); o.z = f2bu(v.z); o.w = f2bu(v.w);
  *(ushort4*)(Wb + (size_t)row * KD + k) = o;
}

// emb f32 (20000 x 1024) -> bf16 RNE (same rounding the conv staging used)
__global__ void prep_embbf_kernel(const float* __restrict__ emb, ushort_t* __restrict__ embb){
  size_t i4 = ((size_t)blockIdx.x * 256 + threadIdx.x) * 4;
  if (i4 >= 20000ULL * KD) return;
  float4 f = *(const float4*)(emb + i4);
  ushort4 o;
  o.x = f2bu(f.x); o.y = f2bu(f.y); o.z = f2bu(f.z); o.w = f2bu(f.w);
  *(ushort4*)(embb + i4) = o;
}

__global__ void prep_tfwT_kernel(const float* __restrict__ tfw, float* __restrict__ tfwT){
  int idx = blockIdx.x * 256 + threadIdx.x;
  if (idx >= 300 * EMB) return;
  int j = idx >> 9, o = idx & 511;
  tfwT[(size_t)j * EMB + o] = tfw[(size_t)o * 300 + j];
}

// split f32 -> (hi bf16 trunc, lo bf16 RNE of remainder)
__global__ void split_kernel(const float* __restrict__ src, ushort_t* __restrict__ hi,
                             ushort_t* __restrict__ lo, int n){
  int i4 = (blockIdx.x * 256 + threadIdx.x) * 4;
  if (i4 >= n) return;
  float4 f = *(const float4*)(src + i4);
  float x[4] = {f.x, f.y, f.z, f.w};
  ushort4 h, l;
  ushort_t hh[4], ll[4];
  #pragma unroll
  for (int e = 0; e < 4; e++){
    unsigned u = __float_as_uint(x[e]);
    float hf = __uint_as_float(u & 0xFFFF0000u);
    hh[e] = (ushort_t)(u >> 16);
    ll[e] = f2bu(x[e] - hf);
  }
  h.x=hh[0]; h.y=hh[1]; h.z=hh[2]; h.w=hh[3];
  l.x=ll[0]; l.y=ll[1]; l.z=ll[2]; l.w=ll[3];
  *(ushort4*)(hi + i4) = h;
  *(ushort4*)(lo + i4) = l;
}

__global__ void qkvbias_kernel(const float* __restrict__ bq, const float* __restrict__ bk,
                               const float* __restrict__ bv, float* __restrict__ bqkv){
  int l = blockIdx.x;
  for (int j = threadIdx.x; j < 1536; j += 256){
    float v;
    if (j < 512) v = bq[l * 512 + j];
    else if (j < 1024) v = bk[l * 512 + j - 512];
    else v = bv[l * 512 + j - 1024];
    bqkv[l * 1536 + j] = v;
  }
}

// grid-stride float4 zero (for split-K accumulators)
__global__ __launch_bounds__(256) void zerobuf_kernel(float* __restrict__ p, size_t n4){
  size_t i = (size_t)blockIdx.x * 256 + threadIdx.x;
  size_t stride = (size_t)gridDim.x * 256;
  for (; i < n4; i += stride)
    ((float4*)p)[i] = make_float4(0.f, 0.f, 0.f, 0.f);
}

// ---------------------------------------------------------------------------
// Conv GEMM (textcnn stage 1): C[m][n] = Eb[m] . Wb[n], bf16 in/out, f32 acc.
// ---------------------------------------------------------------------------
__global__ __launch_bounds__(256, 4) void conv_gemm_kernel(
    const int* __restrict__ tok, const ushort_t* __restrict__ embb,
    const ushort_t* __restrict__ Wb, ushort_t* __restrict__ Cout, int Mc)
{
  __shared__ ushort_t Al[128][40];
  __shared__ ushort_t Bl[128][40];
  const int tid = threadIdx.x;
  const int t = xcd_swz(blockIdx.x, CT);
  const int n0 = (t % CNT) * 128;
  const int m0 = (t / CNT) * 128;
  const int wave = tid >> 6, lane = tid & 63;
  const int wm = (wave >> 1) * 64, wn = (wave & 1) * 64;
  const int lcol = lane & 15, lq = lane >> 4;

  v4f acc[4][4];
  #pragma unroll
  for (int i = 0; i < 4; i++)
    #pragma unroll
    for (int j = 0; j < 4; j++) acc[i][j] = (v4f){0.f, 0.f, 0.f, 0.f};

  const int srow = tid >> 1, skh = (tid & 1) * 16;
  const int am = m0 + srow;
  const ushort_t* aep = (am < Mc) ? (embb + (size_t)tok[am] * KD + skh) : nullptr;
  const ushort_t* bep = Wb + (size_t)(n0 + srow) * KD + skh;

  for (int k0 = 0; k0 < KD; k0 += 32){
    uint4 a0 = make_uint4(0,0,0,0), a1 = make_uint4(0,0,0,0);
    if (aep){
      a0 = *(const uint4*)(aep + k0);
      a1 = *(const uint4*)(aep + k0 + 8);
    }
    *(uint4*)&Al[srow][skh]     = a0;
    *(uint4*)&Al[srow][skh + 8] = a1;
    uint4 b0 = *(const uint4*)(bep + k0);
    uint4 b1 = *(const uint4*)(bep + k0 + 8);
    *(uint4*)&Bl[srow][skh]     = b0;
    *(uint4*)&Bl[srow][skh + 8] = b1;
    __syncthreads();

    v8s af[4];
    #pragma unroll
    for (int mi = 0; mi < 4; mi++)
      af[mi] = *(const v8s*)&Al[wm + mi*16 + lcol][lq*8];
    #pragma unroll
    for (int ni = 0; ni < 4; ni++){
      v8s bf = *(const v8s*)&Bl[wn + ni*16 + lcol][lq*8];
      #pragma unroll
      for (int mi = 0; mi < 4; mi++)
        acc[mi][ni] = __builtin_amdgcn_mfma_f32_16x16x32_bf16(af[mi], bf, acc[mi][ni], 0, 0, 0);
    }
    __syncthreads();
  }

  #pragma unroll
  for (int ni = 0; ni < 4; ni++){
    int n = n0 + wn + ni*16 + lcol;
    #pragma unroll
    for (int mi = 0; mi < 4; mi++){
      int mbase = m0 + wm + mi*16 + lq*4;
      #pragma unroll
      for (int rg = 0; rg < 4; rg++){
        int m = mbase + rg;
        if (m < Mc) Cout[(size_t)m * VC + n] = f2bu(acc[mi][ni][rg]);
      }
    }
  }
}

// ---------------------------------------------------------------------------
// Pool + FC + ln_free (textcnn stage 2): one block per seq row in chunk.
// ---------------------------------------------------------------------------
__global__ __launch_bounds__(256, 2) void pool_fc_kernel(
    const ushort_t* __restrict__ Cc, const float* __restrict__ tfwT,
    const float* __restrict__ cb1, const float* __restrict__ cb2,
    const float* __restrict__ cb3, const float* __restrict__ tfb,
    float* __restrict__ basep)
{
  __shared__ ushort_t Sg[VC][54];
  __shared__ float pooled[304];
  __shared__ float red[8];
  const int tid = threadIdx.x;
  const int r = blockIdx.x;

  const unsigned* cr = (const unsigned*)(Cc + (size_t)r * TOKN * VC);
  for (int p = 0; p < TOKN; p++){
    for (int t = tid; t < VC/2; t += 256){
      unsigned u = cr[p * (VC/2) + t];
      Sg[2*t][p]   = (ushort_t)(u & 0xFFFFu);
      Sg[2*t+1][p] = (ushort_t)(u >> 16);
    }
  }
  __syncthreads();

  for (int c = tid; c < 300; c += 256){
    float mv = -1e30f;
    if (c < 100){
      float bb = cb1[c];
      for (int p = 0; p < 50; p++) mv = fmaxf(mv, bu2f(Sg[c][p]) + bb);
    } else if (c < 200){
      int o = c - 100; float bb = cb2[o];
      for (int p = 0; p < 49; p++)
        mv = fmaxf(mv, bu2f(Sg[100 + o][p]) + bu2f(Sg[200 + o][p + 1]) + bb);
    } else {
      int o = c - 200; float bb = cb3[o];
      for (int p = 0; p < 48; p++)
        mv = fmaxf(mv, bu2f(Sg[300 + o][p]) + bu2f(Sg[400 + o][p + 1]) + bu2f(Sg[500 + o][p + 2]) + bb);
    }
    pooled[c] = fmaxf(mv, 0.f);
  }
  __syncthreads();

  float v0 = tfb[tid], v1 = tfb[tid + 256];
  for (int j = 0; j < 300; j++){
    float pj = pooled[j];
    v0 = fmaf(pj, tfwT[(size_t)j * EMB + tid], v0);
    v1 = fmaf(pj, tfwT[(size_t)j * EMB + tid + 256], v1);
  }
  float tot = block_reduce(v0 + v1, red, 4, false);
  float mu = tot * (1.f / 512.f);
  float s0 = v0 - mu, s1 = v1 - mu;
  float var = block_reduce(s0 * s0 + s1 * s1, red, 4, false) * (1.f / 512.f);
  float sc = sqrtf(1.f / (var + 1e-12f));
  basep[(size_t)r * EMB + tid] = s0 * sc;
  basep[(size_t)r * EMB + tid + 256] = s1 * sc;
}

// ---------------------------------------------------------------------------
// Split-bf16 MFMA GEMM, 128x128 tile, PRE-SPLIT weights, 1-D swizzled grid.
// ---------------------------------------------------------------------------
__global__ __launch_bounds__(256, 3) void gemm_mfma_pre_kernel(
    const float* __restrict__ A, const ushort_t* __restrict__ Whi,
    const ushort_t* __restrict__ Wlo, const float* __restrict__ bias,
    float* __restrict__ C, int M, int N, int K, int ldc, int act, int mt, int nt)
{
  __shared__ ushort_t Ahi[128][40];
  __shared__ ushort_t Alo[128][40];
  __shared__ ushort_t Bhi[128][40];
  __shared__ ushort_t Blo[128][40];

  const int tid = threadIdx.x;
  const int t = xcd_swz(blockIdx.x, mt * nt);
  const int n0 = (t % nt) * 128, m0 = (t / nt) * 128;
  const int wave = tid >> 6, lane = tid & 63;
  const int wm = (wave >> 1) * 64, wn = (wave & 1) * 64;
  const int lcol = lane & 15, lq = lane >> 4;

  v4f acc[4][4];
  #pragma unroll
  for (int i = 0; i < 4; i++)
    #pragma unroll
    for (int j = 0; j < 4; j++) acc[i][j] = (v4f){0.f, 0.f, 0.f, 0.f};

  const int srow = tid >> 1;
  const int skh  = (tid & 1) * 16;
  const int am = m0 + srow, bn = n0 + srow;
  const bool mok = (am < M), nok = (bn < N);
  const float* ap = A + (size_t)am * K + skh;
  const ushort_t* bph = Whi + (size_t)bn * K + skh;
  const ushort_t* bpl = Wlo + (size_t)bn * K + skh;

  for (int k0 = 0; k0 < K; k0 += 32){
    bool kfull = (k0 + 32 <= K);
    // ---- stage A (split on the fly) ----
    {
      float av[16];
      if (mok && kfull){
        #pragma unroll
        for (int q = 0; q < 4; q++){
          float4 f = *(const float4*)(ap + k0 + q*4);
          av[q*4+0]=f.x; av[q*4+1]=f.y; av[q*4+2]=f.z; av[q*4+3]=f.w;
        }
      } else {
        #pragma unroll
        for (int e = 0; e < 16; e++){
          int k = k0 + skh + e;
          av[e] = (mok && k < K) ? ap[k0 + e] : 0.f;
        }
      }
      uint4 uh[2], ul[2];
      #pragma unroll
      for (int h = 0; h < 2; h++){
        unsigned hw[8], lw[8];
        #pragma unroll
        for (int e = 0; e < 8; e++){
          float x = av[h*8+e];
          unsigned u = __float_as_uint(x);
          float hf = __uint_as_float(u & 0xFFFF0000u);
          hw[e] = u >> 16;
          lw[e] = f2bu(x - hf);
        }
        uh[h] = make_uint4(hw[0]|(hw[1]<<16), hw[2]|(hw[3]<<16), hw[4]|(hw[5]<<16), hw[6]|(hw[7]<<16));
        ul[h] = make_uint4(lw[0]|(lw[1]<<16), lw[2]|(lw[3]<<16), lw[4]|(lw[5]<<16), lw[6]|(lw[7]<<16));
      }
      *(uint4*)&Ahi[srow][skh]     = uh[0];
      *(uint4*)&Ahi[srow][skh + 8] = uh[1];
      *(uint4*)&Alo[srow][skh]     = ul[0];
      *(uint4*)&Alo[srow][skh + 8] = ul[1];
    }
    // ---- stage B (pre-split: plain copies) ----
    {
      uint4 h0 = make_uint4(0,0,0,0), h1 = h0, l0 = h0, l1 = h0;
      if (nok && kfull){
        h0 = *(const uint4*)(bph + k0);
        h1 = *(const uint4*)(bph + k0 + 8);
        l0 = *(const uint4*)(bpl + k0);
        l1 = *(const uint4*)(bpl + k0 + 8);
      } else if (nok){
        ushort_t he[16], le[16];
        #pragma unroll
        for (int e = 0; e < 16; e++){
          int k = k0 + skh + e;
          he[e] = (k < K) ? bph[k0 + e] : (ushort_t)0;
          le[e] = (k < K) ? bpl[k0 + e] : (ushort_t)0;
        }
        h0 = *(uint4*)&he[0]; h1 = *(uint4*)&he[8];
        l0 = *(uint4*)&le[0]; l1 = *(uint4*)&le[8];
      }
      *(uint4*)&Bhi[srow][skh]     = h0;
      *(uint4*)&Bhi[srow][skh + 8] = h1;
      *(uint4*)&Blo[srow][skh]     = l0;
      *(uint4*)&Blo[srow][skh + 8] = l1;
    }
    __syncthreads();

    v8s ah[4], al[4];
    #pragma unroll
    for (int mi = 0; mi < 4; mi++){
      ah[mi] = *(const v8s*)&Ahi[wm + mi*16 + lcol][lq*8];
      al[mi] = *(const v8s*)&Alo[wm + mi*16 + lcol][lq*8];
    }
    #pragma unroll
    for (int ni = 0; ni < 4; ni++){
      v8s bh = *(const v8s*)&Bhi[wn + ni*16 + lcol][lq*8];
      v8s bl = *(const v8s*)&Blo[wn + ni*16 + lcol][lq*8];
      #pragma unroll
      for (int mi = 0; mi < 4; mi++){
        acc[mi][ni] = __builtin_amdgcn_mfma_f32_16x16x32_bf16(ah[mi], bh, acc[mi][ni], 0, 0, 0);
        acc[mi][ni] = __builtin_amdgcn_mfma_f32_16x16x32_bf16(al[mi], bh, acc[mi][ni], 0, 0, 0);
        acc[mi][ni] = __builtin_amdgcn_mfma_f32_16x16x32_bf16(ah[mi], bl, acc[mi][ni], 0, 0, 0);
      }
    }
    __syncthreads();
  }

  #pragma unroll
  for (int ni = 0; ni < 4; ni++){
    int n = n0 + wn + ni*16 + lcol;
    if (n >= N) continue;
    float bv = bias[n];
    #pragma unroll
    for (int mi = 0; mi < 4; mi++){
      int mbase = m0 + wm + mi*16 + lq*4;
      #pragma unroll
      for (int rg = 0; rg < 4; rg++){
        int m = mbase + rg;
        if (m >= M) continue;
        float v = acc[mi][ni][rg] + bv;
        if (act == 1) v = fmaxf(v, 0.f);
        else if (act == 2) v = 0.5f * v * (1.f + erff(v * 0.70710678118654752f));
        C[(size_t)m * ldc + n] = v;
      }
    }
  }
}

// ---------------------------------------------------------------------------
// Split-bf16 MFMA GEMM, 128M x 64N tile, PRE-SPLIT weights, 1-D swizzled grid,
// optional split-K (ks slices accumulate into pre-zeroed C via atomicAdd;
// slice 0 folds the bias; host guarantees act==0 when ks>1).
// ---------------------------------------------------------------------------
__global__ __launch_bounds__(256, 4) void gemm_mfma_pre64_kernel(
    const float* __restrict__ A, const ushort_t* __restrict__ Whi,
    const ushort_t* __restrict__ Wlo, const float* __restrict__ bias,
    float* __restrict__ C, int M, int N, int K, int ldc, int act, int mt, int nt, int ks)
{
  __shared__ ushort_t Ahi[128][40];
  __shared__ ushort_t Alo[128][40];
  __shared__ ushort_t Bhi[64][40];
  __shared__ ushort_t Blo[64][40];

  const int tid = threadIdx.x;
  const int tiles = mt * nt;
  const int t_ = xcd_swz(blockIdx.x, tiles * ks);
  const int slice = t_ / tiles;
  const int t = t_ % tiles;
  const int n0 = (t % nt) * 64, m0 = (t / nt) * 128;
  // K-slice bounds (32-aligned)
  const int kstep = ((K + 31) / 32 + ks - 1) / ks;   // k-steps per slice
  const int kb = slice * kstep * 32;
  const int ke = min(K, kb + kstep * 32);
  if (kb >= ke) return;
  const int wave = tid >> 6, lane = tid & 63;
  const int wm = (wave >> 1) * 64, wn = (wave & 1) * 32;
  const int lcol = lane & 15, lq = lane >> 4;

  v4f acc[4][2];
  #pragma unroll
  for (int i = 0; i < 4; i++)
    #pragma unroll
    for (int j = 0; j < 2; j++) acc[i][j] = (v4f){0.f, 0.f, 0.f, 0.f};

  // A staging: 256 threads, row tid>>1, 16-elem half (tid&1)*16
  const int srow = tid >> 1;
  const int skh  = (tid & 1) * 16;
  const int am = m0 + srow;
  const bool mok = (am < M);
  const float* ap = A + (size_t)am * K + skh;
  // B staging: 256 threads, row tid>>2, 8-elem quarter (tid&3)*8
  const int brow = tid >> 2;
  const int bkq  = (tid & 3) * 8;
  const int bn = n0 + brow;
  const bool nok = (bn < N);
  const ushort_t* bph = Whi + (size_t)bn * K + bkq;
  const ushort_t* bpl = Wlo + (size_t)bn * K + bkq;

  for (int k0 = kb; k0 < ke; k0 += 32){
    bool kfull = (k0 + 32 <= K);
    // ---- stage A (split on the fly) ----
    {
      float av[16];
      if (mok && kfull){
        #pragma unroll
        for (int q = 0; q < 4; q++){
          float4 f = *(const float4*)(ap + k0 + q*4);
          av[q*4+0]=f.x; av[q*4+1]=f.y; av[q*4+2]=f.z; av[q*4+3]=f.w;
        }
      } else {
        #pragma unroll
        for (int e = 0; e < 16; e++){
          int k = k0 + skh + e;
          av[e] = (mok && k < K) ? ap[k0 + e] : 0.f;
        }
      }
      uint4 uh[2], ul[2];
      #pragma unroll
      for (int h = 0; h < 2; h++){
        unsigned hw[8], lw[8];
        #pragma unroll
        for (int e = 0; e < 8; e++){
          float x = av[h*8+e];
          unsigned u = __float_as_uint(x);
          float hf = __uint_as_float(u & 0xFFFF0000u);
          hw[e] = u >> 16;
          lw[e] = f2bu(x - hf);
        }
        uh[h] = make_uint4(hw[0]|(hw[1]<<16), hw[2]|(hw[3]<<16), hw[4]|(hw[5]<<16), hw[6]|(hw[7]<<16));
        ul[h] = make_uint4(lw[0]|(lw[1]<<16), lw[2]|(lw[3]<<16), lw[4]|(lw[5]<<16), lw[6]|(lw[7]<<16));
      }
      *(uint4*)&Ahi[srow][skh]     = uh[0];
      *(uint4*)&Ahi[srow][skh + 8] = uh[1];
      *(uint4*)&Alo[srow][skh]     = ul[0];
      *(uint4*)&Alo[srow][skh + 8] = ul[1];
    }
    // ---- stage B (pre-split: plain 8-elem copies) ----
    {
      uint4 h0 = make_uint4(0,0,0,0), l0 = h0;
      if (nok && kfull){
        h0 = *(const uint4*)(bph + k0);
        l0 = *(const uint4*)(bpl + k0);
      } else if (nok){
        ushort_t he[8], le[8];
        #pragma unroll
        for (int e = 0; e < 8; e++){
          int k = k0 + bkq + e;
          he[e] = (k < K) ? bph[k0 + e] : (ushort_t)0;
          le[e] = (k < K) ? bpl[k0 + e] : (ushort_t)0;
        }
        h0 = *(uint4*)&he[0];
        l0 = *(uint4*)&le[0];
      }
      *(uint4*)&Bhi[brow][bkq] = h0;
      *(uint4*)&Blo[brow][bkq] = l0;
    }
    __syncthreads();

    v8s ah[4], al[4];
    #pragma unroll
    for (int mi = 0; mi < 4; mi++){
      ah[mi] = *(const v8s*)&Ahi[wm + mi*16 + lcol][lq*8];
      al[mi] = *(const v8s*)&Alo[wm + mi*16 + lcol][lq*8];
    }
    #pragma unroll
    for (int ni = 0; ni < 2; ni++){
      v8s bh = *(const v8s*)&Bhi[wn + ni*16 + lcol][lq*8];
      v8s bl = *(const v8s*)&Blo[wn + ni*16 + lcol][lq*8];
      #pragma unroll
      for (int mi = 0; mi < 4; mi++){
        acc[mi][ni] = __builtin_amdgcn_mfma_f32_16x16x32_bf16(ah[mi], bh, acc[mi][ni], 0, 0, 0);
        acc[mi][ni] = __builtin_amdgcn_mfma_f32_16x16x32_bf16(al[mi], bh, acc[mi][ni], 0, 0, 0);
        acc[mi][ni] = __builtin_amdgcn_mfma_f32_16x16x32_bf16(ah[mi], bl, acc[mi][ni], 0, 0, 0);
      }
    }
    __syncthreads();
  }

  #pragma unroll
  for (int ni = 0; ni < 2; ni++){
    int n = n0 + wn + ni*16 + lcol;
    if (n >= N) continue;
    float bv = (ks == 1 || slice == 0) ? bias[n] : 0.f;
    #pragma unroll
    for (int mi = 0; mi < 4; mi++){
      int mbase = m0 + wm + mi*16 + lq*4;
      #pragma unroll
      for (int rg = 0; rg < 4; rg++){
        int m = mbase + rg;
        if (m >= M) continue;
        float v = acc[mi][ni][rg] + bv;
        if (ks == 1){
          if (act == 1) v = fmaxf(v, 0.f);
          else if (act == 2) v = 0.5f * v * (1.f + erff(v * 0.70710678118654752f));
          C[(size_t)m * ldc + n] = v;
        } else {
          atomicAdd(&C[(size_t)m * ldc + n], v);
        }
      }
    }
  }
}

// ---------------------------------------------------------------------------
// On-the-fly split GEMM (fallback when ws too small for pre-split weights).
// ---------------------------------------------------------------------------
__global__ __launch_bounds__(256, 2) void gemm_mfma_kernel(
    const float* __restrict__ A, const float* __restrict__ W,
    const float* __restrict__ bias, float* __restrict__ C,
    int M, int N, int K, int ldc, int act)
{
  __shared__ ushort_t Ahi[128][40];
  __shared__ ushort_t Alo[128][40];
  __shared__ ushort_t Bhi[128][40];
  __shared__ ushort_t Blo[128][40];

  const int tid = threadIdx.x;
  const int m0 = blockIdx.y * 128, n0 = blockIdx.x * 128;
  const int wave = tid >> 6, lane = tid & 63;
  const int wm = (wave >> 1) * 64, wn = (wave & 1) * 64;
  const int lcol = lane & 15, lq = lane >> 4;

  v4f acc[4][4];
  #pragma unroll
  for (int i = 0; i < 4; i++)
    #pragma unroll
    for (int j = 0; j < 4; j++) acc[i][j] = (v4f){0.f, 0.f, 0.f, 0.f};

  const int srow = tid >> 1;
  const int skh  = (tid & 1) * 16;

  for (int k0 = 0; k0 < K; k0 += 32){
    {
      float av[16];
      int m = m0 + srow;
      const float* ap = A + (size_t)m * K + k0 + skh;
      bool mok = (m < M);
      if (mok && (k0 + 32 <= K)){
        #pragma unroll
        for (int q = 0; q < 4; q++){
          float4 f = ((const float4*)ap)[q];
          av[q*4+0]=f.x; av[q*4+1]=f.y; av[q*4+2]=f.z; av[q*4+3]=f.w;
        }
      } else {
        #pragma unroll
        for (int e = 0; e < 16; e++){
          int k = k0 + skh + e;
          av[e] = (mok && k < K) ? ap[e] : 0.f;
        }
      }
      uint4 uh[2], ul[2];
      #pragma unroll
      for (int h = 0; h < 2; h++){
        unsigned hw[8], lw[8];
        #pragma unroll
        for (int e = 0; e < 8; e++){
          float x = av[h*8+e];
          unsigned u = __float_as_uint(x);
          float hf = __uint_as_float(u & 0xFFFF0000u);
          hw[e] = u >> 16;
          lw[e] = f2bu(x - hf);
        }
        uh[h] = make_uint4(hw[0]|(hw[1]<<16), hw[2]|(hw[3]<<16), hw[4]|(hw[5]<<16), hw[6]|(hw[7]<<16));
        ul[h] = make_uint4(lw[0]|(lw[1]<<16), lw[2]|(lw[3]<<16), lw[4]|(lw[5]<<16), lw[6]|(lw[7]<<16));
      }
      *(uint4*)&Ahi[srow][skh]     = uh[0];
      *(uint4*)&Ahi[srow][skh + 8] = uh[1];
      *(uint4*)&Alo[srow][skh]     = ul[0];
      *(uint4*)&Alo[srow][skh + 8] = ul[1];
    }
    {
      float bv[16];
      int n = n0 + srow;
      const float* bp = W + (size_t)n * K + k0 + skh;
      bool nok = (n < N);
      if (nok && (k0 + 32 <= K)){
        #pragma unroll
        for (int q = 0; q < 4; q++){
          float4 f = ((const float4*)bp)[q];
          bv[q*4+0]=f.x; bv[q*4+1]=f.y; bv[q*4+2]=f.z; bv[q*4+3]=f.w;
        }
      } else {
        #pragma unroll
        for (int e = 0; e < 16; e++){
          int k = k0 + skh + e;
          bv[e] = (nok && k < K) ? bp[e] : 0.f;
        }
      }
      uint4 uh[2], ul[2];
      #pragma unroll
      for (int h = 0; h < 2; h++){
        unsigned hw[8], lw[8];
        #pragma unroll
        for (int e = 0; e < 8; e++){
          float x = bv[h*8+e];
          unsigned u = __float_as_uint(x);
          float hf = __uint_as_float(u & 0xFFFF0000u);
          hw[e] = u >> 16;
          lw[e] = f2bu(x - hf);
        }
        uh[h] = make_uint4(hw[0]|(hw[1]<<16), hw[2]|(hw[3]<<16), hw[4]|(hw[5]<<16), hw[6]|(hw[7]<<16));
        ul[h] = make_uint4(lw[0]|(lw[1]<<16), lw[2]|(lw[3]<<16), lw[4]|(lw[5]<<16), lw[6]|(lw[7]<<16));
      }
      *(uint4*)&Bhi[srow][skh]     = uh[0];
      *(uint4*)&Bhi[srow][skh + 8] = uh[1];
      *(uint4*)&Blo[srow][skh]     = ul[0];
      *(uint4*)&Blo[srow][skh + 8] = ul[1];
    }
    __syncthreads();

    v8s ah[4], al[4];
    #pragma unroll
    for (int mi = 0; mi < 4; mi++){
      ah[mi] = *(const v8s*)&Ahi[wm + mi*16 + lcol][lq*8];
      al[mi] = *(const v8s*)&Alo[wm + mi*16 + lcol][lq*8];
    }
    #pragma unroll
    for (int ni = 0; ni < 4; ni++){
      v8s bh = *(const v8s*)&Bhi[wn + ni*16 + lcol][lq*8];
      v8s bl = *(const v8s*)&Blo[wn + ni*16 + lcol][lq*8];
      #pragma unroll
      for (int mi = 0; mi < 4; mi++){
        acc[mi][ni] = __builtin_amdgcn_mfma_f32_16x16x32_bf16(ah[mi], bh, acc[mi][ni], 0, 0, 0);
        acc[mi][ni] = __builtin_amdgcn_mfma_f32_16x16x32_bf16(al[mi], bh, acc[mi][ni], 0, 0, 0);
        acc[mi][ni] = __builtin_amdgcn_mfma_f32_16x16x32_bf16(ah[mi], bl, acc[mi][ni], 0, 0, 0);
      }
    }
    __syncthreads();
  }

  #pragma unroll
  for (int ni = 0; ni < 4; ni++){
    int n = n0 + wn + ni*16 + lcol;
    if (n >= N) continue;
    float bv = bias[n];
    #pragma unroll
    for (int mi = 0; mi < 4; mi++){
      int mbase = m0 + wm + mi*16 + lq*4;
      #pragma unroll
      for (int rg = 0; rg < 4; rg++){
        int m = mbase + rg;
        if (m >= M) continue;
        float v = acc[mi][ni][rg] + bv;
        if (act == 1) v = fmaxf(v, 0.f);
        else if (act == 2) v = 0.5f * v * (1.f + erff(v * 0.70710678118654752f));
        C[(size_t)m * ldc + n] = v;
      }
    }
  }
}

// ---------------------------------------------------------------------------
// f32 GEMM kept for tiny shapes (M=32).
// ---------------------------------------------------------------------------
__global__ __launch_bounds__(256) void gemm_kernel(
    const float* __restrict__ A, const float* __restrict__ W,
    const float* __restrict__ bias, float* __restrict__ C,
    int M, int N, int K, int act)
{
  __shared__ float As[16][64];
  __shared__ float Ws[16][64];
  const int tid = threadIdx.x;
  const int m0 = blockIdx.y * 64, n0 = blockIdx.x * 64;
  const int lr = tid >> 2;
  const int lk = (tid & 3) * 4;
  const int tx = tid & 15, ty = tid >> 4;
  float cc[4][4];
  #pragma unroll
  for (int i = 0; i < 4; i++)
    #pragma unroll
    for (int j = 0; j < 4; j++) cc[i][j] = 0.f;

  for (int k0 = 0; k0 < K; k0 += 16){
    #pragma unroll
    for (int i = 0; i < 4; i++){
      int k = k0 + lk + i;
      int m = m0 + lr;
      As[lk + i][lr] = (m < M && k < K) ? A[(size_t)m * K + k] : 0.f;
      int n = n0 + lr;
      Ws[lk + i][lr] = (n < N && k < K) ? W[(size_t)n * K + k] : 0.f;
    }
    __syncthreads();
    #pragma unroll
    for (int kk = 0; kk < 16; kk++){
      float4 a = *(const float4*)&As[kk][ty * 4];
      float4 b = *(const float4*)&Ws[kk][tx * 4];
      float av[4] = {a.x, a.y, a.z, a.w};
      float bv[4] = {b.x, b.y, b.z, b.w};
      #pragma unroll
      for (int i = 0; i < 4; i++)
        #pragma unroll
        for (int j = 0; j < 4; j++) cc[i][j] = fmaf(av[i], bv[j], cc[i][j]);
    }
    __syncthreads();
  }

  #pragma unroll
  for (int i = 0; i < 4; i++){
    int m = m0 + ty * 4 + i;
    if (m >= M) continue;
    #pragma unroll
    for (int j = 0; j < 4; j++){
      int n = n0 + tx * 4 + j;
      if (n >= N) continue;
      float v = cc[i][j] + bias[n];
      if (act == 1) v = fmaxf(v, 0.f);
      else if (act == 2) v = 0.5f * v * (1.f + erff(v * 0.70710678118654752f));
      C[(size_t)m * N + n] = v;
    }
  }
}

// ---------------------------------------------------------------------------
// LayerNorm over EMB=512.
// ---------------------------------------------------------------------------
__global__ __launch_bounds__(256) void ln_kernel(
    const float* __restrict__ X, const float* __restrict__ Res,
    const float* __restrict__ g, const float* __restrict__ bta,
    const float* __restrict__ pscale, const float* __restrict__ pbias,
    float* __restrict__ Y, int S, float eps)
{
  __shared__ float red[8];
  const int r = blockIdx.x, tid = threadIdx.x;
  size_t o0 = (size_t)r * EMB + tid;
  size_t o1 = o0 + 256;
  float v0 = X[o0] + (Res ? Res[o0] : 0.f);
  float v1 = X[o1] + (Res ? Res[o1] : 0.f);
  float tot = block_reduce(v0 + v1, red, 4, false);
  float mu = tot * (1.f / 512.f);
  float s0 = v0 - mu, s1 = v1 - mu;
  float var = block_reduce(s0 * s0 + s1 * s1, red, 4, false) * (1.f / 512.f);
  float rs = 1.f / sqrtf(var + eps);
  float y0 = s0 * rs, y1 = s1 * rs;
  if (g){
    y0 = y0 * g[tid] + bta[tid];
    y1 = y1 * g[tid + 256] + bta[tid + 256];
  }
  if (pscale){
    int b = r / S, t = r % S;
    size_t po = ((size_t)(b * 300 + t)) * EMB;
    y0 = y0 * pscale[po + tid] + pbias[po + tid];
    y1 = y1 * pscale[po + tid + 256] + pbias[po + tid + 256];
  }
  Y[o0] = y0;
  Y[o1] = y1;
}

// ---------------------------------------------------------------------------
// V column-mean per (b,h) (for fully-masked uniform-softmax rows).
// ---------------------------------------------------------------------------
__global__ __launch_bounds__(64) void vmean_kernel(const float* __restrict__ qkv,
                                                   float* __restrict__ vm, int S){
  int bh = blockIdx.x; int b = bh >> 3, h = bh & 7; int d = threadIdx.x;
  const float* vr = qkv + (size_t)(b * S) * 1536 + 1024 + h * DH + d;
  float s = 0.f;
  for (int j = 0; j < S; j++) s += vr[(size_t)j * 1536];
  vm[bh * DH + d] = s / (float)S;
}

// ---------------------------------------------------------------------------
// Attention, full rows only: i==0 (all b,h) plus b==0,h>=6 (all i>0).
// One wave per row; original serial-dot structure (rare rows).
// ---------------------------------------------------------------------------
__global__ __launch_bounds__(64) void attn_full_kernel(
    const float* __restrict__ qkv, float* __restrict__ Ctx, int S)
{
  __shared__ float qv[DH];
  __shared__ float sc[SEQ];
  const int tid = threadIdx.x;
  const int blk = blockIdx.x;
  int b, h, i;
  if (blk < NB * HEADS){ b = blk >> 3; h = blk & 7; i = 0; }
  else {
    int idx = blk - NB * HEADS;
    b = 0; h = 6 + idx / (S - 1); i = 1 + idx % (S - 1);
  }
  const size_t rowoff = ((size_t)(b * S + i)) * 1536 + h * DH;
  const size_t coff = ((size_t)(b * S + i)) * EMB + h * DH;

  qv[tid] = qkv[rowoff + tid];
  __syncthreads();
  for (int j = tid; j < S; j += 64){
    const float* kr = qkv + ((size_t)(b * S + j)) * 1536 + 512 + h * DH;
    float d = 0.f;
    #pragma unroll
    for (int d4 = 0; d4 < 16; d4++){
      float4 kk = *(const float4*)(kr + d4 * 4);
      d = fmaf(qv[d4*4+0], kk.x, d);
      d = fmaf(qv[d4*4+1], kk.y, d);
      d = fmaf(qv[d4*4+2], kk.z, d);
      d = fmaf(qv[d4*4+3], kk.w, d);
    }
    sc[j] = d * 0.125f;
  }
  __syncthreads();
  float mx = -INFINITY;
  for (int j = tid; j < S; j += 64) mx = fmaxf(mx, sc[j]);
  #pragma unroll
  for (int o = 32; o > 0; o >>= 1) mx = fmaxf(mx, __shfl_down(mx, o, 64));
  mx = __shfl(mx, 0, 64);
  float sm = 0.f;
  for (int j = tid; j < S; j += 64){ float e = expf(sc[j] - mx); sc[j] = e; sm += e; }
  #pragma unroll
  for (int o = 32; o > 0; o >>= 1) sm += __shfl_down(sm, o, 64);
  sm = __shfl(sm, 0, 64);
  float inv = 1.f / sm;
  __syncthreads();
  float a_ = 0.f;
  const float* vr = qkv + ((size_t)(b * S)) * 1536 + 1024 + h * DH + tid;
  for (int j = 0; j < S; j++) a_ = fmaf(sc[j], vr[(size_t)j * 1536], a_);
  Ctx[coff + tid] = a_ * inv;
}

// ---------------------------------------------------------------------------
// Attention, banded rows (h<6, i>0): band of <=10 keys around the diagonal.
// 4 waves/block, 1 row/wave, register-only (no LDS, no barriers): all 64
// lanes compute q*k partials, shfl_xor butterfly per band element, softmax
// over <=10 redundantly in registers, coalesced V accumulation.
// ---------------------------------------------------------------------------
__global__ __launch_bounds__(256) void attn_band_kernel(
    const float* __restrict__ qkv, float* __restrict__ Ctx, int S)
{
  const int rows = NB * 6 * (S - 1);
  const int r = blockIdx.x * 4 + (threadIdx.x >> 6);
  const int lane = threadIdx.x & 63;
  if (r >= rows) return;
  const int i = 1 + r % (S - 1);
  const int q_ = r / (S - 1);
  const int h = q_ % 6, b = q_ / 6;
  const float* base = qkv + (size_t)(b * S) * 1536;
  const float qd = base[(size_t)i * 1536 + h * DH + lane];
  const int lo = max(0, i - 5), hi = min(S - 1, i + 4);
  const int cnt = hi - lo + 1;

  float sc_r[10];
  #pragma unroll
  for (int jj = 0; jj < 10; jj++){
    float p = 0.f;
    if (jj < cnt) p = qd * base[(size_t)(lo + jj) * 1536 + 512 + h * DH + lane];
    #pragma unroll
    for (int o = 32; o > 0; o >>= 1) p += __shfl_xor(p, o, 64);
    sc_r[jj] = (jj < cnt) ? p * 0.125f : -INFINITY;
  }
  float mx = sc_r[0];
  #pragma unroll
  for (int jj = 1; jj < 10; jj++) mx = fmaxf(mx, sc_r[jj]);
  float sm = 0.f;
  #pragma unroll
  for (int jj = 0; jj < 10; jj++){ sc_r[jj] = expf(sc_r[jj] - mx); sm += sc_r[jj]; }
  const float inv = 1.f / sm;
  float a_ = 0.f;
  #pragma unroll
  for (int jj = 0; jj < 10; jj++){
    if (jj < cnt) a_ = fmaf(sc_r[jj], base[(size_t)(lo + jj) * 1536 + 1024 + h * DH + lane], a_);
  }
  Ctx[((size_t)(b * S + i)) * EMB + h * DH + lane] = a_ * inv;
}

// ---------------------------------------------------------------------------
// Fully-masked rows (h>=6, b>0, i>0): uniform softmax -> V column mean.
// ---------------------------------------------------------------------------
__global__ __launch_bounds__(256) void vmfill_kernel(
    const float* __restrict__ vm, float* __restrict__ Ctx, int S)
{
  const int total = (NB - 1) * 2 * (S - 1) * 64;
  int idx = blockIdx.x * 256 + threadIdx.x;
  if (idx >= total) return;
  const int d = idx & 63;
  int rest = idx >> 6;
  const int i = 1 + rest % (S - 1);
  rest /= (S - 1);
  const int h = 6 + (rest & 1);
  const int b = 1 + (rest >> 1);
  Ctx[((size_t)(b * S + i)) * EMB + h * DH + d] = vm[(b * HEADS + h) * DH + d];
}

// --------------------------- small utility kernels -------------------------
__global__ void buildx1_kernel(const float* __restrict__ base, float* __restrict__ x1){
  int idx = blockIdx.x * 256 + threadIdx.x;
  if (idx >= NB * 101 * EMB) return;
  int e = idx & 511;
  int bt = idx >> 9;
  int t = bt % 101, b = bt / 101;
  x1[idx] = (t == 0) ? 0.f : base[((size_t)(b * SEQ + t - 1)) * EMB + e];
}

__global__ void extract_kernel(const float* __restrict__ p2, float* __restrict__ clsE, float* __restrict__ tok){
  int idx = blockIdx.x * 256 + threadIdx.x;
  if (idx >= NB * 101 * NCLS) return;
  int n = idx % NCLS;
  int bt = idx / NCLS;
  int t = bt % 101, b = bt / 101;
  float v = p2[idx];
  if (t == 0) clsE[b * NCLS + n] = v;
  else tok[((size_t)(b * 100 + t - 1)) * NCLS + n] = v;
}

__global__ void zero_kernel(float* p){ if (threadIdx.x == 0) p[0] = 0.f; }

__global__ __launch_bounds__(256) void slhat_kernel(
    const float* __restrict__ P, const float* __restrict__ ls, float* __restrict__ SLh)
{
  int bm = blockIdx.x;
  int b = bm / NCLS, m = bm % NCLS;
  int n = threadIdx.x;
  if (n >= NCLS) return;
  const float* Pb = P + (size_t)b * 100 * NCLS;
  float s = 0.f;
  for (int t = 0; t < 100; t++) s = fmaf(Pb[t * NCLS + m], Pb[t * NCLS + n], s);
  SLh[((size_t)bm) * NCLS + n] = ls[m * NCLS + n] + 0.4f * s;
}

__global__ __launch_bounds__(256) void outIII_kernel(
    const float* __restrict__ cls3, const float* __restrict__ SLh, float* __restrict__ o3)
{
  int b = blockIdx.x, n = threadIdx.x;
  if (n >= NCLS) return;
  float s = 0.f;
  for (int m = 0; m < NCLS; m++)
    s = fmaf(cls3[b * NCLS + m], SLh[((size_t)(b * NCLS + m)) * NCLS + n], s);
  o3[b * NCLS + n] = s;
}

__global__ __launch_bounds__(256) void softmax_out_kernel(const float* __restrict__ X, float* __restrict__ O, int n){
  __shared__ float red[8];
  int r = blockIdx.x, tid = threadIdx.x;
  float mx = -INFINITY;
  for (int j = tid; j < n; j += 256) mx = fmaxf(mx, X[(size_t)r * n + j]);
  mx = block_reduce(mx, red, 4, true);
  float sm = 0.f;
  for (int j = tid; j < n; j += 256) sm += expf(X[(size_t)r * n + j] - mx);
  sm = block_reduce(sm, red, 4, false);
  for (int j = tid; j < n; j += 256) O[(size_t)r * n + j] = expf(X[(size_t)r * n + j] - mx) / sm;
}

__global__ __launch_bounds__(256) void normalize_kernel(
    const float* __restrict__ clsE, const float* __restrict__ u4,
    float* __restrict__ imn, float* __restrict__ sn)
{
  __shared__ float red[8];
  int r = blockIdx.x, tid = threadIdx.x;
  const float* s = (r < NB) ? (clsE + (size_t)r * NCLS) : (u4 + (size_t)(r - NB) * NCLS);
  float* d = (r < NB) ? (imn + (size_t)r * NCLS) : (sn + (size_t)(r - NB) * NCLS);
  float v = (tid < NCLS) ? s[tid] : 0.f;
  float ss = block_reduce(v * v, red, 4, false);
  float nrm = fmaxf(sqrtf(ss), 1e-12f);
  if (tid < NCLS) d[tid] = v / nrm;
}

__global__ __launch_bounds__(1024) void contrastive_kernel(
    const float* __restrict__ imn, const float* __restrict__ sn, float* __restrict__ out)
{
  __shared__ float sc[NB][NB];
  __shared__ float red[16];
  int tid = threadIdx.x;
  int i = tid >> 5, j = tid & 31;
  float d = 0.f;
  for (int c = 0; c < NCLS; c++) d = fmaf(imn[i * NCLS + c], sn[j * NCLS + c], d);
  sc[i][j] = d;
  __syncthreads();
  float di = sc[i][i], dj = sc[j][j];
  float v = 0.f;
  if (i != j)
    v = fmaxf(0.02f + sc[i][j] - di, 0.f) + fmaxf(0.02f + sc[i][j] - dj, 0.f);
  #pragma unroll
  for (int o = 32; o > 0; o >>= 1) v += __shfl_down(v, o, 64);
  if ((tid & 63) == 0) red[tid >> 6] = v;
  __syncthreads();
  if (tid == 0){
    float s = 0.f;
    for (int w = 0; w < 16; w++) s += red[w];
    out[13057] = s * 0.01f;
  }
}

// ---------------------------------------------------------------------------
// Two-stage means over rows of p1 (NCLS cols) and ap (EMB cols).
// ---------------------------------------------------------------------------
__global__ __launch_bounds__(256) void means_part_kernel(
    const float* __restrict__ p1, const float* __restrict__ ap,
    float* __restrict__ part)
{
  const int blk = blockIdx.x;
  const int bi = blk / MSEG, seg = blk % MSEG;
  const int b = bi >> 1, i = bi & 1;
  const int start = i;
  const int cnt = (i == 0) ? 100 : 199;
  const int per = (cnt + MSEG - 1) / MSEG;
  const int r0 = seg * per;
  const int r1 = min(r0 + per, cnt);
  float* dst = part + (size_t)blk * 720;
  for (int c = threadIdx.x; c < NCLS + EMB; c += 256){
    float s = 0.f;
    if (c < NCLS){
      for (int rr = r0; rr < r1; rr++)
        s += p1[((size_t)(b * SEQ + start + rr)) * NCLS + c];
    } else {
      int cc = c - NCLS;
      for (int rr = r0; rr < r1; rr++)
        s += ap[((size_t)(b * SEQ + start + rr)) * EMB + cc];
    }
    dst[c] = s;
  }
}

__global__ __launch_bounds__(256) void means_final_kernel(
    const float* __restrict__ part, float* __restrict__ mp, float* __restrict__ ma)
{
  const int bi = blockIdx.x;
  const int i = bi & 1;
  const float icnt = (i == 0) ? (1.f / 100.f) : (1.f / 199.f);
  for (int c = threadIdx.x; c < NCLS + EMB; c += 256){
    float s = 0.f;
    #pragma unroll
    for (int g = 0; g < MSEG; g++)
      s += part[((size_t)(bi * MSEG + g)) * 720 + c];
    if (c < NCLS) mp[(size_t)bi * NCLS + c] = s * icnt;
    else          ma[(size_t)bi * EMB + (c - NCLS)] = s * icnt;
  }
}

__global__ __launch_bounds__(64) void klfinal_kernel(
    const float* __restrict__ cbuf, const float* __restrict__ abuf, float* __restrict__ acc)
{
  const int b = blockIdx.x, lane = threadIdx.x;
  float rk[4], re[4];
  #pragma unroll
  for (int pr = 0; pr < 4; pr++){
    int i = pr >> 1, j = pr & 1;
    const float* c1 = cbuf + ((size_t)(b * 2 + i)) * NCLS;
    const float* c2 = cbuf + ((size_t)(b * 2 + j)) * NCLS;
    float s = 0.f;
    for (int n = lane; n < NCLS; n += 64){
      float x = c1[n] + 1e-6f, y = c2[n] + 1e-6f;
      s += x * logf(x / y);
    }
    #pragma unroll
    for (int o = 32; o > 0; o >>= 1) s += __shfl_down(s, o, 64);
    rk[pr] = __shfl(s, 0, 64);
    const float* a1 = abuf + ((size_t)(b * 2 + i)) * EMB;
    const float* a2 = abuf + ((size_t)(b * 2 + j)) * EMB;
    float s2 = 0.f;
    for (int n = lane; n < EMB; n += 64){
      float dd = a1[n] - a2[n];
      s2 += dd * dd;
    }
    #pragma unroll
    for (int o = 32; o > 0; o >>= 1) s2 += __shfl_down(s2, o, 64);
    re[pr] = sqrtf(__shfl(s2, 0, 64) + 1e-12f);
  }
  if (lane == 0){
    float sk[4], se[4];
    float mk = -INFINITY, me = -INFINITY;
    for (int p = 0; p < 4; p++){
      sk[p] = rk[p] * 10.f;
      mk = fmaxf(mk, sk[p]);
      se[p] = re[p];
      me = fmaxf(me, se[p]);
    }
    float ssk = 0.f, sse = 0.f;
    for (int p = 0; p < 4; p++){ sk[p] = expf(sk[p] - mk); ssk += sk[p]; se[p] = expf(se[p] - me); sse += se[p]; }
    float loss = 0.f;
    for (int p = 0; p < 4; p++){
      float x = sk[p] / ssk + 1e-6f, y = se[p] / sse + 1e-6f;
      loss += x * logf(x / y);
    }
    atomicAdd(acc, loss);
  }
}

__global__ void finalize_kernel(const float* __restrict__ acc, float* __restrict__ out){
  if (threadIdx.x == 0) out[13056] = acc[0] * (100000.f / 32.f);
}

// ---------------------------------------------------------------------------
extern "C" void kernel_launch(void* const* d_in, const int* in_sizes, int n_in,
                              void* d_out, int out_size, void* d_ws, size_t ws_size,
                              hipStream_t stream)
{
  (void)in_sizes; (void)n_in; (void)out_size;
  const int*   src  = (const int*)  d_in[0];
  const float* user_info = (const float*)d_in[1];
  const float* ls   = (const float*)d_in[2];
  const float* emb  = (const float*)d_in[3];
  const float* cw1  = (const float*)d_in[4];  const float* cb1 = (const float*)d_in[5];
  const float* cw2  = (const float*)d_in[6];  const float* cb2 = (const float*)d_in[7];
  const float* cw3  = (const float*)d_in[8];  const float* cb3 = (const float*)d_in[9];
  const float* tfw  = (const float*)d_in[10]; const float* tfb = (const float*)d_in[11];
  const float* wq   = (const float*)d_in[12]; const float* bq  = (const float*)d_in[13];
  const float* wk   = (const float*)d_in[14]; const float* bk  = (const float*)d_in[15];
  const float* wv   = (const float*)d_in[16]; const float* bv  = (const float*)d_in[17];
  const float* wo   = (const float*)d_in[18]; const float* bo  = (const float*)d_in[19];
  const float* l1g  = (const float*)d_in[20]; const float* l1b = (const float*)d_in[21];
  const float* fw1  = (const float*)d_in[22]; const float* fb1 = (const float*)d_in[23];
  const float* fw2  = (const float*)d_in[24]; const float* fb2 = (const float*)d_in[25];
  const float* l2g  = (const float*)d_in[26]; const float* l2b = (const float*)d_in[27];
  const float* fc1w = (const float*)d_in[28]; const float* fc1b= (const float*)d_in[29];
  const float* fc2w = (const float*)d_in[30]; const float* fc2b= (const float*)d_in[31];
  const float* fc3w = (const float*)d_in[32]; const float* fc3b= (const float*)d_in[33];
  const float* fc4w = (const float*)d_in[34]; const float* fc4b= (const float*)d_in[35];
  const float* pscale = (const float*)d_in[36];
  const float* pbias  = (const float*)d_in[37];
  float* out = (float*)d_out;
  float* ws = (float*)d_ws;

  size_t off = 0;
  auto alloc = [&](size_t n){ float* p = ws + off; off += ((n + 3) & ~(size_t)3); return p; };
  float* base = alloc(6400ULL * EMB);
  float* x1   = alloc((size_t)NB * 101 * EMB);
  float* qkv  = alloc(6400ULL * 1536);
  float* ctx  = alloc(6400ULL * EMB);
  float* proj = alloc(6400ULL * EMB);
  float* hb   = alloc(6400ULL * FFND);         // FFN buffer; reused as conv-chunk out + means partials
  float* p2   = alloc(6400ULL * NCLS);
  float* clsE = alloc((size_t)NB * NCLS);
  float* tok  = alloc(3200ULL * NCLS);
  float* Pb   = alloc(3200ULL * NCLS);
  float* cls3 = alloc((size_t)NB * NCLS);
  float* SLh  = alloc((size_t)NB * NCLS * NCLS);
  float* o3   = alloc((size_t)NB * NCLS);
  float* u4   = alloc((size_t)NB * NCLS);
  float* imn  = alloc((size_t)NB * NCLS);
  float* sn   = alloc((size_t)NB * NCLS);
  float* mp   = alloc(64ULL * NCLS);
  float* ma   = alloc(64ULL * EMB);
  float* cbf  = alloc(64ULL * NCLS);
  float* abf  = alloc(64ULL * EMB);
  float* lacc = alloc(4);
  float* vmb  = alloc((size_t)NB * HEADS * DH);
  ushort_t* Wb = (ushort_t*)alloc((size_t)VC * KD / 2);   // conv weights bf16
  float* tfwT = alloc(300ULL * EMB);
  float* bqkv = alloc(4ULL * 1536);
  // bf16 embedding table (20000x1024, 41 MB) ALIASES qkv+ctx: only live
  // during textcnn stage 1, which completes before any encoder kernel runs.
  ushort_t* embb = (ushort_t*)qkv;
  // pre-split encoder weights (bf16 hi/lo). Element offsets within each array:
  const size_t OQKV = 0, OWO = 3145728, OF1 = 4194304, OF2 = 8388608;
  const size_t OC1 = 12582912, OC2 = 12845056, OC3 = 12949504, WTOT = 12991120;
  ushort_t* WhiA = (ushort_t*)alloc((WTOT + 1) / 2);
  ushort_t* WloA = (ushort_t*)alloc((WTOT + 1) / 2);
  const bool presplit = (off * sizeof(float) <= ws_size);   // ~205 MB needed

  auto gemm_f32 = [&](const float* A, const float* W, const float* bi, float* C,
                      int M, int N, int K, int act){
    dim3 g((N + 63) / 64, (M + 63) / 64);
    gemm_kernel<<<g, 256, 0, stream>>>(A, W, bi, C, M, N, K, act);
  };
  auto gemm_fly = [&](const float* A, const float* W, const float* bi, float* C,
                      int M, int N, int K, int ldc, int act){
    dim3 g((N + 127) / 128, (M + 127) / 128);
    gemm_mfma_kernel<<<g, 256, 0, stream>>>(A, W, bi, C, M, N, K, ldc, act);
  };
  auto gemm_pre = [&](const float* A, size_t woff, const float* bi, float* C,
                      int M, int N, int K, int ldc, int act){
    int mt = (M + 127) / 128;
    if (N <= 512){
      int nt = (N + 63) / 64;
      int tiles = mt * nt;
      // split-K only for large-K bias-only GEMMs (FFN2): small-K split-K's
      // zero-pass + atomic RMW overhead outweighed its gain (round-5 A/B).
      int ks = 1;
      if (act == 0 && K >= 1024){
        while (ks < 8 && tiles * ks * 2 <= 2048 && K / (ks * 2) >= 128) ks *= 2;
      }
      if (ks > 1){
        size_t n4 = ((size_t)M * N) / 4;
        int zg = (int)min((n4 + 255) / 256, (size_t)2048);
        zerobuf_kernel<<<zg, 256, 0, stream>>>(C, n4);
      }
      gemm_mfma_pre64_kernel<<<tiles * ks, 256, 0, stream>>>(
          A, WhiA + woff, WloA + woff, bi, C, M, N, K, ldc, act, mt, nt, ks);
    } else {
      int nt = (N + 127) / 128;
      gemm_mfma_pre_kernel<<<mt * nt, 256, 0, stream>>>(
          A, WhiA + woff, WloA + woff, bi, C, M, N, K, ldc, act, mt, nt);
    }
  };
  auto split = [&](const float* srcw, size_t woff, int n){
    split_kernel<<<(n / 4 + 255) / 256, 256, 0, stream>>>(srcw, WhiA + woff, WloA + woff, n);
  };

  // Stage 0: weight prep (same work every call; graph-safe)
  prep_w_kernel<<<(VC * KD / 4 + 255) / 256, 256, 0, stream>>>(cw1, cw2, cw3, Wb);
  prep_embbf_kernel<<<(int)((20000ULL * KD / 4 + 255) / 256), 256, 0, stream>>>(emb, embb);
  prep_tfwT_kernel<<<(300 * EMB + 255) / 256, 256, 0, stream>>>(tfw, tfwT);
  if (presplit){
    for (int l = 0; l < NLAYERS; l++){
      split(wq + (size_t)l * 262144, OQKV + (size_t)l * 786432,          262144);
      split(wk + (size_t)l * 262144, OQKV + (size_t)l * 786432 + 262144, 262144);
      split(wv + (size_t)l * 262144, OQKV + (size_t)l * 786432 + 524288, 262144);
      split(wo + (size_t)l * 262144, OWO + (size_t)l * 262144, 262144);
      split(fw1 + (size_t)l * 1048576, OF1 + (size_t)l * 1048576, 1048576);
      split(fw2 + (size_t)l * 1048576, OF2 + (size_t)l * 1048576, 1048576);
    }
    split(fc1w, OC1, 262144);
    split(fc2w, OC2, NCLS * EMB);
    split(fc3w, OC3, NCLS * NCLS);
    qkvbias_kernel<<<4, 256, 0, stream>>>(bq, bk, bv, bqkv);
  }

  // Stage 1: textcnn = conv GEMM (chunked, reusing hb) + pool/FC/ln
  for (int c = 0; c < CCH; c++){
    conv_gemm_kernel<<<CT, 256, 0, stream>>>(
        src + (size_t)c * CM, embb, Wb, (ushort_t*)hb, CM);
    pool_fc_kernel<<<CROWS, 256, 0, stream>>>(
        (ushort_t*)hb, tfwT, cb1, cb2, cb3, tfb, base + (size_t)c * CROWS * EMB);
  }
  buildx1_kernel<<<(NB * 101 * EMB + 255) / 256, 256, 0, stream>>>(base, x1);

  auto encoder = [&](float* x, int S){
    int M = NB * S;
    for (int l = 0; l < NLAYERS; l++){
      if (presplit){
        gemm_pre(x, OQKV + (size_t)l * 786432, bqkv + l * 1536, qkv, M, 1536, EMB, 1536, 0);
      } else {
        gemm_fly(x, wq + (size_t)l * EMB * EMB, bq + l * EMB, qkv,        M, EMB, EMB, 1536, 0);
        gemm_fly(x, wk + (size_t)l * EMB * EMB, bk + l * EMB, qkv + 512,  M, EMB, EMB, 1536, 0);
        gemm_fly(x, wv + (size_t)l * EMB * EMB, bv + l * EMB, qkv + 1024, M, EMB, EMB, 1536, 0);
      }
      vmean_kernel<<<NB * HEADS, 64, 0, stream>>>(qkv, vmb, S);
      attn_full_kernel<<<NB * HEADS + 2 * (S - 1), 64, 0, stream>>>(qkv, ctx, S);
      attn_band_kernel<<<(NB * 6 * (S - 1) + 3) / 4, 256, 0, stream>>>(qkv, ctx, S);
      vmfill_kernel<<<((NB - 1) * 2 * (S - 1) * 64 + 255) / 256, 256, 0, stream>>>(vmb, ctx, S);
      if (presplit) gemm_pre(ctx, OWO + (size_t)l * 262144, bo + l * EMB, proj, M, EMB, EMB, EMB, 0);
      else gemm_fly(ctx, wo + (size_t)l * EMB * EMB, bo + l * EMB, proj, M, EMB, EMB, EMB, 0);
      ln_kernel<<<M, 256, 0, stream>>>(proj, x, l1g + l * EMB, l1b + l * EMB, nullptr, nullptr, x, S, 1e-5f);
      if (presplit) gemm_pre(x, OF1 + (size_t)l * 1048576, fb1 + l * FFND, hb, M, FFND, EMB, FFND, 1);
      else gemm_fly(x, fw1 + (size_t)l * FFND * EMB, fb1 + l * FFND, hb, M, FFND, EMB, FFND, 1);
      if (presplit) gemm_pre(hb, OF2 + (size_t)l * 1048576, fb2 + l * EMB, proj, M, EMB, FFND, EMB, 0);
      else gemm_fly(hb, fw2 + (size_t)l * EMB * FFND, fb2 + l * EMB, proj, M, EMB, FFND, EMB, 0);
      ln_kernel<<<M, 256, 0, stream>>>(proj, x, l2g + l * EMB, l2b + l * EMB, nullptr, nullptr, x, S, 1e-5f);
    }
    if (presplit) gemm_pre(x, OC1, fc1b, ctx, M, EMB, EMB, EMB, 2);
    else gemm_fly(x, fc1w, fc1b, ctx, M, EMB, EMB, EMB, 2);
    ln_kernel<<<M, 256, 0, stream>>>(ctx, nullptr, nullptr, nullptr, pscale, pbias, ctx, S, 1e-12f);
    if (presplit) gemm_pre(ctx, OC2, fc2b, p2, M, NCLS, EMB, NCLS, 0);
    else gemm_fly(ctx, fc2w, fc2b, p2, M, NCLS, EMB, NCLS, 0);
  };

  // Branch 1: S=101
  encoder(x1, 101);
  extract_kernel<<<(NB * 101 * NCLS + 255) / 256, 256, 0, stream>>>(p2, clsE, tok);
  if (presplit) gemm_pre(tok, OC3, fc3b, Pb, 3200, NCLS, NCLS, NCLS, 0);
  else gemm_fly(tok, fc3w, fc3b, Pb, 3200, NCLS, NCLS, NCLS, 0);
  gemm_f32(clsE, fc3w, fc3b, cls3, NB, NCLS, NCLS, 0);
  slhat_kernel<<<NB * NCLS, 256, 0, stream>>>(Pb, ls, SLh);
  outIII_kernel<<<NB, 256, 0, stream>>>(cls3, SLh, o3);
  softmax_out_kernel<<<NB, 256, 0, stream>>>(o3, out, NCLS);                    // output 0
  softmax_out_kernel<<<NB, 256, 0, stream>>>(clsE, out + NB * NCLS, NCLS);      // output 1
  gemm_f32(user_info, fc4w, fc4b, u4, NB, NCLS, 142, 0);
  normalize_kernel<<<64, 256, 0, stream>>>(clsE, u4, imn, sn);
  contrastive_kernel<<<1, 1024, 0, stream>>>(imn, sn, out);                     // output 3

  // Branch 2: S=200
  encoder(base, SEQ);
  zero_kernel<<<1, 64, 0, stream>>>(lacc);
  // two-stage means: partials into hb (free after encoder), then reduce
  means_part_kernel<<<64 * MSEG, 256, 0, stream>>>(p2, ctx, hb);
  means_final_kernel<<<64, 256, 0, stream>>>(hb, mp, ma);
  softmax_out_kernel<<<64, 256, 0, stream>>>(mp, cbf, NCLS);
  softmax_out_kernel<<<64, 256, 0, stream>>>(ma, abf, EMB);
  klfinal_kernel<<<NB, 64, 0, stream>>>(cbf, abf, lacc);
  finalize_kernel<<<1, 64, 0, stream>>>(lacc, out);                             // output 2
}

// Round 8
// 4949.341 us; speedup vs baseline: 1.0725x; 1.0037x over previous
//
#include <hip/hip_runtime.h>
#include <math.h>

#define EMB 512
#define HEADS 8
#define NLAYERS 4
#define NB 32
#define SEQ 200
#define TOKN 50
#define DH 64
#define FFND 2048
#define NCLS 204
#define VC 640          // virtual conv channels, padded (600 real)
#define KD 1024         // conv K dim
#define CCH 8           // conv row-chunks
#define CROWS (6400/CCH)        // 800 seq rows per chunk
#define CM (CROWS*TOKN)         // 40000 GEMM M-rows per chunk
#define MSEG 16                 // means two-stage row segments
#define CMT ((CM + 127) / 128)  // 313 m-tiles
#define CNT (VC / 128)          // 5 n-tiles
#define CT  (CMT * CNT)         // 1565 tiles

typedef __attribute__((ext_vector_type(8))) short v8s;
typedef __attribute__((ext_vector_type(4))) float v4f;
typedef unsigned short ushort_t;

__device__ __forceinline__ ushort_t f2bu(float f){  // f32 -> bf16 bits, RNE
  unsigned u = __float_as_uint(f);
  return (ushort_t)((u + 0x7FFFu + ((u >> 16) & 1u)) >> 16);
}
__device__ __forceinline__ float bu2f(ushort_t u){
  return __uint_as_float(((unsigned)u) << 16);
}

// bijective XCD-chunk swizzle (m204): orig dispatch id -> logical tile id,
// contiguous logical tiles per XCD.
__device__ __forceinline__ int xcd_swz(int lin, int nwg){
  int xcd = lin & 7, idx = lin >> 3;
  int q = nwg >> 3, r = nwg & 7;
  return ((xcd < r) ? xcd * (q + 1) : r * (q + 1) + (xcd - r) * q) + idx;
}

__device__ __forceinline__ float block_reduce(float v, float* red, int nwaves, bool domax){
  int tid = threadIdx.x;
  #pragma unroll
  for (int o = 32; o > 0; o >>= 1){
    float t = __shfl_down(v, o, 64);
    v = domax ? fmaxf(v, t) : (v + t);
  }
  __syncthreads();
  if ((tid & 63) == 0) red[tid >> 6] = v;
  __syncthreads();
  float r = red[0];
  for (int i = 1; i < nwaves; i++) r = domax ? fmaxf(r, red[i]) : (r + red[i]);
  return r;
}

// ---------------------------------------------------------------------------
// Prep kernels
// ---------------------------------------------------------------------------
__global__ void prep_w_kernel(const float* __restrict__ cw1, const float* __restrict__ cw2,
                              const float* __restrict__ cw3, ushort_t* __restrict__ Wb){
  int idx4 = blockIdx.x * 256 + threadIdx.x;
  if (idx4 >= VC * KD / 4) return;
  int row = idx4 >> 8;
  int k = (idx4 & 255) * 4;
  float4 v = make_float4(0.f, 0.f, 0.f, 0.f);
  const float* s = nullptr;
  if (row < 100)      s = cw1 + (size_t)row * KD;
  else if (row < 200) s = cw2 + (size_t)((row - 100) * 2 + 0) * KD;
  else if (row < 300) s = cw2 + (size_t)((row - 200) * 2 + 1) * KD;
  else if (row < 400) s = cw3 + (size_t)((row - 300) * 3 + 0) * KD;
  else if (row < 500) s = cw3 + (size_t)((row - 400) * 3 + 1) * KD;
  else if (row < 600) s = cw3 + (size_t)((row - 500) * 3 + 2) * KD;
  if (s) v = *(const float4*)(s + k);
  ushort4 o;
  o.x = f2bu(v.x); o.y = f2bu(v.y); o.z = f2bu(v.z); o.w = f2bu(v.w);
  *(ushort4*)(Wb + (size_t)row * KD + k) = o;
}

// emb f32 (20000 x 1024) -> bf16 RNE (same rounding the conv staging used)
__global__ void prep_embbf_kernel(const float* __restrict__ emb, ushort_t* __restrict__ embb){
  size_t i4 = ((size_t)blockIdx.x * 256 + threadIdx.x) * 4;
  if (i4 >= 20000ULL * KD) return;
  float4 f = *(const float4*)(emb + i4);
  ushort4 o;
  o.x = f2bu(f.x); o.y = f2bu(f.y); o.z = f2bu(f.z); o.w = f2bu(f.w);
  *(ushort4*)(embb + i4) = o;
}

__global__ void prep_tfwT_kernel(const float* __restrict__ tfw, float* __restrict__ tfwT){
  int idx = blockIdx.x * 256 + threadIdx.x;
  if (idx >= 300 * EMB) return;
  int j = idx >> 9, o = idx & 511;
  tfwT[(size_t)j * EMB + o] = tfw[(size_t)o * 300 + j];
}

// split f32 -> (hi bf16 trunc, lo bf16 RNE of remainder)
__global__ void split_kernel(const float* __restrict__ src, ushort_t* __restrict__ hi,
                             ushort_t* __restrict__ lo, int n){
  int i4 = (blockIdx.x * 256 + threadIdx.x) * 4;
  if (i4 >= n) return;
  float4 f = *(const float4*)(src + i4);
  float x[4] = {f.x, f.y, f.z, f.w};
  ushort4 h, l;
  ushort_t hh[4], ll[4];
  #pragma unroll
  for (int e = 0; e < 4; e++){
    unsigned u = __float_as_uint(x[e]);
    float hf = __uint_as_float(u & 0xFFFF0000u);
    hh[e] = (ushort_t)(u >> 16);
    ll[e] = f2bu(x[e] - hf);
  }
  h.x=hh[0]; h.y=hh[1]; h.z=hh[2]; h.w=hh[3];
  l.x=ll[0]; l.y=ll[1]; l.z=ll[2]; l.w=ll[3];
  *(ushort4*)(hi + i4) = h;
  *(ushort4*)(lo + i4) = l;
}

__global__ void qkvbias_kernel(const float* __restrict__ bq, const float* __restrict__ bk,
                               const float* __restrict__ bv, float* __restrict__ bqkv){
  int l = blockIdx.x;
  for (int j = threadIdx.x; j < 1536; j += 256){
    float v;
    if (j < 512) v = bq[l * 512 + j];
    else if (j < 1024) v = bk[l * 512 + j - 512];
    else v = bv[l * 512 + j - 1024];
    bqkv[l * 1536 + j] = v;
  }
}

// grid-stride float4 zero (for split-K accumulators)
__global__ __launch_bounds__(256) void zerobuf_kernel(float* __restrict__ p, size_t n4){
  size_t i = (size_t)blockIdx.x * 256 + threadIdx.x;
  size_t stride = (size_t)gridDim.x * 256;
  for (; i < n4; i += stride)
    ((float4*)p)[i] = make_float4(0.f, 0.f, 0.f, 0.f);
}

// ---------------------------------------------------------------------------
// Conv GEMM (textcnn stage 1): C[m][n] = Eb[m] . Wb[n], bf16 in/out, f32 acc.
// ---------------------------------------------------------------------------
__global__ __launch_bounds__(256, 4) void conv_gemm_kernel(
    const int* __restrict__ tok, const ushort_t* __restrict__ embb,
    const ushort_t* __restrict__ Wb, ushort_t* __restrict__ Cout, int Mc)
{
  __shared__ ushort_t Al[128][40];
  __shared__ ushort_t Bl[128][40];
  const int tid = threadIdx.x;
  const int t = xcd_swz(blockIdx.x, CT);
  const int n0 = (t % CNT) * 128;
  const int m0 = (t / CNT) * 128;
  const int wave = tid >> 6, lane = tid & 63;
  const int wm = (wave >> 1) * 64, wn = (wave & 1) * 64;
  const int lcol = lane & 15, lq = lane >> 4;

  v4f acc[4][4];
  #pragma unroll
  for (int i = 0; i < 4; i++)
    #pragma unroll
    for (int j = 0; j < 4; j++) acc[i][j] = (v4f){0.f, 0.f, 0.f, 0.f};

  const int srow = tid >> 1, skh = (tid & 1) * 16;
  const int am = m0 + srow;
  const ushort_t* aep = (am < Mc) ? (embb + (size_t)tok[am] * KD + skh) : nullptr;
  const ushort_t* bep = Wb + (size_t)(n0 + srow) * KD + skh;

  for (int k0 = 0; k0 < KD; k0 += 32){
    uint4 a0 = make_uint4(0,0,0,0), a1 = make_uint4(0,0,0,0);
    if (aep){
      a0 = *(const uint4*)(aep + k0);
      a1 = *(const uint4*)(aep + k0 + 8);
    }
    *(uint4*)&Al[srow][skh]     = a0;
    *(uint4*)&Al[srow][skh + 8] = a1;
    uint4 b0 = *(const uint4*)(bep + k0);
    uint4 b1 = *(const uint4*)(bep + k0 + 8);
    *(uint4*)&Bl[srow][skh]     = b0;
    *(uint4*)&Bl[srow][skh + 8] = b1;
    __syncthreads();

    v8s af[4];
    #pragma unroll
    for (int mi = 0; mi < 4; mi++)
      af[mi] = *(const v8s*)&Al[wm + mi*16 + lcol][lq*8];
    #pragma unroll
    for (int ni = 0; ni < 4; ni++){
      v8s bf = *(const v8s*)&Bl[wn + ni*16 + lcol][lq*8];
      #pragma unroll
      for (int mi = 0; mi < 4; mi++)
        acc[mi][ni] = __builtin_amdgcn_mfma_f32_16x16x32_bf16(af[mi], bf, acc[mi][ni], 0, 0, 0);
    }
    __syncthreads();
  }

  #pragma unroll
  for (int ni = 0; ni < 4; ni++){
    int n = n0 + wn + ni*16 + lcol;
    #pragma unroll
    for (int mi = 0; mi < 4; mi++){
      int mbase = m0 + wm + mi*16 + lq*4;
      #pragma unroll
      for (int rg = 0; rg < 4; rg++){
        int m = mbase + rg;
        if (m < Mc) Cout[(size_t)m * VC + n] = f2bu(acc[mi][ni][rg]);
      }
    }
  }
}

// ---------------------------------------------------------------------------
// Pool + FC + ln_free (textcnn stage 2): one block per seq row in chunk.
// ---------------------------------------------------------------------------
__global__ __launch_bounds__(256, 2) void pool_fc_kernel(
    const ushort_t* __restrict__ Cc, const float* __restrict__ tfwT,
    const float* __restrict__ cb1, const float* __restrict__ cb2,
    const float* __restrict__ cb3, const float* __restrict__ tfb,
    float* __restrict__ basep)
{
  __shared__ ushort_t Sg[VC][54];
  __shared__ float pooled[304];
  __shared__ float red[8];
  const int tid = threadIdx.x;
  const int r = blockIdx.x;

  const unsigned* cr = (const unsigned*)(Cc + (size_t)r * TOKN * VC);
  for (int p = 0; p < TOKN; p++){
    for (int t = tid; t < VC/2; t += 256){
      unsigned u = cr[p * (VC/2) + t];
      Sg[2*t][p]   = (ushort_t)(u & 0xFFFFu);
      Sg[2*t+1][p] = (ushort_t)(u >> 16);
    }
  }
  __syncthreads();

  for (int c = tid; c < 300; c += 256){
    float mv = -1e30f;
    if (c < 100){
      float bb = cb1[c];
      for (int p = 0; p < 50; p++) mv = fmaxf(mv, bu2f(Sg[c][p]) + bb);
    } else if (c < 200){
      int o = c - 100; float bb = cb2[o];
      for (int p = 0; p < 49; p++)
        mv = fmaxf(mv, bu2f(Sg[100 + o][p]) + bu2f(Sg[200 + o][p + 1]) + bb);
    } else {
      int o = c - 200; float bb = cb3[o];
      for (int p = 0; p < 48; p++)
        mv = fmaxf(mv, bu2f(Sg[300 + o][p]) + bu2f(Sg[400 + o][p + 1]) + bu2f(Sg[500 + o][p + 2]) + bb);
    }
    pooled[c] = fmaxf(mv, 0.f);
  }
  __syncthreads();

  float v0 = tfb[tid], v1 = tfb[tid + 256];
  for (int j = 0; j < 300; j++){
    float pj = pooled[j];
    v0 = fmaf(pj, tfwT[(size_t)j * EMB + tid], v0);
    v1 = fmaf(pj, tfwT[(size_t)j * EMB + tid + 256], v1);
  }
  float tot = block_reduce(v0 + v1, red, 4, false);
  float mu = tot * (1.f / 512.f);
  float s0 = v0 - mu, s1 = v1 - mu;
  float var = block_reduce(s0 * s0 + s1 * s1, red, 4, false) * (1.f / 512.f);
  float sc = sqrtf(1.f / (var + 1e-12f));
  basep[(size_t)r * EMB + tid] = s0 * sc;
  basep[(size_t)r * EMB + tid + 256] = s1 * sc;
}

// ---------------------------------------------------------------------------
// Split-bf16 MFMA GEMM, 128x128 tile, PRE-SPLIT weights, 1-D swizzled grid.
// splitout: apply act, then store split hi/lo bf16 planes (for FFN1->FFN2).
// ---------------------------------------------------------------------------
__global__ __launch_bounds__(256, 3) void gemm_mfma_pre_kernel(
    const float* __restrict__ A, const ushort_t* __restrict__ Whi,
    const ushort_t* __restrict__ Wlo, const float* __restrict__ bias,
    float* __restrict__ C, int M, int N, int K, int ldc, int act, int mt, int nt,
    ushort_t* __restrict__ Chi, ushort_t* __restrict__ Clo, int splitout)
{
  __shared__ ushort_t Ahi[128][40];
  __shared__ ushort_t Alo[128][40];
  __shared__ ushort_t Bhi[128][40];
  __shared__ ushort_t Blo[128][40];

  const int tid = threadIdx.x;
  const int t = xcd_swz(blockIdx.x, mt * nt);
  const int n0 = (t % nt) * 128, m0 = (t / nt) * 128;
  const int wave = tid >> 6, lane = tid & 63;
  const int wm = (wave >> 1) * 64, wn = (wave & 1) * 64;
  const int lcol = lane & 15, lq = lane >> 4;

  v4f acc[4][4];
  #pragma unroll
  for (int i = 0; i < 4; i++)
    #pragma unroll
    for (int j = 0; j < 4; j++) acc[i][j] = (v4f){0.f, 0.f, 0.f, 0.f};

  const int srow = tid >> 1;
  const int skh  = (tid & 1) * 16;
  const int am = m0 + srow, bn = n0 + srow;
  const bool mok = (am < M), nok = (bn < N);
  const float* ap = A + (size_t)am * K + skh;
  const ushort_t* bph = Whi + (size_t)bn * K + skh;
  const ushort_t* bpl = Wlo + (size_t)bn * K + skh;

  for (int k0 = 0; k0 < K; k0 += 32){
    bool kfull = (k0 + 32 <= K);
    // ---- stage A (split on the fly) ----
    {
      float av[16];
      if (mok && kfull){
        #pragma unroll
        for (int q = 0; q < 4; q++){
          float4 f = *(const float4*)(ap + k0 + q*4);
          av[q*4+0]=f.x; av[q*4+1]=f.y; av[q*4+2]=f.z; av[q*4+3]=f.w;
        }
      } else {
        #pragma unroll
        for (int e = 0; e < 16; e++){
          int k = k0 + skh + e;
          av[e] = (mok && k < K) ? ap[k0 + e] : 0.f;
        }
      }
      uint4 uh[2], ul[2];
      #pragma unroll
      for (int h = 0; h < 2; h++){
        unsigned hw[8], lw[8];
        #pragma unroll
        for (int e = 0; e < 8; e++){
          float x = av[h*8+e];
          unsigned u = __float_as_uint(x);
          float hf = __uint_as_float(u & 0xFFFF0000u);
          hw[e] = u >> 16;
          lw[e] = f2bu(x - hf);
        }
        uh[h] = make_uint4(hw[0]|(hw[1]<<16), hw[2]|(hw[3]<<16), hw[4]|(hw[5]<<16), hw[6]|(hw[7]<<16));
        ul[h] = make_uint4(lw[0]|(lw[1]<<16), lw[2]|(lw[3]<<16), lw[4]|(lw[5]<<16), lw[6]|(lw[7]<<16));
      }
      *(uint4*)&Ahi[srow][skh]     = uh[0];
      *(uint4*)&Ahi[srow][skh + 8] = uh[1];
      *(uint4*)&Alo[srow][skh]     = ul[0];
      *(uint4*)&Alo[srow][skh + 8] = ul[1];
    }
    // ---- stage B (pre-split: plain copies) ----
    {
      uint4 h0 = make_uint4(0,0,0,0), h1 = h0, l0 = h0, l1 = h0;
      if (nok && kfull){
        h0 = *(const uint4*)(bph + k0);
        h1 = *(const uint4*)(bph + k0 + 8);
        l0 = *(const uint4*)(bpl + k0);
        l1 = *(const uint4*)(bpl + k0 + 8);
      } else if (nok){
        ushort_t he[16], le[16];
        #pragma unroll
        for (int e = 0; e < 16; e++){
          int k = k0 + skh + e;
          he[e] = (k < K) ? bph[k0 + e] : (ushort_t)0;
          le[e] = (k < K) ? bpl[k0 + e] : (ushort_t)0;
        }
        h0 = *(uint4*)&he[0]; h1 = *(uint4*)&he[8];
        l0 = *(uint4*)&le[0]; l1 = *(uint4*)&le[8];
      }
      *(uint4*)&Bhi[srow][skh]     = h0;
      *(uint4*)&Bhi[srow][skh + 8] = h1;
      *(uint4*)&Blo[srow][skh]     = l0;
      *(uint4*)&Blo[srow][skh + 8] = l1;
    }
    __syncthreads();

    v8s ah[4], al[4];
    #pragma unroll
    for (int mi = 0; mi < 4; mi++){
      ah[mi] = *(const v8s*)&Ahi[wm + mi*16 + lcol][lq*8];
      al[mi] = *(const v8s*)&Alo[wm + mi*16 + lcol][lq*8];
    }
    #pragma unroll
    for (int ni = 0; ni < 4; ni++){
      v8s bh = *(const v8s*)&Bhi[wn + ni*16 + lcol][lq*8];
      v8s bl = *(const v8s*)&Blo[wn + ni*16 + lcol][lq*8];
      #pragma unroll
      for (int mi = 0; mi < 4; mi++){
        acc[mi][ni] = __builtin_amdgcn_mfma_f32_16x16x32_bf16(ah[mi], bh, acc[mi][ni], 0, 0, 0);
        acc[mi][ni] = __builtin_amdgcn_mfma_f32_16x16x32_bf16(al[mi], bh, acc[mi][ni], 0, 0, 0);
        acc[mi][ni] = __builtin_amdgcn_mfma_f32_16x16x32_bf16(ah[mi], bl, acc[mi][ni], 0, 0, 0);
      }
    }
    __syncthreads();
  }

  #pragma unroll
  for (int ni = 0; ni < 4; ni++){
    int n = n0 + wn + ni*16 + lcol;
    if (n >= N) continue;
    float bv = bias[n];
    #pragma unroll
    for (int mi = 0; mi < 4; mi++){
      int mbase = m0 + wm + mi*16 + lq*4;
      #pragma unroll
      for (int rg = 0; rg < 4; rg++){
        int m = mbase + rg;
        if (m >= M) continue;
        float v = acc[mi][ni][rg] + bv;
        if (act == 1) v = fmaxf(v, 0.f);
        else if (act == 2) v = 0.5f * v * (1.f + erff(v * 0.70710678118654752f));
        if (splitout){
          unsigned u = __float_as_uint(v);
          float hf = __uint_as_float(u & 0xFFFF0000u);
          Chi[(size_t)m * ldc + n] = (ushort_t)(u >> 16);
          Clo[(size_t)m * ldc + n] = f2bu(v - hf);
        } else {
          C[(size_t)m * ldc + n] = v;
        }
      }
    }
  }
}

// ---------------------------------------------------------------------------
// Split-bf16 MFMA GEMM, 128M x 64N tile, PRE-SPLIT weights AND PRE-SPLIT A,
// 1-D swizzled grid, optional split-K (atomic accumulate into pre-zeroed C).
// A staging is plain copies: kills the f32->split VALU chain (round-7 PMC:
// VALUBusy 20% > MfmaUtil 14% on FFN2).
// ---------------------------------------------------------------------------
__global__ __launch_bounds__(256, 4) void gemm_mfma_pre64A_kernel(
    const ushort_t* __restrict__ Ahig, const ushort_t* __restrict__ Alog,
    const ushort_t* __restrict__ Whi, const ushort_t* __restrict__ Wlo,
    const float* __restrict__ bias, float* __restrict__ C,
    int M, int N, int K, int ldc, int mt, int nt, int ks)
{
  __shared__ ushort_t Ahi[128][40];
  __shared__ ushort_t Alo[128][40];
  __shared__ ushort_t Bhi[64][40];
  __shared__ ushort_t Blo[64][40];

  const int tid = threadIdx.x;
  const int tiles = mt * nt;
  const int t_ = xcd_swz(blockIdx.x, tiles * ks);
  const int slice = t_ / tiles;
  const int t = t_ % tiles;
  const int n0 = (t % nt) * 64, m0 = (t / nt) * 128;
  const int kstep = ((K + 31) / 32 + ks - 1) / ks;
  const int kb = slice * kstep * 32;
  const int ke = min(K, kb + kstep * 32);
  if (kb >= ke) return;
  const int wave = tid >> 6, lane = tid & 63;
  const int wm = (wave >> 1) * 64, wn = (wave & 1) * 32;
  const int lcol = lane & 15, lq = lane >> 4;

  v4f acc[4][2];
  #pragma unroll
  for (int i = 0; i < 4; i++)
    #pragma unroll
    for (int j = 0; j < 2; j++) acc[i][j] = (v4f){0.f, 0.f, 0.f, 0.f};

  const int srow = tid >> 1;
  const int skh  = (tid & 1) * 16;
  const int am = m0 + srow;
  const bool mok = (am < M);
  const ushort_t* aph = Ahig + (size_t)am * K + skh;
  const ushort_t* apl = Alog + (size_t)am * K + skh;
  const int brow = tid >> 2;
  const int bkq  = (tid & 3) * 8;
  const int bn = n0 + brow;
  const bool nok = (bn < N);
  const ushort_t* bph = Whi + (size_t)bn * K + bkq;
  const ushort_t* bpl = Wlo + (size_t)bn * K + bkq;

  for (int k0 = kb; k0 < ke; k0 += 32){
    bool kfull = (k0 + 32 <= K);
    // ---- stage A (pre-split: plain copies) ----
    {
      uint4 h0 = make_uint4(0,0,0,0), h1 = h0, l0 = h0, l1 = h0;
      if (mok && kfull){
        h0 = *(const uint4*)(aph + k0);
        h1 = *(const uint4*)(aph + k0 + 8);
        l0 = *(const uint4*)(apl + k0);
        l1 = *(const uint4*)(apl + k0 + 8);
      } else if (mok){
        ushort_t he[16], le[16];
        #pragma unroll
        for (int e = 0; e < 16; e++){
          int k = k0 + skh + e;
          he[e] = (k < K) ? aph[k0 + e] : (ushort_t)0;
          le[e] = (k < K) ? apl[k0 + e] : (ushort_t)0;
        }
        h0 = *(uint4*)&he[0]; h1 = *(uint4*)&he[8];
        l0 = *(uint4*)&le[0]; l1 = *(uint4*)&le[8];
      }
      *(uint4*)&Ahi[srow][skh]     = h0;
      *(uint4*)&Ahi[srow][skh + 8] = h1;
      *(uint4*)&Alo[srow][skh]     = l0;
      *(uint4*)&Alo[srow][skh + 8] = l1;
    }
    // ---- stage B (pre-split: plain 8-elem copies) ----
    {
      uint4 h0 = make_uint4(0,0,0,0), l0 = h0;
      if (nok && kfull){
        h0 = *(const uint4*)(bph + k0);
        l0 = *(const uint4*)(bpl + k0);
      } else if (nok){
        ushort_t he[8], le[8];
        #pragma unroll
        for (int e = 0; e < 8; e++){
          int k = k0 + bkq + e;
          he[e] = (k < K) ? bph[k0 + e] : (ushort_t)0;
          le[e] = (k < K) ? bpl[k0 + e] : (ushort_t)0;
        }
        h0 = *(uint4*)&he[0];
        l0 = *(uint4*)&le[0];
      }
      *(uint4*)&Bhi[brow][bkq] = h0;
      *(uint4*)&Blo[brow][bkq] = l0;
    }
    __syncthreads();

    v8s ah[4], al[4];
    #pragma unroll
    for (int mi = 0; mi < 4; mi++){
      ah[mi] = *(const v8s*)&Ahi[wm + mi*16 + lcol][lq*8];
      al[mi] = *(const v8s*)&Alo[wm + mi*16 + lcol][lq*8];
    }
    #pragma unroll
    for (int ni = 0; ni < 2; ni++){
      v8s bh = *(const v8s*)&Bhi[wn + ni*16 + lcol][lq*8];
      v8s bl = *(const v8s*)&Blo[wn + ni*16 + lcol][lq*8];
      #pragma unroll
      for (int mi = 0; mi < 4; mi++){
        acc[mi][ni] = __builtin_amdgcn_mfma_f32_16x16x32_bf16(ah[mi], bh, acc[mi][ni], 0, 0, 0);
        acc[mi][ni] = __builtin_amdgcn_mfma_f32_16x16x32_bf16(al[mi], bh, acc[mi][ni], 0, 0, 0);
        acc[mi][ni] = __builtin_amdgcn_mfma_f32_16x16x32_bf16(ah[mi], bl, acc[mi][ni], 0, 0, 0);
      }
    }
    __syncthreads();
  }

  #pragma unroll
  for (int ni = 0; ni < 2; ni++){
    int n = n0 + wn + ni*16 + lcol;
    if (n >= N) continue;
    float bv = (ks == 1 || slice == 0) ? bias[n] : 0.f;
    #pragma unroll
    for (int mi = 0; mi < 4; mi++){
      int mbase = m0 + wm + mi*16 + lq*4;
      #pragma unroll
      for (int rg = 0; rg < 4; rg++){
        int m = mbase + rg;
        if (m >= M) continue;
        float v = acc[mi][ni][rg] + bv;
        if (ks == 1) C[(size_t)m * ldc + n] = v;
        else atomicAdd(&C[(size_t)m * ldc + n], v);
      }
    }
  }
}

// ---------------------------------------------------------------------------
// Split-bf16 MFMA GEMM, 128M x 64N tile, PRE-SPLIT weights, f32 A,
// 1-D swizzled grid, optional split-K.
// ---------------------------------------------------------------------------
__global__ __launch_bounds__(256, 4) void gemm_mfma_pre64_kernel(
    const float* __restrict__ A, const ushort_t* __restrict__ Whi,
    const ushort_t* __restrict__ Wlo, const float* __restrict__ bias,
    float* __restrict__ C, int M, int N, int K, int ldc, int act, int mt, int nt, int ks)
{
  __shared__ ushort_t Ahi[128][40];
  __shared__ ushort_t Alo[128][40];
  __shared__ ushort_t Bhi[64][40];
  __shared__ ushort_t Blo[64][40];

  const int tid = threadIdx.x;
  const int tiles = mt * nt;
  const int t_ = xcd_swz(blockIdx.x, tiles * ks);
  const int slice = t_ / tiles;
  const int t = t_ % tiles;
  const int n0 = (t % nt) * 64, m0 = (t / nt) * 128;
  const int kstep = ((K + 31) / 32 + ks - 1) / ks;
  const int kb = slice * kstep * 32;
  const int ke = min(K, kb + kstep * 32);
  if (kb >= ke) return;
  const int wave = tid >> 6, lane = tid & 63;
  const int wm = (wave >> 1) * 64, wn = (wave & 1) * 32;
  const int lcol = lane & 15, lq = lane >> 4;

  v4f acc[4][2];
  #pragma unroll
  for (int i = 0; i < 4; i++)
    #pragma unroll
    for (int j = 0; j < 2; j++) acc[i][j] = (v4f){0.f, 0.f, 0.f, 0.f};

  const int srow = tid >> 1;
  const int skh  = (tid & 1) * 16;
  const int am = m0 + srow;
  const bool mok = (am < M);
  const float* ap = A + (size_t)am * K + skh;
  const int brow = tid >> 2;
  const int bkq  = (tid & 3) * 8;
  const int bn = n0 + brow;
  const bool nok = (bn < N);
  const ushort_t* bph = Whi + (size_t)bn * K + bkq;
  const ushort_t* bpl = Wlo + (size_t)bn * K + bkq;

  for (int k0 = kb; k0 < ke; k0 += 32){
    bool kfull = (k0 + 32 <= K);
    // ---- stage A (split on the fly) ----
    {
      float av[16];
      if (mok && kfull){
        #pragma unroll
        for (int q = 0; q < 4; q++){
          float4 f = *(const float4*)(ap + k0 + q*4);
          av[q*4+0]=f.x; av[q*4+1]=f.y; av[q*4+2]=f.z; av[q*4+3]=f.w;
        }
      } else {
        #pragma unroll
        for (int e = 0; e < 16; e++){
          int k = k0 + skh + e;
          av[e] = (mok && k < K) ? ap[k0 + e] : 0.f;
        }
      }
      uint4 uh[2], ul[2];
      #pragma unroll
      for (int h = 0; h < 2; h++){
        unsigned hw[8], lw[8];
        #pragma unroll
        for (int e = 0; e < 8; e++){
          float x = av[h*8+e];
          unsigned u = __float_as_uint(x);
          float hf = __uint_as_float(u & 0xFFFF0000u);
          hw[e] = u >> 16;
          lw[e] = f2bu(x - hf);
        }
        uh[h] = make_uint4(hw[0]|(hw[1]<<16), hw[2]|(hw[3]<<16), hw[4]|(hw[5]<<16), hw[6]|(hw[7]<<16));
        ul[h] = make_uint4(lw[0]|(lw[1]<<16), lw[2]|(lw[3]<<16), lw[4]|(lw[5]<<16), lw[6]|(lw[7]<<16));
      }
      *(uint4*)&Ahi[srow][skh]     = uh[0];
      *(uint4*)&Ahi[srow][skh + 8] = uh[1];
      *(uint4*)&Alo[srow][skh]     = ul[0];
      *(uint4*)&Alo[srow][skh + 8] = ul[1];
    }
    // ---- stage B (pre-split: plain 8-elem copies) ----
    {
      uint4 h0 = make_uint4(0,0,0,0), l0 = h0;
      if (nok && kfull){
        h0 = *(const uint4*)(bph + k0);
        l0 = *(const uint4*)(bpl + k0);
      } else if (nok){
        ushort_t he[8], le[8];
        #pragma unroll
        for (int e = 0; e < 8; e++){
          int k = k0 + bkq + e;
          he[e] = (k < K) ? bph[k0 + e] : (ushort_t)0;
          le[e] = (k < K) ? bpl[k0 + e] : (ushort_t)0;
        }
        h0 = *(uint4*)&he[0];
        l0 = *(uint4*)&le[0];
      }
      *(uint4*)&Bhi[brow][bkq] = h0;
      *(uint4*)&Blo[brow][bkq] = l0;
    }
    __syncthreads();

    v8s ah[4], al[4];
    #pragma unroll
    for (int mi = 0; mi < 4; mi++){
      ah[mi] = *(const v8s*)&Ahi[wm + mi*16 + lcol][lq*8];
      al[mi] = *(const v8s*)&Alo[wm + mi*16 + lcol][lq*8];
    }
    #pragma unroll
    for (int ni = 0; ni < 2; ni++){
      v8s bh = *(const v8s*)&Bhi[wn + ni*16 + lcol][lq*8];
      v8s bl = *(const v8s*)&Blo[wn + ni*16 + lcol][lq*8];
      #pragma unroll
      for (int mi = 0; mi < 4; mi++){
        acc[mi][ni] = __builtin_amdgcn_mfma_f32_16x16x32_bf16(ah[mi], bh, acc[mi][ni], 0, 0, 0);
        acc[mi][ni] = __builtin_amdgcn_mfma_f32_16x16x32_bf16(al[mi], bh, acc[mi][ni], 0, 0, 0);
        acc[mi][ni] = __builtin_amdgcn_mfma_f32_16x16x32_bf16(ah[mi], bl, acc[mi][ni], 0, 0, 0);
      }
    }
    __syncthreads();
  }

  #pragma unroll
  for (int ni = 0; ni < 2; ni++){
    int n = n0 + wn + ni*16 + lcol;
    if (n >= N) continue;
    float bv = (ks == 1 || slice == 0) ? bias[n] : 0.f;
    #pragma unroll
    for (int mi = 0; mi < 4; mi++){
      int mbase = m0 + wm + mi*16 + lq*4;
      #pragma unroll
      for (int rg = 0; rg < 4; rg++){
        int m = mbase + rg;
        if (m >= M) continue;
        float v = acc[mi][ni][rg] + bv;
        if (ks == 1){
          if (act == 1) v = fmaxf(v, 0.f);
          else if (act == 2) v = 0.5f * v * (1.f + erff(v * 0.70710678118654752f));
          C[(size_t)m * ldc + n] = v;
        } else {
          atomicAdd(&C[(size_t)m * ldc + n], v);
        }
      }
    }
  }
}

// ---------------------------------------------------------------------------
// On-the-fly split GEMM (fallback when ws too small for pre-split weights).
// ---------------------------------------------------------------------------
__global__ __launch_bounds__(256, 2) void gemm_mfma_kernel(
    const float* __restrict__ A, const float* __restrict__ W,
    const float* __restrict__ bias, float* __restrict__ C,
    int M, int N, int K, int ldc, int act)
{
  __shared__ ushort_t Ahi[128][40];
  __shared__ ushort_t Alo[128][40];
  __shared__ ushort_t Bhi[128][40];
  __shared__ ushort_t Blo[128][40];

  const int tid = threadIdx.x;
  const int m0 = blockIdx.y * 128, n0 = blockIdx.x * 128;
  const int wave = tid >> 6, lane = tid & 63;
  const int wm = (wave >> 1) * 64, wn = (wave & 1) * 64;
  const int lcol = lane & 15, lq = lane >> 4;

  v4f acc[4][4];
  #pragma unroll
  for (int i = 0; i < 4; i++)
    #pragma unroll
    for (int j = 0; j < 4; j++) acc[i][j] = (v4f){0.f, 0.f, 0.f, 0.f};

  const int srow = tid >> 1;
  const int skh  = (tid & 1) * 16;

  for (int k0 = 0; k0 < K; k0 += 32){
    {
      float av[16];
      int m = m0 + srow;
      const float* ap = A + (size_t)m * K + k0 + skh;
      bool mok = (m < M);
      if (mok && (k0 + 32 <= K)){
        #pragma unroll
        for (int q = 0; q < 4; q++){
          float4 f = ((const float4*)ap)[q];
          av[q*4+0]=f.x; av[q*4+1]=f.y; av[q*4+2]=f.z; av[q*4+3]=f.w;
        }
      } else {
        #pragma unroll
        for (int e = 0; e < 16; e++){
          int k = k0 + skh + e;
          av[e] = (mok && k < K) ? ap[e] : 0.f;
        }
      }
      uint4 uh[2], ul[2];
      #pragma unroll
      for (int h = 0; h < 2; h++){
        unsigned hw[8], lw[8];
        #pragma unroll
        for (int e = 0; e < 8; e++){
          float x = av[h*8+e];
          unsigned u = __float_as_uint(x);
          float hf = __uint_as_float(u & 0xFFFF0000u);
          hw[e] = u >> 16;
          lw[e] = f2bu(x - hf);
        }
        uh[h] = make_uint4(hw[0]|(hw[1]<<16), hw[2]|(hw[3]<<16), hw[4]|(hw[5]<<16), hw[6]|(hw[7]<<16));
        ul[h] = make_uint4(lw[0]|(lw[1]<<16), lw[2]|(lw[3]<<16), lw[4]|(lw[5]<<16), lw[6]|(lw[7]<<16));
      }
      *(uint4*)&Ahi[srow][skh]     = uh[0];
      *(uint4*)&Ahi[srow][skh + 8] = uh[1];
      *(uint4*)&Alo[srow][skh]     = ul[0];
      *(uint4*)&Alo[srow][skh + 8] = ul[1];
    }
    {
      float bv[16];
      int n = n0 + srow;
      const float* bp = W + (size_t)n * K + k0 + skh;
      bool nok = (n < N);
      if (nok && (k0 + 32 <= K)){
        #pragma unroll
        for (int q = 0; q < 4; q++){
          float4 f = ((const float4*)bp)[q];
          bv[q*4+0]=f.x; bv[q*4+1]=f.y; bv[q*4+2]=f.z; bv[q*4+3]=f.w;
        }
      } else {
        #pragma unroll
        for (int e = 0; e < 16; e++){
          int k = k0 + skh + e;
          bv[e] = (nok && k < K) ? bp[e] : 0.f;
        }
      }
      uint4 uh[2], ul[2];
      #pragma unroll
      for (int h = 0; h < 2; h++){
        unsigned hw[8], lw[8];
        #pragma unroll
        for (int e = 0; e < 8; e++){
          float x = bv[h*8+e];
          unsigned u = __float_as_uint(x);
          float hf = __uint_as_float(u & 0xFFFF0000u);
          hw[e] = u >> 16;
          lw[e] = f2bu(x - hf);
        }
        uh[h] = make_uint4(hw[0]|(hw[1]<<16), hw[2]|(hw[3]<<16), hw[4]|(hw[5]<<16), hw[6]|(hw[7]<<16));
        ul[h] = make_uint4(lw[0]|(lw[1]<<16), lw[2]|(lw[3]<<16), lw[4]|(lw[5]<<16), lw[6]|(lw[7]<<16));
      }
      *(uint4*)&Bhi[srow][skh]     = uh[0];
      *(uint4*)&Bhi[srow][skh + 8] = uh[1];
      *(uint4*)&Blo[srow][skh]     = ul[0];
      *(uint4*)&Blo[srow][skh + 8] = ul[1];
    }
    __syncthreads();

    v8s ah[4], al[4];
    #pragma unroll
    for (int mi = 0; mi < 4; mi++){
      ah[mi] = *(const v8s*)&Ahi[wm + mi*16 + lcol][lq*8];
      al[mi] = *(const v8s*)&Alo[wm + mi*16 + lcol][lq*8];
    }
    #pragma unroll
    for (int ni = 0; ni < 4; ni++){
      v8s bh = *(const v8s*)&Bhi[wn + ni*16 + lcol][lq*8];
      v8s bl = *(const v8s*)&Blo[wn + ni*16 + lcol][lq*8];
      #pragma unroll
      for (int mi = 0; mi < 4; mi++){
        acc[mi][ni] = __builtin_amdgcn_mfma_f32_16x16x32_bf16(ah[mi], bh, acc[mi][ni], 0, 0, 0);
        acc[mi][ni] = __builtin_amdgcn_mfma_f32_16x16x32_bf16(al[mi], bh, acc[mi][ni], 0, 0, 0);
        acc[mi][ni] = __builtin_amdgcn_mfma_f32_16x16x32_bf16(ah[mi], bl, acc[mi][ni], 0, 0, 0);
      }
    }
    __syncthreads();
  }

  #pragma unroll
  for (int ni = 0; ni < 4; ni++){
    int n = n0 + wn + ni*16 + lcol;
    if (n >= N) continue;
    float bv = bias[n];
    #pragma unroll
    for (int mi = 0; mi < 4; mi++){
      int mbase = m0 + wm + mi*16 + lq*4;
      #pragma unroll
      for (int rg = 0; rg < 4; rg++){
        int m = mbase + rg;
        if (m >= M) continue;
        float v = acc[mi][ni][rg] + bv;
        if (act == 1) v = fmaxf(v, 0.f);
        else if (act == 2) v = 0.5f * v * (1.f + erff(v * 0.70710678118654752f));
        C[(size_t)m * ldc + n] = v;
      }
    }
  }
}

// ---------------------------------------------------------------------------
// f32 GEMM kept for tiny shapes (M=32).
// ---------------------------------------------------------------------------
__global__ __launch_bounds__(256) void gemm_kernel(
    const float* __restrict__ A, const float* __restrict__ W,
    const float* __restrict__ bias, float* __restrict__ C,
    int M, int N, int K, int act)
{
  __shared__ float As[16][64];
  __shared__ float Ws[16][64];
  const int tid = threadIdx.x;
  const int m0 = blockIdx.y * 64, n0 = blockIdx.x * 64;
  const int lr = tid >> 2;
  const int lk = (tid & 3) * 4;
  const int tx = tid & 15, ty = tid >> 4;
  float cc[4][4];
  #pragma unroll
  for (int i = 0; i < 4; i++)
    #pragma unroll
    for (int j = 0; j < 4; j++) cc[i][j] = 0.f;

  for (int k0 = 0; k0 < K; k0 += 16){
    #pragma unroll
    for (int i = 0; i < 4; i++){
      int k = k0 + lk + i;
      int m = m0 + lr;
      As[lk + i][lr] = (m < M && k < K) ? A[(size_t)m * K + k] : 0.f;
      int n = n0 + lr;
      Ws[lk + i][lr] = (n < N && k < K) ? W[(size_t)n * K + k] : 0.f;
    }
    __syncthreads();
    #pragma unroll
    for (int kk = 0; kk < 16; kk++){
      float4 a = *(const float4*)&As[kk][ty * 4];
      float4 b = *(const float4*)&Ws[kk][tx * 4];
      float av[4] = {a.x, a.y, a.z, a.w};
      float bv[4] = {b.x, b.y, b.z, b.w};
      #pragma unroll
      for (int i = 0; i < 4; i++)
        #pragma unroll
        for (int j = 0; j < 4; j++) cc[i][j] = fmaf(av[i], bv[j], cc[i][j]);
    }
    __syncthreads();
  }

  #pragma unroll
  for (int i = 0; i < 4; i++){
    int m = m0 + ty * 4 + i;
    if (m >= M) continue;
    #pragma unroll
    for (int j = 0; j < 4; j++){
      int n = n0 + tx * 4 + j;
      if (n >= N) continue;
      float v = cc[i][j] + bias[n];
      if (act == 1) v = fmaxf(v, 0.f);
      else if (act == 2) v = 0.5f * v * (1.f + erff(v * 0.70710678118654752f));
      C[(size_t)m * N + n] = v;
    }
  }
}

// ---------------------------------------------------------------------------
// LayerNorm over EMB=512.
// ---------------------------------------------------------------------------
__global__ __launch_bounds__(256) void ln_kernel(
    const float* __restrict__ X, const float* __restrict__ Res,
    const float* __restrict__ g, const float* __restrict__ bta,
    const float* __restrict__ pscale, const float* __restrict__ pbias,
    float* __restrict__ Y, int S, float eps)
{
  __shared__ float red[8];
  const int r = blockIdx.x, tid = threadIdx.x;
  size_t o0 = (size_t)r * EMB + tid;
  size_t o1 = o0 + 256;
  float v0 = X[o0] + (Res ? Res[o0] : 0.f);
  float v1 = X[o1] + (Res ? Res[o1] : 0.f);
  float tot = block_reduce(v0 + v1, red, 4, false);
  float mu = tot * (1.f / 512.f);
  float s0 = v0 - mu, s1 = v1 - mu;
  float var = block_reduce(s0 * s0 + s1 * s1, red, 4, false) * (1.f / 512.f);
  float rs = 1.f / sqrtf(var + eps);
  float y0 = s0 * rs, y1 = s1 * rs;
  if (g){
    y0 = y0 * g[tid] + bta[tid];
    y1 = y1 * g[tid + 256] + bta[tid + 256];
  }
  if (pscale){
    int b = r / S, t = r % S;
    size_t po = ((size_t)(b * 300 + t)) * EMB;
    y0 = y0 * pscale[po + tid] + pbias[po + tid];
    y1 = y1 * pscale[po + tid + 256] + pbias[po + tid + 256];
  }
  Y[o0] = y0;
  Y[o1] = y1;
}

// ---------------------------------------------------------------------------
// V column-mean per (b,h) (for fully-masked uniform-softmax rows).
// ---------------------------------------------------------------------------
__global__ __launch_bounds__(64) void vmean_kernel(const float* __restrict__ qkv,
                                                   float* __restrict__ vm, int S){
  int bh = blockIdx.x; int b = bh >> 3, h = bh & 7; int d = threadIdx.x;
  const float* vr = qkv + (size_t)(b * S) * 1536 + 1024 + h * DH + d;
  float s = 0.f;
  for (int j = 0; j < S; j++) s += vr[(size_t)j * 1536];
  vm[bh * DH + d] = s / (float)S;
}

// ---------------------------------------------------------------------------
// Attention, full rows only: i==0 (all b,h) plus b==0,h>=6 (all i>0).
// ---------------------------------------------------------------------------
__global__ __launch_bounds__(64) void attn_full_kernel(
    const float* __restrict__ qkv, float* __restrict__ Ctx, int S)
{
  __shared__ float qv[DH];
  __shared__ float sc[SEQ];
  const int tid = threadIdx.x;
  const int blk = blockIdx.x;
  int b, h, i;
  if (blk < NB * HEADS){ b = blk >> 3; h = blk & 7; i = 0; }
  else {
    int idx = blk - NB * HEADS;
    b = 0; h = 6 + idx / (S - 1); i = 1 + idx % (S - 1);
  }
  const size_t rowoff = ((size_t)(b * S + i)) * 1536 + h * DH;
  const size_t coff = ((size_t)(b * S + i)) * EMB + h * DH;

  qv[tid] = qkv[rowoff + tid];
  __syncthreads();
  for (int j = tid; j < S; j += 64){
    const float* kr = qkv + ((size_t)(b * S + j)) * 1536 + 512 + h * DH;
    float d = 0.f;
    #pragma unroll
    for (int d4 = 0; d4 < 16; d4++){
      float4 kk = *(const float4*)(kr + d4 * 4);
      d = fmaf(qv[d4*4+0], kk.x, d);
      d = fmaf(qv[d4*4+1], kk.y, d);
      d = fmaf(qv[d4*4+2], kk.z, d);
      d = fmaf(qv[d4*4+3], kk.w, d);
    }
    sc[j] = d * 0.125f;
  }
  __syncthreads();
  float mx = -INFINITY;
  for (int j = tid; j < S; j += 64) mx = fmaxf(mx, sc[j]);
  #pragma unroll
  for (int o = 32; o > 0; o >>= 1) mx = fmaxf(mx, __shfl_down(mx, o, 64));
  mx = __shfl(mx, 0, 64);
  float sm = 0.f;
  for (int j = tid; j < S; j += 64){ float e = expf(sc[j] - mx); sc[j] = e; sm += e; }
  #pragma unroll
  for (int o = 32; o > 0; o >>= 1) sm += __shfl_down(sm, o, 64);
  sm = __shfl(sm, 0, 64);
  float inv = 1.f / sm;
  __syncthreads();
  float a_ = 0.f;
  const float* vr = qkv + ((size_t)(b * S)) * 1536 + 1024 + h * DH + tid;
  for (int j = 0; j < S; j++) a_ = fmaf(sc[j], vr[(size_t)j * 1536], a_);
  Ctx[coff + tid] = a_ * inv;
}

// ---------------------------------------------------------------------------
// Attention, banded rows (h<6, i>0): register-only, 4 waves/block, 1 row/wave.
// ---------------------------------------------------------------------------
__global__ __launch_bounds__(256) void attn_band_kernel(
    const float* __restrict__ qkv, float* __restrict__ Ctx, int S)
{
  const int rows = NB * 6 * (S - 1);
  const int r = blockIdx.x * 4 + (threadIdx.x >> 6);
  const int lane = threadIdx.x & 63;
  if (r >= rows) return;
  const int i = 1 + r % (S - 1);
  const int q_ = r / (S - 1);
  const int h = q_ % 6, b = q_ / 6;
  const float* base = qkv + (size_t)(b * S) * 1536;
  const float qd = base[(size_t)i * 1536 + h * DH + lane];
  const int lo = max(0, i - 5), hi = min(S - 1, i + 4);
  const int cnt = hi - lo + 1;

  float sc_r[10];
  #pragma unroll
  for (int jj = 0; jj < 10; jj++){
    float p = 0.f;
    if (jj < cnt) p = qd * base[(size_t)(lo + jj) * 1536 + 512 + h * DH + lane];
    #pragma unroll
    for (int o = 32; o > 0; o >>= 1) p += __shfl_xor(p, o, 64);
    sc_r[jj] = (jj < cnt) ? p * 0.125f : -INFINITY;
  }
  float mx = sc_r[0];
  #pragma unroll
  for (int jj = 1; jj < 10; jj++) mx = fmaxf(mx, sc_r[jj]);
  float sm = 0.f;
  #pragma unroll
  for (int jj = 0; jj < 10; jj++){ sc_r[jj] = expf(sc_r[jj] - mx); sm += sc_r[jj]; }
  const float inv = 1.f / sm;
  float a_ = 0.f;
  #pragma unroll
  for (int jj = 0; jj < 10; jj++){
    if (jj < cnt) a_ = fmaf(sc_r[jj], base[(size_t)(lo + jj) * 1536 + 1024 + h * DH + lane], a_);
  }
  Ctx[((size_t)(b * S + i)) * EMB + h * DH + lane] = a_ * inv;
}

// ---------------------------------------------------------------------------
// Fully-masked rows (h>=6, b>0, i>0): uniform softmax -> V column mean.
// ---------------------------------------------------------------------------
__global__ __launch_bounds__(256) void vmfill_kernel(
    const float* __restrict__ vm, float* __restrict__ Ctx, int S)
{
  const int total = (NB - 1) * 2 * (S - 1) * 64;
  int idx = blockIdx.x * 256 + threadIdx.x;
  if (idx >= total) return;
  const int d = idx & 63;
  int rest = idx >> 6;
  const int i = 1 + rest % (S - 1);
  rest /= (S - 1);
  const int h = 6 + (rest & 1);
  const int b = 1 + (rest >> 1);
  Ctx[((size_t)(b * S + i)) * EMB + h * DH + d] = vm[(b * HEADS + h) * DH + d];
}

// --------------------------- small utility kernels -------------------------
__global__ void buildx1_kernel(const float* __restrict__ base, float* __restrict__ x1){
  int idx = blockIdx.x * 256 + threadIdx.x;
  if (idx >= NB * 101 * EMB) return;
  int e = idx & 511;
  int bt = idx >> 9;
  int t = bt % 101, b = bt / 101;
  x1[idx] = (t == 0) ? 0.f : base[((size_t)(b * SEQ + t - 1)) * EMB + e];
}

__global__ void extract_kernel(const float* __restrict__ p2, float* __restrict__ clsE, float* __restrict__ tok){
  int idx = blockIdx.x * 256 + threadIdx.x;
  if (idx >= NB * 101 * NCLS) return;
  int n = idx % NCLS;
  int bt = idx / NCLS;
  int t = bt % 101, b = bt / 101;
  float v = p2[idx];
  if (t == 0) clsE[b * NCLS + n] = v;
  else tok[((size_t)(b * 100 + t - 1)) * NCLS + n] = v;
}

__global__ void zero_kernel(float* p){ if (threadIdx.x == 0) p[0] = 0.f; }

__global__ __launch_bounds__(256) void slhat_kernel(
    const float* __restrict__ P, const float* __restrict__ ls, float* __restrict__ SLh)
{
  int bm = blockIdx.x;
  int b = bm / NCLS, m = bm % NCLS;
  int n = threadIdx.x;
  if (n >= NCLS) return;
  const float* Pb = P + (size_t)b * 100 * NCLS;
  float s = 0.f;
  for (int t = 0; t < 100; t++) s = fmaf(Pb[t * NCLS + m], Pb[t * NCLS + n], s);
  SLh[((size_t)bm) * NCLS + n] = ls[m * NCLS + n] + 0.4f * s;
}

__global__ __launch_bounds__(256) void outIII_kernel(
    const float* __restrict__ cls3, const float* __restrict__ SLh, float* __restrict__ o3)
{
  int b = blockIdx.x, n = threadIdx.x;
  if (n >= NCLS) return;
  float s = 0.f;
  for (int m = 0; m < NCLS; m++)
    s = fmaf(cls3[b * NCLS + m], SLh[((size_t)(b * NCLS + m)) * NCLS + n], s);
  o3[b * NCLS + n] = s;
}

__global__ __launch_bounds__(256) void softmax_out_kernel(const float* __restrict__ X, float* __restrict__ O, int n){
  __shared__ float red[8];
  int r = blockIdx.x, tid = threadIdx.x;
  float mx = -INFINITY;
  for (int j = tid; j < n; j += 256) mx = fmaxf(mx, X[(size_t)r * n + j]);
  mx = block_reduce(mx, red, 4, true);
  float sm = 0.f;
  for (int j = tid; j < n; j += 256) sm += expf(X[(size_t)r * n + j] - mx);
  sm = block_reduce(sm, red, 4, false);
  for (int j = tid; j < n; j += 256) O[(size_t)r * n + j] = expf(X[(size_t)r * n + j] - mx) / sm;
}

__global__ __launch_bounds__(256) void normalize_kernel(
    const float* __restrict__ clsE, const float* __restrict__ u4,
    float* __restrict__ imn, float* __restrict__ sn)
{
  __shared__ float red[8];
  int r = blockIdx.x, tid = threadIdx.x;
  const float* s = (r < NB) ? (clsE + (size_t)r * NCLS) : (u4 + (size_t)(r - NB) * NCLS);
  float* d = (r < NB) ? (imn + (size_t)r * NCLS) : (sn + (size_t)(r - NB) * NCLS);
  float v = (tid < NCLS) ? s[tid] : 0.f;
  float ss = block_reduce(v * v, red, 4, false);
  float nrm = fmaxf(sqrtf(ss), 1e-12f);
  if (tid < NCLS) d[tid] = v / nrm;
}

__global__ __launch_bounds__(1024) void contrastive_kernel(
    const float* __restrict__ imn, const float* __restrict__ sn, float* __restrict__ out)
{
  __shared__ float sc[NB][NB];
  __shared__ float red[16];
  int tid = threadIdx.x;
  int i = tid >> 5, j = tid & 31;
  float d = 0.f;
  for (int c = 0; c < NCLS; c++) d = fmaf(imn[i * NCLS + c], sn[j * NCLS + c], d);
  sc[i][j] = d;
  __syncthreads();
  float di = sc[i][i], dj = sc[j][j];
  float v = 0.f;
  if (i != j)
    v = fmaxf(0.02f + sc[i][j] - di, 0.f) + fmaxf(0.02f + sc[i][j] - dj, 0.f);
  #pragma unroll
  for (int o = 32; o > 0; o >>= 1) v += __shfl_down(v, o, 64);
  if ((tid & 63) == 0) red[tid >> 6] = v;
  __syncthreads();
  if (tid == 0){
    float s = 0.f;
    for (int w = 0; w < 16; w++) s += red[w];
    out[13057] = s * 0.01f;
  }
}

// ---------------------------------------------------------------------------
// Two-stage means over rows of p1 (NCLS cols) and ap (EMB cols).
// ---------------------------------------------------------------------------
__global__ __launch_bounds__(256) void means_part_kernel(
    const float* __restrict__ p1, const float* __restrict__ ap,
    float* __restrict__ part)
{
  const int blk = blockIdx.x;
  const int bi = blk / MSEG, seg = blk % MSEG;
  const int b = bi >> 1, i = bi & 1;
  const int start = i;
  const int cnt = (i == 0) ? 100 : 199;
  const int per = (cnt + MSEG - 1) / MSEG;
  const int r0 = seg * per;
  const int r1 = min(r0 + per, cnt);
  float* dst = part + (size_t)blk * 720;
  for (int c = threadIdx.x; c < NCLS + EMB; c += 256){
    float s = 0.f;
    if (c < NCLS){
      for (int rr = r0; rr < r1; rr++)
        s += p1[((size_t)(b * SEQ + start + rr)) * NCLS + c];
    } else {
      int cc = c - NCLS;
      for (int rr = r0; rr < r1; rr++)
        s += ap[((size_t)(b * SEQ + start + rr)) * EMB + cc];
    }
    dst[c] = s;
  }
}

__global__ __launch_bounds__(256) void means_final_kernel(
    const float* __restrict__ part, float* __restrict__ mp, float* __restrict__ ma)
{
  const int bi = blockIdx.x;
  const int i = bi & 1;
  const float icnt = (i == 0) ? (1.f / 100.f) : (1.f / 199.f);
  for (int c = threadIdx.x; c < NCLS + EMB; c += 256){
    float s = 0.f;
    #pragma unroll
    for (int g = 0; g < MSEG; g++)
      s += part[((size_t)(bi * MSEG + g)) * 720 + c];
    if (c < NCLS) mp[(size_t)bi * NCLS + c] = s * icnt;
    else          ma[(size_t)bi * EMB + (c - NCLS)] = s * icnt;
  }
}

__global__ __launch_bounds__(64) void klfinal_kernel(
    const float* __restrict__ cbuf, const float* __restrict__ abuf, float* __restrict__ acc)
{
  const int b = blockIdx.x, lane = threadIdx.x;
  float rk[4], re[4];
  #pragma unroll
  for (int pr = 0; pr < 4; pr++){
    int i = pr >> 1, j = pr & 1;
    const float* c1 = cbuf + ((size_t)(b * 2 + i)) * NCLS;
    const float* c2 = cbuf + ((size_t)(b * 2 + j)) * NCLS;
    float s = 0.f;
    for (int n = lane; n < NCLS; n += 64){
      float x = c1[n] + 1e-6f, y = c2[n] + 1e-6f;
      s += x * logf(x / y);
    }
    #pragma unroll
    for (int o = 32; o > 0; o >>= 1) s += __shfl_down(s, o, 64);
    rk[pr] = __shfl(s, 0, 64);
    const float* a1 = abuf + ((size_t)(b * 2 + i)) * EMB;
    const float* a2 = abuf + ((size_t)(b * 2 + j)) * EMB;
    float s2 = 0.f;
    for (int n = lane; n < EMB; n += 64){
      float dd = a1[n] - a2[n];
      s2 += dd * dd;
    }
    #pragma unroll
    for (int o = 32; o > 0; o >>= 1) s2 += __shfl_down(s2, o, 64);
    re[pr] = sqrtf(__shfl(s2, 0, 64) + 1e-12f);
  }
  if (lane == 0){
    float sk[4], se[4];
    float mk = -INFINITY, me = -INFINITY;
    for (int p = 0; p < 4; p++){
      sk[p] = rk[p] * 10.f;
      mk = fmaxf(mk, sk[p]);
      se[p] = re[p];
      me = fmaxf(me, se[p]);
    }
    float ssk = 0.f, sse = 0.f;
    for (int p = 0; p < 4; p++){ sk[p] = expf(sk[p] - mk); ssk += sk[p]; se[p] = expf(se[p] - me); sse += se[p]; }
    float loss = 0.f;
    for (int p = 0; p < 4; p++){
      float x = sk[p] / ssk + 1e-6f, y = se[p] / sse + 1e-6f;
      loss += x * logf(x / y);
    }
    atomicAdd(acc, loss);
  }
}

__global__ void finalize_kernel(const float* __restrict__ acc, float* __restrict__ out){
  if (threadIdx.x == 0) out[13056] = acc[0] * (100000.f / 32.f);
}

// ---------------------------------------------------------------------------
extern "C" void kernel_launch(void* const* d_in, const int* in_sizes, int n_in,
                              void* d_out, int out_size, void* d_ws, size_t ws_size,
                              hipStream_t stream)
{
  (void)in_sizes; (void)n_in; (void)out_size;
  const int*   src  = (const int*)  d_in[0];
  const float* user_info = (const float*)d_in[1];
  const float* ls   = (const float*)d_in[2];
  const float* emb  = (const float*)d_in[3];
  const float* cw1  = (const float*)d_in[4];  const float* cb1 = (const float*)d_in[5];
  const float* cw2  = (const float*)d_in[6];  const float* cb2 = (const float*)d_in[7];
  const float* cw3  = (const float*)d_in[8];  const float* cb3 = (const float*)d_in[9];
  const float* tfw  = (const float*)d_in[10]; const float* tfb = (const float*)d_in[11];
  const float* wq   = (const float*)d_in[12]; const float* bq  = (const float*)d_in[13];
  const float* wk   = (const float*)d_in[14]; const float* bk  = (const float*)d_in[15];
  const float* wv   = (const float*)d_in[16]; const float* bv  = (const float*)d_in[17];
  const float* wo   = (const float*)d_in[18]; const float* bo  = (const float*)d_in[19];
  const float* l1g  = (const float*)d_in[20]; const float* l1b = (const float*)d_in[21];
  const float* fw1  = (const float*)d_in[22]; const float* fb1 = (const float*)d_in[23];
  const float* fw2  = (const float*)d_in[24]; const float* fb2 = (const float*)d_in[25];
  const float* l2g  = (const float*)d_in[26]; const float* l2b = (const float*)d_in[27];
  const float* fc1w = (const float*)d_in[28]; const float* fc1b= (const float*)d_in[29];
  const float* fc2w = (const float*)d_in[30]; const float* fc2b= (const float*)d_in[31];
  const float* fc3w = (const float*)d_in[32]; const float* fc3b= (const float*)d_in[33];
  const float* fc4w = (const float*)d_in[34]; const float* fc4b= (const float*)d_in[35];
  const float* pscale = (const float*)d_in[36];
  const float* pbias  = (const float*)d_in[37];
  float* out = (float*)d_out;
  float* ws = (float*)d_ws;

  size_t off = 0;
  auto alloc = [&](size_t n){ float* p = ws + off; off += ((n + 3) & ~(size_t)3); return p; };
  float* base = alloc(6400ULL * EMB);
  float* x1   = alloc((size_t)NB * 101 * EMB);
  float* qkv  = alloc(6400ULL * 1536);
  float* ctx  = alloc(6400ULL * EMB);
  float* proj = alloc(6400ULL * EMB);
  float* hb   = alloc(6400ULL * FFND);         // FFN buffer; aliased as (hbh,hbl) split planes
  float* p2   = alloc(6400ULL * NCLS);
  float* clsE = alloc((size_t)NB * NCLS);
  float* tok  = alloc(3200ULL * NCLS);
  float* Pb   = alloc(3200ULL * NCLS);
  float* cls3 = alloc((size_t)NB * NCLS);
  float* SLh  = alloc((size_t)NB * NCLS * NCLS);
  float* o3   = alloc((size_t)NB * NCLS);
  float* u4   = alloc((size_t)NB * NCLS);
  float* imn  = alloc((size_t)NB * NCLS);
  float* sn   = alloc((size_t)NB * NCLS);
  float* mp   = alloc(64ULL * NCLS);
  float* ma   = alloc(64ULL * EMB);
  float* cbf  = alloc(64ULL * NCLS);
  float* abf  = alloc(64ULL * EMB);
  float* lacc = alloc(4);
  float* vmb  = alloc((size_t)NB * HEADS * DH);
  ushort_t* Wb = (ushort_t*)alloc((size_t)VC * KD / 2);   // conv weights bf16
  float* tfwT = alloc(300ULL * EMB);
  float* bqkv = alloc(4ULL * 1536);
  // bf16 embedding table (20000x1024, 41 MB) ALIASES qkv+ctx: only live
  // during textcnn stage 1, which completes before any encoder kernel runs.
  ushort_t* embb = (ushort_t*)qkv;
  // FFN1 split output planes ALIAS hb exactly (2 x 6400x2048 ushort = hb bytes).
  ushort_t* hbh = (ushort_t*)hb;
  ushort_t* hbl = hbh + 6400ULL * FFND;
  // pre-split encoder weights (bf16 hi/lo). Element offsets within each array:
  const size_t OQKV = 0, OWO = 3145728, OF1 = 4194304, OF2 = 8388608;
  const size_t OC1 = 12582912, OC2 = 12845056, OC3 = 12949504, WTOT = 12991120;
  ushort_t* WhiA = (ushort_t*)alloc((WTOT + 1) / 2);
  ushort_t* WloA = (ushort_t*)alloc((WTOT + 1) / 2);
  const bool presplit = (off * sizeof(float) <= ws_size);   // ~205 MB needed

  auto gemm_f32 = [&](const float* A, const float* W, const float* bi, float* C,
                      int M, int N, int K, int act){
    dim3 g((N + 63) / 64, (M + 63) / 64);
    gemm_kernel<<<g, 256, 0, stream>>>(A, W, bi, C, M, N, K, act);
  };
  auto gemm_fly = [&](const float* A, const float* W, const float* bi, float* C,
                      int M, int N, int K, int ldc, int act){
    dim3 g((N + 127) / 128, (M + 127) / 128);
    gemm_mfma_kernel<<<g, 256, 0, stream>>>(A, W, bi, C, M, N, K, ldc, act);
  };
  auto gemm_pre = [&](const float* A, size_t woff, const float* bi, float* C,
                      int M, int N, int K, int ldc, int act){
    int mt = (M + 127) / 128;
    if (N <= 512){
      int nt = (N + 63) / 64;
      int tiles = mt * nt;
      int ks = 1;
      if (act == 0 && K >= 1024){
        while (ks < 8 && tiles * ks * 2 <= 2048 && K / (ks * 2) >= 128) ks *= 2;
      }
      if (ks > 1){
        size_t n4 = ((size_t)M * N) / 4;
        int zg = (int)min((n4 + 255) / 256, (size_t)2048);
        zerobuf_kernel<<<zg, 256, 0, stream>>>(C, n4);
      }
      gemm_mfma_pre64_kernel<<<tiles * ks, 256, 0, stream>>>(
          A, WhiA + woff, WloA + woff, bi, C, M, N, K, ldc, act, mt, nt, ks);
    } else {
      int nt = (N + 127) / 128;
      gemm_mfma_pre_kernel<<<mt * nt, 256, 0, stream>>>(
          A, WhiA + woff, WloA + woff, bi, C, M, N, K, ldc, act, mt, nt,
          nullptr, nullptr, 0);
    }
  };
  auto split = [&](const float* srcw, size_t woff, int n){
    split_kernel<<<(n / 4 + 255) / 256, 256, 0, stream>>>(srcw, WhiA + woff, WloA + woff, n);
  };

  // Stage 0: weight prep (same work every call; graph-safe)
  prep_w_kernel<<<(VC * KD / 4 + 255) / 256, 256, 0, stream>>>(cw1, cw2, cw3, Wb);
  prep_embbf_kernel<<<(int)((20000ULL * KD / 4 + 255) / 256), 256, 0, stream>>>(emb, embb);
  prep_tfwT_kernel<<<(300 * EMB + 255) / 256, 256, 0, stream>>>(tfw, tfwT);
  if (presplit){
    for (int l = 0; l < NLAYERS; l++){
      split(wq + (size_t)l * 262144, OQKV + (size_t)l * 786432,          262144);
      split(wk + (size_t)l * 262144, OQKV + (size_t)l * 786432 + 262144, 262144);
      split(wv + (size_t)l * 262144, OQKV + (size_t)l * 786432 + 524288, 262144);
      split(wo + (size_t)l * 262144, OWO + (size_t)l * 262144, 262144);
      split(fw1 + (size_t)l * 1048576, OF1 + (size_t)l * 1048576, 1048576);
      split(fw2 + (size_t)l * 1048576, OF2 + (size_t)l * 1048576, 1048576);
    }
    split(fc1w, OC1, 262144);
    split(fc2w, OC2, NCLS * EMB);
    split(fc3w, OC3, NCLS * NCLS);
    qkvbias_kernel<<<4, 256, 0, stream>>>(bq, bk, bv, bqkv);
  }

  // Stage 1: textcnn = conv GEMM (chunked, reusing hb) + pool/FC/ln
  for (int c = 0; c < CCH; c++){
    conv_gemm_kernel<<<CT, 256, 0, stream>>>(
        src + (size_t)c * CM, embb, Wb, (ushort_t*)hb, CM);
    pool_fc_kernel<<<CROWS, 256, 0, stream>>>(
        (ushort_t*)hb, tfwT, cb1, cb2, cb3, tfb, base + (size_t)c * CROWS * EMB);
  }
  buildx1_kernel<<<(NB * 101 * EMB + 255) / 256, 256, 0, stream>>>(base, x1);

  auto encoder = [&](float* x, int S){
    int M = NB * S;
    for (int l = 0; l < NLAYERS; l++){
      if (presplit){
        gemm_pre(x, OQKV + (size_t)l * 786432, bqkv + l * 1536, qkv, M, 1536, EMB, 1536, 0);
      } else {
        gemm_fly(x, wq + (size_t)l * EMB * EMB, bq + l * EMB, qkv,        M, EMB, EMB, 1536, 0);
        gemm_fly(x, wk + (size_t)l * EMB * EMB, bk + l * EMB, qkv + 512,  M, EMB, EMB, 1536, 0);
        gemm_fly(x, wv + (size_t)l * EMB * EMB, bv + l * EMB, qkv + 1024, M, EMB, EMB, 1536, 0);
      }
      vmean_kernel<<<NB * HEADS, 64, 0, stream>>>(qkv, vmb, S);
      attn_full_kernel<<<NB * HEADS + 2 * (S - 1), 64, 0, stream>>>(qkv, ctx, S);
      attn_band_kernel<<<(NB * 6 * (S - 1) + 3) / 4, 256, 0, stream>>>(qkv, ctx, S);
      vmfill_kernel<<<((NB - 1) * 2 * (S - 1) * 64 + 255) / 256, 256, 0, stream>>>(vmb, ctx, S);
      if (presplit) gemm_pre(ctx, OWO + (size_t)l * 262144, bo + l * EMB, proj, M, EMB, EMB, EMB, 0);
      else gemm_fly(ctx, wo + (size_t)l * EMB * EMB, bo + l * EMB, proj, M, EMB, EMB, EMB, 0);
      ln_kernel<<<M, 256, 0, stream>>>(proj, x, l1g + l * EMB, l1b + l * EMB, nullptr, nullptr, x, S, 1e-5f);
      if (presplit){
        // FFN1: split output into (hbh, hbl) -- kills FFN2's A-split VALU chain
        int mt = (M + 127) / 128, nt2 = FFND / 128;
        gemm_mfma_pre_kernel<<<mt * nt2, 256, 0, stream>>>(
            x, WhiA + OF1 + (size_t)l * 1048576, WloA + OF1 + (size_t)l * 1048576,
            fb1 + l * FFND, nullptr, M, FFND, EMB, FFND, 1, mt, nt2, hbh, hbl, 1);
        // FFN2: pre-split A, split-K
        int mt2 = (M + 127) / 128, nt3 = EMB / 64;
        int tiles = mt2 * nt3;
        int ks = 1;
        while (ks < 8 && tiles * ks * 2 <= 2048 && FFND / (ks * 2) >= 128) ks *= 2;
        if (ks > 1){
          size_t n4 = ((size_t)M * EMB) / 4;
          int zg = (int)min((n4 + 255) / 256, (size_t)2048);
          zerobuf_kernel<<<zg, 256, 0, stream>>>(proj, n4);
        }
        gemm_mfma_pre64A_kernel<<<tiles * ks, 256, 0, stream>>>(
            hbh, hbl, WhiA + OF2 + (size_t)l * 1048576, WloA + OF2 + (size_t)l * 1048576,
            fb2 + l * EMB, proj, M, EMB, FFND, EMB, mt2, nt3, ks);
      } else {
        gemm_fly(x, fw1 + (size_t)l * FFND * EMB, fb1 + l * FFND, hb, M, FFND, EMB, FFND, 1);
        gemm_fly(hb, fw2 + (size_t)l * EMB * FFND, fb2 + l * EMB, proj, M, EMB, FFND, EMB, 0);
      }
      ln_kernel<<<M, 256, 0, stream>>>(proj, x, l2g + l * EMB, l2b + l * EMB, nullptr, nullptr, x, S, 1e-5f);
    }
    if (presplit) gemm_pre(x, OC1, fc1b, ctx, M, EMB, EMB, EMB, 2);
    else gemm_fly(x, fc1w, fc1b, ctx, M, EMB, EMB, EMB, 2);
    ln_kernel<<<M, 256, 0, stream>>>(ctx, nullptr, nullptr, nullptr, pscale, pbias, ctx, S, 1e-12f);
    if (presplit) gemm_pre(ctx, OC2, fc2b, p2, M, NCLS, EMB, NCLS, 0);
    else gemm_fly(ctx, fc2w, fc2b, p2, M, NCLS, EMB, NCLS, 0);
  };

  // Branch 1: S=101
  encoder(x1, 101);
  extract_kernel<<<(NB * 101 * NCLS + 255) / 256, 256, 0, stream>>>(p2, clsE, tok);
  if (presplit) gemm_pre(tok, OC3, fc3b, Pb, 3200, NCLS, NCLS, NCLS, 0);
  else gemm_fly(tok, fc3w, fc3b, Pb, 3200, NCLS, NCLS, NCLS, 0);
  gemm_f32(clsE, fc3w, fc3b, cls3, NB, NCLS, NCLS, 0);
  slhat_kernel<<<NB * NCLS, 256, 0, stream>>>(Pb, ls, SLh);
  outIII_kernel<<<NB, 256, 0, stream>>>(cls3, SLh, o3);
  softmax_out_kernel<<<NB, 256, 0, stream>>>(o3, out, NCLS);                    // output 0
  softmax_out_kernel<<<NB, 256, 0, stream>>>(clsE, out + NB * NCLS, NCLS);      // output 1
  gemm_f32(user_info, fc4w, fc4b, u4, NB, NCLS, 142, 0);
  normalize_kernel<<<64, 256, 0, stream>>>(clsE, u4, imn, sn);
  contrastive_kernel<<<1, 1024, 0, stream>>>(imn, sn, out);                     // output 3

  // Branch 2: S=200
  encoder(base, SEQ);
  zero_kernel<<<1, 64, 0, stream>>>(lacc);
  // two-stage means: partials into hb (free after encoder), then reduce
  means_part_kernel<<<64 * MSEG, 256, 0, stream>>>(p2, ctx, hb);
  means_final_kernel<<<64, 256, 0, stream>>>(hb, mp, ma);
  softmax_out_kernel<<<64, 256, 0, stream>>>(mp, cbf, NCLS);
  softmax_out_kernel<<<64, 256, 0, stream>>>(ma, abf, EMB);
  klfinal_kernel<<<NB, 64, 0, stream>>>(cbf, abf, lacc);
  finalize_kernel<<<1, 64, 0, stream>>>(lacc, out);                             // output 2
}